// Round 2
// baseline (542.393 us; speedup 1.0000x reference)
//
#include <hip/hip_runtime.h>

#define NN 100000
#define NE 1600000
#define EPSV 1e-5f

// ---------------- CSR build, pass 1: degree histogram + per-edge slot ----------------
__global__ __launch_bounds__(256) void k_hist(const int* __restrict__ dst,
                                              int* __restrict__ deg,
                                              int* __restrict__ epos) {
  int e = blockIdx.x * 256 + threadIdx.x;
  if (e >= NE) return;
  epos[e] = atomicAdd(&deg[dst[e]], 1);
}

// ---------------- CSR build, pass 2: exclusive prefix scan over 100K degrees ----------------
__global__ __launch_bounds__(1024) void k_scan(const int* __restrict__ deg,
                                               int* __restrict__ offset) {
  __shared__ int tmp[1024];
  const int t = threadIdx.x;
  const int CH = 98;  // 1024*98 >= 100000
  int begin = t * CH;
  int end = min(begin + CH, NN);
  int s = 0;
  for (int i = begin; i < end; ++i) s += deg[i];
  tmp[t] = s;
  __syncthreads();
  // Hillis-Steele inclusive scan
  for (int d = 1; d < 1024; d <<= 1) {
    int v = (t >= d) ? tmp[t - d] : 0;
    __syncthreads();
    tmp[t] += v;
    __syncthreads();
  }
  int run = tmp[t] - s;  // exclusive prefix of this chunk
  for (int i = begin; i < end; ++i) {
    offset[i] = run;
    run += deg[i];
  }
}

// ---------------- CSR build, pass 3: place (no atomics) ----------------
__global__ __launch_bounds__(256) void k_place(const int* __restrict__ src,
                                               const int* __restrict__ dst,
                                               const int* __restrict__ offset,
                                               const int* __restrict__ epos,
                                               int* __restrict__ csr) {
  int e = blockIdx.x * 256 + threadIdx.x;
  if (e >= NE) return;
  csr[offset[dst[e]] + epos[e]] = src[e];
}

// ---------------- transpose weights to [k][o] ----------------
__global__ __launch_bounds__(256) void k_transpose(const float* __restrict__ w1l,
                                                   const float* __restrict__ w1r,
                                                   const float* __restrict__ w2l,
                                                   const float* __restrict__ w2r,
                                                   float* __restrict__ wt) {
  int idx = blockIdx.x * 256 + threadIdx.x;  // 0..8191
  int o1 = idx >> 6, k1 = idx & 63;          // w1: [128][64] -> [64][128]
  wt[k1 * 128 + o1] = w1l[idx];
  wt[8192 + k1 * 128 + o1] = w1r[idx];
  int o2 = idx >> 7, k2 = idx & 127;         // w2: [64][128] -> [128][64]
  wt[16384 + k2 * 64 + o2] = w2l[idx];
  wt[24576 + k2 * 64 + o2] = w2r[idx];
}

// ---------------- mean-aggregate 64-dim rows over CSR ----------------
// 16 lanes per node, float4 per lane (256B per gathered row, coalesced)
__global__ __launch_bounds__(256) void k_aggregate(const float* __restrict__ feat,
                                                   const int* __restrict__ deg,
                                                   const int* __restrict__ offset,
                                                   const int* __restrict__ csr,
                                                   float* __restrict__ outb) {
  int tid = threadIdx.x;
  int node = blockIdx.x * 16 + (tid >> 4);
  int j = tid & 15;
  int cnt = deg[node];
  const int* arow = csr + offset[node];
  float ax = 0.f, ay = 0.f, az = 0.f, aw = 0.f;
  int k = 0;
  for (; k + 4 <= cnt; k += 4) {
    int s0 = arow[k], s1 = arow[k + 1], s2 = arow[k + 2], s3 = arow[k + 3];
    float4 v0 = *(const float4*)(feat + (size_t)s0 * 64 + j * 4);
    float4 v1 = *(const float4*)(feat + (size_t)s1 * 64 + j * 4);
    float4 v2 = *(const float4*)(feat + (size_t)s2 * 64 + j * 4);
    float4 v3 = *(const float4*)(feat + (size_t)s3 * 64 + j * 4);
    ax += v0.x + v1.x + v2.x + v3.x;
    ay += v0.y + v1.y + v2.y + v3.y;
    az += v0.z + v1.z + v2.z + v3.z;
    aw += v0.w + v1.w + v2.w + v3.w;
  }
  for (; k < cnt; ++k) {
    int s = arow[k];
    float4 v = *(const float4*)(feat + (size_t)s * 64 + j * 4);
    ax += v.x; ay += v.y; az += v.z; aw += v.w;
  }
  float inv = 1.0f / fmaxf((float)cnt, 1.0f);
  float4 r;
  r.x = ax * inv; r.y = ay * inv; r.z = az * inv; r.w = aw * inv;
  *(float4*)(outb + (size_t)node * 64 + j * 4) = r;
}

// ---------------- layer1 dense: h = relu(bn1(agg1@W1l.T + x@W1r.T + b1l)) ----------------
__global__ __launch_bounds__(256) void k_gemm1(const float* __restrict__ agg1,
                                               const float* __restrict__ x,
                                               const float* __restrict__ wt1l,
                                               const float* __restrict__ wt1r,
                                               const float* __restrict__ b1l,
                                               const float* __restrict__ g1,
                                               const float* __restrict__ be1,
                                               const float* __restrict__ m1,
                                               const float* __restrict__ v1,
                                               float* __restrict__ h) {
  __shared__ float wl[64 * 128];  // [k][o]
  __shared__ float wr[64 * 128];
  const int tid = threadIdx.x;
  const int node0 = blockIdx.x * 32;
  for (int i = tid * 4; i < 8192; i += 1024) {
    *(float4*)&wl[i] = *(const float4*)&wt1l[i];
    *(float4*)&wr[i] = *(const float4*)&wt1r[i];
  }
  __syncthreads();
  const int c = tid & 31;   // output cols c*4..c*4+3
  const int g = tid >> 5;   // nodes g*4..g*4+3
  const float4* wl4 = (const float4*)wl;  // [k][32]
  const float4* wr4 = (const float4*)wr;
  float acc[4][4];
#pragma unroll
  for (int n = 0; n < 4; ++n)
#pragma unroll
    for (int q = 0; q < 4; ++q) acc[n][q] = 0.f;
#pragma unroll 4
  for (int k4 = 0; k4 < 16; ++k4) {
    float4 av[4], xv[4];
#pragma unroll
    for (int n = 0; n < 4; ++n) {
      size_t row = (size_t)(node0 + g * 4 + n) * 64;
      av[n] = *(const float4*)(agg1 + row + k4 * 4);
      xv[n] = *(const float4*)(x + row + k4 * 4);
    }
#pragma unroll
    for (int jj = 0; jj < 4; ++jj) {
      float4 wlv = wl4[(k4 * 4 + jj) * 32 + c];
      float4 wrv = wr4[(k4 * 4 + jj) * 32 + c];
#pragma unroll
      for (int n = 0; n < 4; ++n) {
        float a = ((const float*)&av[n])[jj];
        float xx = ((const float*)&xv[n])[jj];
        acc[n][0] += a * wlv.x + xx * wrv.x;
        acc[n][1] += a * wlv.y + xx * wrv.y;
        acc[n][2] += a * wlv.z + xx * wrv.z;
        acc[n][3] += a * wlv.w + xx * wrv.w;
      }
    }
  }
  const int o = c * 4;
  float4 bias = *(const float4*)&b1l[o];
  float4 gm = *(const float4*)&g1[o];
  float4 bt = *(const float4*)&be1[o];
  float4 mu = *(const float4*)&m1[o];
  float4 va = *(const float4*)&v1[o];
  float sc0 = gm.x * rsqrtf(va.x + EPSV), sh0 = bt.x - mu.x * sc0;
  float sc1 = gm.y * rsqrtf(va.y + EPSV), sh1 = bt.y - mu.y * sc1;
  float sc2 = gm.z * rsqrtf(va.z + EPSV), sh2 = bt.z - mu.z * sc2;
  float sc3 = gm.w * rsqrtf(va.w + EPSV), sh3 = bt.w - mu.w * sc3;
#pragma unroll
  for (int n = 0; n < 4; ++n) {
    float4 ov;
    ov.x = fmaxf((acc[n][0] + bias.x) * sc0 + sh0, 0.f);
    ov.y = fmaxf((acc[n][1] + bias.y) * sc1 + sh1, 0.f);
    ov.z = fmaxf((acc[n][2] + bias.z) * sc2 + sh2, 0.f);
    ov.w = fmaxf((acc[n][3] + bias.w) * sc3 + sh3, 0.f);
    *(float4*)&h[(size_t)(node0 + g * 4 + n) * 128 + o] = ov;
  }
}

// ---------------- layer2 dense: t = h@W2l.T ; r2 = h@W2r.T + b2l ----------------
__global__ __launch_bounds__(256) void k_gemm2(const float* __restrict__ h,
                                               const float* __restrict__ wt2l,
                                               const float* __restrict__ wt2r,
                                               const float* __restrict__ b2l,
                                               float* __restrict__ t,
                                               float* __restrict__ r2) {
  __shared__ float wl[128 * 64];  // [k][o]
  __shared__ float wr[128 * 64];
  const int tid = threadIdx.x;
  const int node0 = blockIdx.x * 32;
  for (int i = tid * 4; i < 8192; i += 1024) {
    *(float4*)&wl[i] = *(const float4*)&wt2l[i];
    *(float4*)&wr[i] = *(const float4*)&wt2r[i];
  }
  __syncthreads();
  const int c = tid & 31;        // c<16 -> t cols, c>=16 -> r2 cols
  const int g = tid >> 5;        // nodes g*4..g*4+3
  const bool isR = (c >= 16);
  const int c4 = c & 15;
  const float4* w4 = (const float4*)(isR ? wr : wl);  // [k][16]
  float acc[4][4];
#pragma unroll
  for (int n = 0; n < 4; ++n)
#pragma unroll
    for (int q = 0; q < 4; ++q) acc[n][q] = 0.f;
#pragma unroll 4
  for (int k4 = 0; k4 < 32; ++k4) {
    float4 av[4];
#pragma unroll
    for (int n = 0; n < 4; ++n)
      av[n] = *(const float4*)(h + (size_t)(node0 + g * 4 + n) * 128 + k4 * 4);
#pragma unroll
    for (int jj = 0; jj < 4; ++jj) {
      float4 wv = w4[(k4 * 4 + jj) * 16 + c4];
#pragma unroll
      for (int n = 0; n < 4; ++n) {
        float a = ((const float*)&av[n])[jj];
        acc[n][0] += a * wv.x;
        acc[n][1] += a * wv.y;
        acc[n][2] += a * wv.z;
        acc[n][3] += a * wv.w;
      }
    }
  }
  const int o = c4 * 4;
  if (!isR) {
#pragma unroll
    for (int n = 0; n < 4; ++n) {
      float4 ov;
      ov.x = acc[n][0]; ov.y = acc[n][1]; ov.z = acc[n][2]; ov.w = acc[n][3];
      *(float4*)&t[(size_t)(node0 + g * 4 + n) * 64 + o] = ov;
    }
  } else {
    float4 bias = *(const float4*)&b2l[o];
#pragma unroll
    for (int n = 0; n < 4; ++n) {
      float4 ov;
      ov.x = acc[n][0] + bias.x; ov.y = acc[n][1] + bias.y;
      ov.z = acc[n][2] + bias.z; ov.w = acc[n][3] + bias.w;
      *(float4*)&r2[(size_t)(node0 + g * 4 + n) * 64 + o] = ov;
    }
  }
}

// ---------------- layer2 aggregate + BN2 finish ----------------
__global__ __launch_bounds__(256) void k_agg2fin(const float* __restrict__ t,
                                                 const int* __restrict__ deg,
                                                 const int* __restrict__ offset,
                                                 const int* __restrict__ csr,
                                                 const float* __restrict__ r2,
                                                 const float* __restrict__ g2,
                                                 const float* __restrict__ be2,
                                                 const float* __restrict__ m2,
                                                 const float* __restrict__ v2,
                                                 float* __restrict__ outp) {
  int tid = threadIdx.x;
  int node = blockIdx.x * 16 + (tid >> 4);
  int j = tid & 15;
  int cnt = deg[node];
  const int* arow = csr + offset[node];
  float ax = 0.f, ay = 0.f, az = 0.f, aw = 0.f;
  int k = 0;
  for (; k + 4 <= cnt; k += 4) {
    int s0 = arow[k], s1 = arow[k + 1], s2 = arow[k + 2], s3 = arow[k + 3];
    float4 v0 = *(const float4*)(t + (size_t)s0 * 64 + j * 4);
    float4 v1 = *(const float4*)(t + (size_t)s1 * 64 + j * 4);
    float4 v2 = *(const float4*)(t + (size_t)s2 * 64 + j * 4);
    float4 v3 = *(const float4*)(t + (size_t)s3 * 64 + j * 4);
    ax += v0.x + v1.x + v2.x + v3.x;
    ay += v0.y + v1.y + v2.y + v3.y;
    az += v0.z + v1.z + v2.z + v3.z;
    aw += v0.w + v1.w + v2.w + v3.w;
  }
  for (; k < cnt; ++k) {
    int s = arow[k];
    float4 v = *(const float4*)(t + (size_t)s * 64 + j * 4);
    ax += v.x; ay += v.y; az += v.z; aw += v.w;
  }
  float inv = 1.0f / fmaxf((float)cnt, 1.0f);
  float4 r = *(const float4*)(r2 + (size_t)node * 64 + j * 4);
  float vx = ax * inv + r.x;
  float vy = ay * inv + r.y;
  float vz = az * inv + r.z;
  float vw = aw * inv + r.w;
  int o = j * 4;
  float4 gm = *(const float4*)&g2[o];
  float4 bt = *(const float4*)&be2[o];
  float4 mu = *(const float4*)&m2[o];
  float4 va = *(const float4*)&v2[o];
  float4 ov;
  ov.x = (vx - mu.x) * (gm.x * rsqrtf(va.x + EPSV)) + bt.x;
  ov.y = (vy - mu.y) * (gm.y * rsqrtf(va.y + EPSV)) + bt.y;
  ov.z = (vz - mu.z) * (gm.z * rsqrtf(va.z + EPSV)) + bt.z;
  ov.w = (vw - mu.w) * (gm.w * rsqrtf(va.w + EPSV)) + bt.w;
  *(float4*)(outp + (size_t)node * 64 + o) = ov;
}

extern "C" void kernel_launch(void* const* d_in, const int* in_sizes, int n_in,
                              void* d_out, int out_size, void* d_ws, size_t ws_size,
                              hipStream_t stream) {
  const float* x   = (const float*)d_in[0];
  const int*   ei  = (const int*)d_in[1];
  const float* w1l = (const float*)d_in[2];
  const float* b1l = (const float*)d_in[3];
  const float* w1r = (const float*)d_in[4];
  const float* g1  = (const float*)d_in[5];
  const float* be1 = (const float*)d_in[6];
  const float* m1  = (const float*)d_in[7];
  const float* v1  = (const float*)d_in[8];
  const float* w2l = (const float*)d_in[9];
  const float* b2l = (const float*)d_in[10];
  const float* w2r = (const float*)d_in[11];
  const float* g2  = (const float*)d_in[12];
  const float* be2 = (const float*)d_in[13];
  const float* m2  = (const float*)d_in[14];
  const float* v2  = (const float*)d_in[15];
  float* outp = (float*)d_out;

  char* ws = (char*)d_ws;
  // layout (bytes), all 16B-aligned:
  //          0 : deg      (   400,000)
  //    400,000 : offset   (   400,016)
  //    800,016 : epos     ( 6,400,000)
  //  7,200,016 : csr      ( 6,400,000)
  // 13,600,016 : wt       (   131,072)
  // 13,731,088 : agg1/r2  (25,600,000)
  // 39,331,088 : h        (51,200,000)
  // 90,531,088 : t        (25,600,000)  -> total ~116.1 MB
  int*   deg    = (int*)ws;
  int*   offset = (int*)(ws + 400000);
  int*   epos   = (int*)(ws + 800016);
  int*   csr    = (int*)(ws + 7200016);
  float* wt     = (float*)(ws + 13600016);
  float* agg1   = (float*)(ws + 13731088);
  float* r2     = agg1;  // agg1 dead after k_gemm1; reuse for r2
  float* h      = (float*)(ws + 39331088);
  float* t      = (float*)(ws + 90531088);

  const int* srcp = ei;
  const int* dstp = ei + NE;

  hipMemsetAsync(deg, 0, NN * sizeof(int), stream);
  hipLaunchKernelGGL(k_hist, dim3(NE / 256), dim3(256), 0, stream,
                     dstp, deg, epos);
  hipLaunchKernelGGL(k_scan, dim3(1), dim3(1024), 0, stream, deg, offset);
  hipLaunchKernelGGL(k_place, dim3(NE / 256), dim3(256), 0, stream,
                     srcp, dstp, offset, epos, csr);
  hipLaunchKernelGGL(k_transpose, dim3(32), dim3(256), 0, stream,
                     w1l, w1r, w2l, w2r, wt);
  hipLaunchKernelGGL(k_aggregate, dim3(NN / 16), dim3(256), 0, stream,
                     x, deg, offset, csr, agg1);
  hipLaunchKernelGGL(k_gemm1, dim3(NN / 32), dim3(256), 0, stream,
                     agg1, x, wt, wt + 8192, b1l, g1, be1, m1, v1, h);
  hipLaunchKernelGGL(k_gemm2, dim3(NN / 32), dim3(256), 0, stream,
                     h, wt + 16384, wt + 24576, b2l, t, r2);
  hipLaunchKernelGGL(k_agg2fin, dim3(NN / 16), dim3(256), 0, stream,
                     t, deg, offset, csr, r2, g2, be2, m2, v2, outp);
}

// Round 3
// 469.689 us; speedup vs baseline: 1.1548x; 1.1548x over previous
//
#include <hip/hip_runtime.h>

#define NN 100000
#define NE 1600000
#define EPSV 1e-5f
#define SCAN_NB 98   // 98 * 1024 >= 100000

// ---------------- CSR build, pass 1: degree histogram ----------------
__global__ __launch_bounds__(256) void k_hist(const int* __restrict__ dst,
                                              int* __restrict__ deg) {
  int e = blockIdx.x * 256 + threadIdx.x;
  if (e >= NE) return;
  atomicAdd(&deg[dst[e]], 1);
}

// ---------------- scan A: per-block (1024 elems) scan + block sums ----------------
__global__ __launch_bounds__(256) void k_scanA(const int* __restrict__ deg,
                                               int* __restrict__ partial,
                                               int* __restrict__ blocksum) {
  __shared__ int ts[256];
  const int t = threadIdx.x;
  const int base = blockIdx.x * 1024 + t * 4;
  int4 v = {0, 0, 0, 0};
  if (base + 4 <= NN) v = *(const int4*)(deg + base);  // NN%4==0: tail aligned
  int s = v.x + v.y + v.z + v.w;
  ts[t] = s;
  __syncthreads();
  for (int d = 1; d < 256; d <<= 1) {
    int val = (t >= d) ? ts[t - d] : 0;
    __syncthreads();
    ts[t] += val;
    __syncthreads();
  }
  int excl = ts[t] - s;
  if (base + 4 <= NN) {
    int4 p;
    p.x = excl;
    p.y = p.x + v.x;
    p.z = p.y + v.y;
    p.w = p.z + v.z;
    *(int4*)(partial + base) = p;
  }
  if (t == 255) blocksum[blockIdx.x] = ts[255];
}

// ---------------- scan B: scan the 98 block sums ----------------
__global__ __launch_bounds__(128) void k_scanB(const int* __restrict__ blocksum,
                                               int* __restrict__ blockbase) {
  __shared__ int ts[128];
  const int t = threadIdx.x;
  int s = (t < SCAN_NB) ? blocksum[t] : 0;
  ts[t] = s;
  __syncthreads();
  for (int d = 1; d < 128; d <<= 1) {
    int val = (t >= d) ? ts[t - d] : 0;
    __syncthreads();
    ts[t] += val;
    __syncthreads();
  }
  if (t < SCAN_NB) blockbase[t] = ts[t] - s;
}

// ---------------- scan C: add block base; write offset + cursor copy ----------------
__global__ __launch_bounds__(256) void k_scanC(const int* __restrict__ partial,
                                               const int* __restrict__ blockbase,
                                               int* __restrict__ offset,
                                               int* __restrict__ cursor) {
  const int base = blockIdx.x * 1024 + threadIdx.x * 4;
  if (base + 4 > NN) return;
  int bb = blockbase[blockIdx.x];
  int4 p = *(const int4*)(partial + base);
  p.x += bb; p.y += bb; p.z += bb; p.w += bb;
  *(int4*)(offset + base) = p;
  *(int4*)(cursor + base) = p;
}

// ---------------- CSR build, pass 3: place via atomic cursor ----------------
__global__ __launch_bounds__(256) void k_place(const int* __restrict__ src,
                                               const int* __restrict__ dst,
                                               int* __restrict__ cursor,
                                               int* __restrict__ csr) {
  int e = blockIdx.x * 256 + threadIdx.x;
  if (e >= NE) return;
  int pos = atomicAdd(&cursor[dst[e]], 1);
  csr[pos] = src[e];
}

// ---------------- transpose weights to [k][o] ----------------
__global__ __launch_bounds__(256) void k_transpose(const float* __restrict__ w1l,
                                                   const float* __restrict__ w1r,
                                                   const float* __restrict__ w2l,
                                                   const float* __restrict__ w2r,
                                                   float* __restrict__ wt) {
  int idx = blockIdx.x * 256 + threadIdx.x;  // 0..8191
  int o1 = idx >> 6, k1 = idx & 63;          // w1: [128][64] -> [64][128]
  wt[k1 * 128 + o1] = w1l[idx];
  wt[8192 + k1 * 128 + o1] = w1r[idx];
  int o2 = idx >> 7, k2 = idx & 127;         // w2: [64][128] -> [128][64]
  wt[16384 + k2 * 64 + o2] = w2l[idx];
  wt[24576 + k2 * 64 + o2] = w2r[idx];
}

// ---------------- mean-aggregate 64-dim rows over CSR ----------------
__global__ __launch_bounds__(256) void k_aggregate(const float* __restrict__ feat,
                                                   const int* __restrict__ deg,
                                                   const int* __restrict__ offset,
                                                   const int* __restrict__ csr,
                                                   float* __restrict__ outb) {
  int tid = threadIdx.x;
  int node = blockIdx.x * 16 + (tid >> 4);
  int j = tid & 15;
  int cnt = deg[node];
  const int* arow = csr + offset[node];
  float ax = 0.f, ay = 0.f, az = 0.f, aw = 0.f;
  int k = 0;
  for (; k + 4 <= cnt; k += 4) {
    int s0 = arow[k], s1 = arow[k + 1], s2 = arow[k + 2], s3 = arow[k + 3];
    float4 v0 = *(const float4*)(feat + (size_t)s0 * 64 + j * 4);
    float4 v1 = *(const float4*)(feat + (size_t)s1 * 64 + j * 4);
    float4 v2 = *(const float4*)(feat + (size_t)s2 * 64 + j * 4);
    float4 v3 = *(const float4*)(feat + (size_t)s3 * 64 + j * 4);
    ax += v0.x + v1.x + v2.x + v3.x;
    ay += v0.y + v1.y + v2.y + v3.y;
    az += v0.z + v1.z + v2.z + v3.z;
    aw += v0.w + v1.w + v2.w + v3.w;
  }
  for (; k < cnt; ++k) {
    int s = arow[k];
    float4 v = *(const float4*)(feat + (size_t)s * 64 + j * 4);
    ax += v.x; ay += v.y; az += v.z; aw += v.w;
  }
  float inv = 1.0f / fmaxf((float)cnt, 1.0f);
  float4 r;
  r.x = ax * inv; r.y = ay * inv; r.z = az * inv; r.w = aw * inv;
  *(float4*)(outb + (size_t)node * 64 + j * 4) = r;
}

// ---------------- layer1 dense: h = relu(bn1(agg1@W1l.T + x@W1r.T + b1l)) ----------------
__global__ __launch_bounds__(256) void k_gemm1(const float* __restrict__ agg1,
                                               const float* __restrict__ x,
                                               const float* __restrict__ wt1l,
                                               const float* __restrict__ wt1r,
                                               const float* __restrict__ b1l,
                                               const float* __restrict__ g1,
                                               const float* __restrict__ be1,
                                               const float* __restrict__ m1,
                                               const float* __restrict__ v1,
                                               float* __restrict__ h) {
  __shared__ float wl[64 * 128];  // [k][o]
  __shared__ float wr[64 * 128];
  const int tid = threadIdx.x;
  const int node0 = blockIdx.x * 32;
  for (int i = tid * 4; i < 8192; i += 1024) {
    *(float4*)&wl[i] = *(const float4*)&wt1l[i];
    *(float4*)&wr[i] = *(const float4*)&wt1r[i];
  }
  __syncthreads();
  const int c = tid & 31;   // output cols c*4..c*4+3
  const int g = tid >> 5;   // nodes g*4..g*4+3
  const float4* wl4 = (const float4*)wl;  // [k][32]
  const float4* wr4 = (const float4*)wr;
  float acc[4][4];
#pragma unroll
  for (int n = 0; n < 4; ++n)
#pragma unroll
    for (int q = 0; q < 4; ++q) acc[n][q] = 0.f;
#pragma unroll 4
  for (int k4 = 0; k4 < 16; ++k4) {
    float4 av[4], xv[4];
#pragma unroll
    for (int n = 0; n < 4; ++n) {
      size_t row = (size_t)(node0 + g * 4 + n) * 64;
      av[n] = *(const float4*)(agg1 + row + k4 * 4);
      xv[n] = *(const float4*)(x + row + k4 * 4);
    }
#pragma unroll
    for (int jj = 0; jj < 4; ++jj) {
      float4 wlv = wl4[(k4 * 4 + jj) * 32 + c];
      float4 wrv = wr4[(k4 * 4 + jj) * 32 + c];
#pragma unroll
      for (int n = 0; n < 4; ++n) {
        float a = ((const float*)&av[n])[jj];
        float xx = ((const float*)&xv[n])[jj];
        acc[n][0] += a * wlv.x + xx * wrv.x;
        acc[n][1] += a * wlv.y + xx * wrv.y;
        acc[n][2] += a * wlv.z + xx * wrv.z;
        acc[n][3] += a * wlv.w + xx * wrv.w;
      }
    }
  }
  const int o = c * 4;
  float4 bias = *(const float4*)&b1l[o];
  float4 gm = *(const float4*)&g1[o];
  float4 bt = *(const float4*)&be1[o];
  float4 mu = *(const float4*)&m1[o];
  float4 va = *(const float4*)&v1[o];
  float sc0 = gm.x * rsqrtf(va.x + EPSV), sh0 = bt.x - mu.x * sc0;
  float sc1 = gm.y * rsqrtf(va.y + EPSV), sh1 = bt.y - mu.y * sc1;
  float sc2 = gm.z * rsqrtf(va.z + EPSV), sh2 = bt.z - mu.z * sc2;
  float sc3 = gm.w * rsqrtf(va.w + EPSV), sh3 = bt.w - mu.w * sc3;
#pragma unroll
  for (int n = 0; n < 4; ++n) {
    float4 ov;
    ov.x = fmaxf((acc[n][0] + bias.x) * sc0 + sh0, 0.f);
    ov.y = fmaxf((acc[n][1] + bias.y) * sc1 + sh1, 0.f);
    ov.z = fmaxf((acc[n][2] + bias.z) * sc2 + sh2, 0.f);
    ov.w = fmaxf((acc[n][3] + bias.w) * sc3 + sh3, 0.f);
    *(float4*)&h[(size_t)(node0 + g * 4 + n) * 128 + o] = ov;
  }
}

// ---------------- layer2 dense: t = h@W2l.T ; r2 = h@W2r.T + b2l ----------------
__global__ __launch_bounds__(256) void k_gemm2(const float* __restrict__ h,
                                               const float* __restrict__ wt2l,
                                               const float* __restrict__ wt2r,
                                               const float* __restrict__ b2l,
                                               float* __restrict__ t,
                                               float* __restrict__ r2) {
  __shared__ float wl[128 * 64];  // [k][o]
  __shared__ float wr[128 * 64];
  const int tid = threadIdx.x;
  const int node0 = blockIdx.x * 32;
  for (int i = tid * 4; i < 8192; i += 1024) {
    *(float4*)&wl[i] = *(const float4*)&wt2l[i];
    *(float4*)&wr[i] = *(const float4*)&wt2r[i];
  }
  __syncthreads();
  const int c = tid & 31;        // c<16 -> t cols, c>=16 -> r2 cols
  const int g = tid >> 5;        // nodes g*4..g*4+3
  const bool isR = (c >= 16);
  const int c4 = c & 15;
  const float4* w4 = (const float4*)(isR ? wr : wl);  // [k][16]
  float acc[4][4];
#pragma unroll
  for (int n = 0; n < 4; ++n)
#pragma unroll
    for (int q = 0; q < 4; ++q) acc[n][q] = 0.f;
#pragma unroll 4
  for (int k4 = 0; k4 < 32; ++k4) {
    float4 av[4];
#pragma unroll
    for (int n = 0; n < 4; ++n)
      av[n] = *(const float4*)(h + (size_t)(node0 + g * 4 + n) * 128 + k4 * 4);
#pragma unroll
    for (int jj = 0; jj < 4; ++jj) {
      float4 wv = w4[(k4 * 4 + jj) * 16 + c4];
#pragma unroll
      for (int n = 0; n < 4; ++n) {
        float a = ((const float*)&av[n])[jj];
        acc[n][0] += a * wv.x;
        acc[n][1] += a * wv.y;
        acc[n][2] += a * wv.z;
        acc[n][3] += a * wv.w;
      }
    }
  }
  const int o = c4 * 4;
  if (!isR) {
#pragma unroll
    for (int n = 0; n < 4; ++n) {
      float4 ov;
      ov.x = acc[n][0]; ov.y = acc[n][1]; ov.z = acc[n][2]; ov.w = acc[n][3];
      *(float4*)&t[(size_t)(node0 + g * 4 + n) * 64 + o] = ov;
    }
  } else {
    float4 bias = *(const float4*)&b2l[o];
#pragma unroll
    for (int n = 0; n < 4; ++n) {
      float4 ov;
      ov.x = acc[n][0] + bias.x; ov.y = acc[n][1] + bias.y;
      ov.z = acc[n][2] + bias.z; ov.w = acc[n][3] + bias.w;
      *(float4*)&r2[(size_t)(node0 + g * 4 + n) * 64 + o] = ov;
    }
  }
}

// ---------------- layer2 aggregate + BN2 finish ----------------
__global__ __launch_bounds__(256) void k_agg2fin(const float* __restrict__ t,
                                                 const int* __restrict__ deg,
                                                 const int* __restrict__ offset,
                                                 const int* __restrict__ csr,
                                                 const float* __restrict__ r2,
                                                 const float* __restrict__ g2,
                                                 const float* __restrict__ be2,
                                                 const float* __restrict__ m2,
                                                 const float* __restrict__ v2,
                                                 float* __restrict__ outp) {
  int tid = threadIdx.x;
  int node = blockIdx.x * 16 + (tid >> 4);
  int j = tid & 15;
  int cnt = deg[node];
  const int* arow = csr + offset[node];
  float ax = 0.f, ay = 0.f, az = 0.f, aw = 0.f;
  int k = 0;
  for (; k + 4 <= cnt; k += 4) {
    int s0 = arow[k], s1 = arow[k + 1], s2 = arow[k + 2], s3 = arow[k + 3];
    float4 v0 = *(const float4*)(t + (size_t)s0 * 64 + j * 4);
    float4 v1 = *(const float4*)(t + (size_t)s1 * 64 + j * 4);
    float4 v2 = *(const float4*)(t + (size_t)s2 * 64 + j * 4);
    float4 v3 = *(const float4*)(t + (size_t)s3 * 64 + j * 4);
    ax += v0.x + v1.x + v2.x + v3.x;
    ay += v0.y + v1.y + v2.y + v3.y;
    az += v0.z + v1.z + v2.z + v3.z;
    aw += v0.w + v1.w + v2.w + v3.w;
  }
  for (; k < cnt; ++k) {
    int s = arow[k];
    float4 v = *(const float4*)(t + (size_t)s * 64 + j * 4);
    ax += v.x; ay += v.y; az += v.z; aw += v.w;
  }
  float inv = 1.0f / fmaxf((float)cnt, 1.0f);
  float4 r = *(const float4*)(r2 + (size_t)node * 64 + j * 4);
  float vx = ax * inv + r.x;
  float vy = ay * inv + r.y;
  float vz = az * inv + r.z;
  float vw = aw * inv + r.w;
  int o = j * 4;
  float4 gm = *(const float4*)&g2[o];
  float4 bt = *(const float4*)&be2[o];
  float4 mu = *(const float4*)&m2[o];
  float4 va = *(const float4*)&v2[o];
  float4 ov;
  ov.x = (vx - mu.x) * (gm.x * rsqrtf(va.x + EPSV)) + bt.x;
  ov.y = (vy - mu.y) * (gm.y * rsqrtf(va.y + EPSV)) + bt.y;
  ov.z = (vz - mu.z) * (gm.z * rsqrtf(va.z + EPSV)) + bt.z;
  ov.w = (vw - mu.w) * (gm.w * rsqrtf(va.w + EPSV)) + bt.w;
  *(float4*)(outp + (size_t)node * 64 + o) = ov;
}

extern "C" void kernel_launch(void* const* d_in, const int* in_sizes, int n_in,
                              void* d_out, int out_size, void* d_ws, size_t ws_size,
                              hipStream_t stream) {
  const float* x   = (const float*)d_in[0];
  const int*   ei  = (const int*)d_in[1];
  const float* w1l = (const float*)d_in[2];
  const float* b1l = (const float*)d_in[3];
  const float* w1r = (const float*)d_in[4];
  const float* g1  = (const float*)d_in[5];
  const float* be1 = (const float*)d_in[6];
  const float* m1  = (const float*)d_in[7];
  const float* v1  = (const float*)d_in[8];
  const float* w2l = (const float*)d_in[9];
  const float* b2l = (const float*)d_in[10];
  const float* w2r = (const float*)d_in[11];
  const float* g2  = (const float*)d_in[12];
  const float* be2 = (const float*)d_in[13];
  const float* m2  = (const float*)d_in[14];
  const float* v2  = (const float*)d_in[15];
  float* outp = (float*)d_out;

  char* ws = (char*)d_ws;
  // layout (bytes), all 16B-aligned:
  //          0 : deg       (   400,000)
  //    400,000 : offset    (   400,000)
  //    800,000 : cursor    (   400,000)
  //  1,200,000 : partial   (   400,000)
  //  1,600,000 : blocksum  (       512)
  //  1,600,512 : blockbase (       512)
  //  1,601,024 : csr       ( 6,400,000)
  //  8,001,024 : wt        (   131,072)
  //  8,132,096 : agg1/r2   (25,600,000)
  // 33,732,096 : h         (51,200,000)
  // 84,932,096 : t         (25,600,000)   -> total ~110.5 MB
  int*   deg       = (int*)ws;
  int*   offset    = (int*)(ws + 400000);
  int*   cursor    = (int*)(ws + 800000);
  int*   partial   = (int*)(ws + 1200000);
  int*   blocksum  = (int*)(ws + 1600000);
  int*   blockbase = (int*)(ws + 1600512);
  int*   csr       = (int*)(ws + 1601024);
  float* wt        = (float*)(ws + 8001024);
  float* agg1      = (float*)(ws + 8132096);
  float* r2        = agg1;  // agg1 dead after k_gemm1; reuse for r2
  float* h         = (float*)(ws + 33732096);
  float* t         = (float*)(ws + 84932096);

  const int* srcp = ei;
  const int* dstp = ei + NE;

  hipMemsetAsync(deg, 0, NN * sizeof(int), stream);
  hipLaunchKernelGGL(k_hist, dim3(NE / 256), dim3(256), 0, stream, dstp, deg);
  hipLaunchKernelGGL(k_scanA, dim3(SCAN_NB), dim3(256), 0, stream,
                     deg, partial, blocksum);
  hipLaunchKernelGGL(k_scanB, dim3(1), dim3(128), 0, stream,
                     blocksum, blockbase);
  hipLaunchKernelGGL(k_scanC, dim3(SCAN_NB), dim3(256), 0, stream,
                     partial, blockbase, offset, cursor);
  hipLaunchKernelGGL(k_place, dim3(NE / 256), dim3(256), 0, stream,
                     srcp, dstp, cursor, csr);
  hipLaunchKernelGGL(k_transpose, dim3(32), dim3(256), 0, stream,
                     w1l, w1r, w2l, w2r, wt);
  hipLaunchKernelGGL(k_aggregate, dim3(NN / 16), dim3(256), 0, stream,
                     x, deg, offset, csr, agg1);
  hipLaunchKernelGGL(k_gemm1, dim3(NN / 32), dim3(256), 0, stream,
                     agg1, x, wt, wt + 8192, b1l, g1, be1, m1, v1, h);
  hipLaunchKernelGGL(k_gemm2, dim3(NN / 32), dim3(256), 0, stream,
                     h, wt + 16384, wt + 24576, b2l, t, r2);
  hipLaunchKernelGGL(k_agg2fin, dim3(NN / 16), dim3(256), 0, stream,
                     t, deg, offset, csr, r2, g2, be2, m2, v2, outp);
}

// Round 4
// 335.034 us; speedup vs baseline: 1.6189x; 1.4019x over previous
//
#include <hip/hip_runtime.h>

#define NN 100000
#define NE 1600000
#define EPSV 1e-5f

#define NBUK 196       // buckets of 512 nodes: bucket = dst >> 9
#define TILE 8192      // edges per k_bin workgroup
#define NTIL 196       // ceil(NE / TILE)
#define CAP  9216      // per-bucket capacity (mean 8163, std ~90 -> +11 sigma)

// ---------------- phase 1: LDS-binned edge partition ----------------
// Packs (dst&511)<<17 | src  (src < 2^17) into u32, appended per-bucket.
__global__ __launch_bounds__(256) void k_bin(const int* __restrict__ src,
                                             const int* __restrict__ dst,
                                             int* __restrict__ gcur,
                                             unsigned* __restrict__ pairs) {
  __shared__ int cnt[NBUK];    // counts, then reused as cursor
  __shared__ int lo[NBUK];     // exclusive local offsets (kept for search)
  __shared__ int gbase[NBUK];  // global append base per bucket
  __shared__ int ts[256];
  __shared__ unsigned stage[TILE];
  const int tid = threadIdx.x;
  const int e0 = blockIdx.x * TILE;
  const int m = min(TILE, NE - e0);

  for (int i = tid; i < NBUK; i += 256) cnt[i] = 0;
  __syncthreads();
  // pass A: local histogram
  for (int i = tid; i < m; i += 256) {
    int d = dst[e0 + i];
    atomicAdd(&cnt[d >> 9], 1);
  }
  __syncthreads();
  // scan 196 counts -> exclusive lo; reserve global space per bucket
  int c = (tid < NBUK) ? cnt[tid] : 0;
  ts[tid] = c;
  __syncthreads();
  for (int d = 1; d < 256; d <<= 1) {
    int v = (tid >= d) ? ts[tid - d] : 0;
    __syncthreads();
    ts[tid] += v;
    __syncthreads();
  }
  if (tid < NBUK) {
    int ex = ts[tid] - c;
    lo[tid] = ex;
    gbase[tid] = atomicAdd(&gcur[tid], c);
    cnt[tid] = ex;  // cursor
  }
  __syncthreads();
  // pass B: re-read edges (L2-hot), place packed entries into LDS stage
  for (int i = tid; i < m; i += 256) {
    int d = dst[e0 + i];
    int s = src[e0 + i];
    int b = d >> 9;
    int pos = atomicAdd(&cnt[b], 1);
    stage[pos] = ((unsigned)(d & 511) << 17) | (unsigned)s;
  }
  __syncthreads();
  // copy out: consecutive stage indices -> consecutive global slots (coalesced)
  for (int i = tid; i < m; i += 256) {
    // largest b with lo[b] <= i
    int a = 0, z = NBUK - 1;
    while (a < z) {
      int mid = (a + z + 1) >> 1;
      if (lo[mid] <= i) a = mid; else z = mid - 1;
    }
    int rel = gbase[a] + (i - lo[a]);
    if (rel < CAP) pairs[(size_t)a * CAP + rel] = stage[i];
  }
}

// ---------------- phase 1.5: scan bucket counts ----------------
__global__ __launch_bounds__(256) void k_bscan(const int* __restrict__ gcur,
                                               int* __restrict__ bucketBase) {
  __shared__ int ts[256];
  const int tid = threadIdx.x;
  int c = (tid < NBUK) ? min(gcur[tid], CAP) : 0;
  ts[tid] = c;
  __syncthreads();
  for (int d = 1; d < 256; d <<= 1) {
    int v = (tid >= d) ? ts[tid - d] : 0;
    __syncthreads();
    ts[tid] += v;
    __syncthreads();
  }
  if (tid < NBUK) bucketBase[tid] = ts[tid] - c;
}

// ---------------- phase 2: per-bucket CSR build (all LDS, coalesced out) ----------------
__global__ __launch_bounds__(256) void k_build(const unsigned* __restrict__ pairs,
                                               const int* __restrict__ gcur,
                                               const int* __restrict__ bucketBase,
                                               int* __restrict__ deg,
                                               int* __restrict__ offset,
                                               int* __restrict__ csr) {
  __shared__ int hist[512];   // counts, then cursor
  __shared__ int lofs[512];
  __shared__ int ts[256];
  __shared__ unsigned stage[CAP];
  const int tid = threadIdx.x;
  const int b = blockIdx.x;
  const int count = min(gcur[b], CAP);
  const int nbase = b * 512;
  const int nloc = min(512, NN - nbase);
  const unsigned* pb = pairs + (size_t)b * CAP;
  const int obase = bucketBase[b];

  hist[tid] = 0; hist[tid + 256] = 0;
  __syncthreads();
  // pass A: local-node histogram
  for (int i = tid; i < count; i += 256) {
    atomicAdd(&hist[pb[i] >> 17], 1);
  }
  __syncthreads();
  // scan 512 via 256 threads (2 elems each)
  int v0 = hist[2 * tid], v1 = hist[2 * tid + 1];
  int s = v0 + v1;
  ts[tid] = s;
  __syncthreads();
  for (int d = 1; d < 256; d <<= 1) {
    int v = (tid >= d) ? ts[tid - d] : 0;
    __syncthreads();
    ts[tid] += v;
    __syncthreads();
  }
  int ex = ts[tid] - s;
  lofs[2 * tid] = ex;
  lofs[2 * tid + 1] = ex + v0;
  __syncthreads();
  // write deg / offset (coalesced), set cursor
  for (int n = tid; n < nloc; n += 256) {
    deg[nbase + n] = hist[n];
    offset[nbase + n] = obase + lofs[n];
  }
  __syncthreads();
  hist[2 * tid] = lofs[2 * tid];
  hist[2 * tid + 1] = lofs[2 * tid + 1];
  __syncthreads();
  // pass B: place src into LDS stage ordered by node
  for (int i = tid; i < count; i += 256) {
    unsigned e = pb[i];
    int pos = atomicAdd(&hist[e >> 17], 1);
    stage[pos] = e & 0x1FFFFu;
  }
  __syncthreads();
  // coalesced CSR segment write
  for (int i = tid; i < count; i += 256) csr[obase + i] = (int)stage[i];
}

// ---------------- transpose weights to [k][o] ----------------
__global__ __launch_bounds__(256) void k_transpose(const float* __restrict__ w1l,
                                                   const float* __restrict__ w1r,
                                                   const float* __restrict__ w2l,
                                                   const float* __restrict__ w2r,
                                                   float* __restrict__ wt) {
  int idx = blockIdx.x * 256 + threadIdx.x;  // 0..8191
  int o1 = idx >> 6, k1 = idx & 63;          // w1: [128][64] -> [64][128]
  wt[k1 * 128 + o1] = w1l[idx];
  wt[8192 + k1 * 128 + o1] = w1r[idx];
  int o2 = idx >> 7, k2 = idx & 127;         // w2: [64][128] -> [128][64]
  wt[16384 + k2 * 64 + o2] = w2l[idx];
  wt[24576 + k2 * 64 + o2] = w2r[idx];
}

// ---------------- mean-aggregate 64-dim rows over CSR ----------------
__global__ __launch_bounds__(256) void k_aggregate(const float* __restrict__ feat,
                                                   const int* __restrict__ deg,
                                                   const int* __restrict__ offset,
                                                   const int* __restrict__ csr,
                                                   float* __restrict__ outb) {
  int tid = threadIdx.x;
  int node = blockIdx.x * 16 + (tid >> 4);
  int j = tid & 15;
  int cnt = deg[node];
  const int* arow = csr + offset[node];
  float ax = 0.f, ay = 0.f, az = 0.f, aw = 0.f;
  int k = 0;
  for (; k + 4 <= cnt; k += 4) {
    int s0 = arow[k], s1 = arow[k + 1], s2 = arow[k + 2], s3 = arow[k + 3];
    float4 v0 = *(const float4*)(feat + (size_t)s0 * 64 + j * 4);
    float4 v1 = *(const float4*)(feat + (size_t)s1 * 64 + j * 4);
    float4 v2 = *(const float4*)(feat + (size_t)s2 * 64 + j * 4);
    float4 v3 = *(const float4*)(feat + (size_t)s3 * 64 + j * 4);
    ax += v0.x + v1.x + v2.x + v3.x;
    ay += v0.y + v1.y + v2.y + v3.y;
    az += v0.z + v1.z + v2.z + v3.z;
    aw += v0.w + v1.w + v2.w + v3.w;
  }
  for (; k < cnt; ++k) {
    int s = arow[k];
    float4 v = *(const float4*)(feat + (size_t)s * 64 + j * 4);
    ax += v.x; ay += v.y; az += v.z; aw += v.w;
  }
  float inv = 1.0f / fmaxf((float)cnt, 1.0f);
  float4 r;
  r.x = ax * inv; r.y = ay * inv; r.z = az * inv; r.w = aw * inv;
  *(float4*)(outb + (size_t)node * 64 + j * 4) = r;
}

// ---------------- layer1 dense: h = relu(bn1(agg1@W1l.T + x@W1r.T + b1l)) ----------------
__global__ __launch_bounds__(256) void k_gemm1(const float* __restrict__ agg1,
                                               const float* __restrict__ x,
                                               const float* __restrict__ wt1l,
                                               const float* __restrict__ wt1r,
                                               const float* __restrict__ b1l,
                                               const float* __restrict__ g1,
                                               const float* __restrict__ be1,
                                               const float* __restrict__ m1,
                                               const float* __restrict__ v1,
                                               float* __restrict__ h) {
  __shared__ float wl[64 * 128];  // [k][o]
  __shared__ float wr[64 * 128];
  const int tid = threadIdx.x;
  const int node0 = blockIdx.x * 32;
  for (int i = tid * 4; i < 8192; i += 1024) {
    *(float4*)&wl[i] = *(const float4*)&wt1l[i];
    *(float4*)&wr[i] = *(const float4*)&wt1r[i];
  }
  __syncthreads();
  const int c = tid & 31;   // output cols c*4..c*4+3
  const int g = tid >> 5;   // nodes g*4..g*4+3
  const float4* wl4 = (const float4*)wl;  // [k][32]
  const float4* wr4 = (const float4*)wr;
  float acc[4][4];
#pragma unroll
  for (int n = 0; n < 4; ++n)
#pragma unroll
    for (int q = 0; q < 4; ++q) acc[n][q] = 0.f;
#pragma unroll 4
  for (int k4 = 0; k4 < 16; ++k4) {
    float4 av[4], xv[4];
#pragma unroll
    for (int n = 0; n < 4; ++n) {
      size_t row = (size_t)(node0 + g * 4 + n) * 64;
      av[n] = *(const float4*)(agg1 + row + k4 * 4);
      xv[n] = *(const float4*)(x + row + k4 * 4);
    }
#pragma unroll
    for (int jj = 0; jj < 4; ++jj) {
      float4 wlv = wl4[(k4 * 4 + jj) * 32 + c];
      float4 wrv = wr4[(k4 * 4 + jj) * 32 + c];
#pragma unroll
      for (int n = 0; n < 4; ++n) {
        float a = ((const float*)&av[n])[jj];
        float xx = ((const float*)&xv[n])[jj];
        acc[n][0] += a * wlv.x + xx * wrv.x;
        acc[n][1] += a * wlv.y + xx * wrv.y;
        acc[n][2] += a * wlv.z + xx * wrv.z;
        acc[n][3] += a * wlv.w + xx * wrv.w;
      }
    }
  }
  const int o = c * 4;
  float4 bias = *(const float4*)&b1l[o];
  float4 gm = *(const float4*)&g1[o];
  float4 bt = *(const float4*)&be1[o];
  float4 mu = *(const float4*)&m1[o];
  float4 va = *(const float4*)&v1[o];
  float sc0 = gm.x * rsqrtf(va.x + EPSV), sh0 = bt.x - mu.x * sc0;
  float sc1 = gm.y * rsqrtf(va.y + EPSV), sh1 = bt.y - mu.y * sc1;
  float sc2 = gm.z * rsqrtf(va.z + EPSV), sh2 = bt.z - mu.z * sc2;
  float sc3 = gm.w * rsqrtf(va.w + EPSV), sh3 = bt.w - mu.w * sc3;
#pragma unroll
  for (int n = 0; n < 4; ++n) {
    float4 ov;
    ov.x = fmaxf((acc[n][0] + bias.x) * sc0 + sh0, 0.f);
    ov.y = fmaxf((acc[n][1] + bias.y) * sc1 + sh1, 0.f);
    ov.z = fmaxf((acc[n][2] + bias.z) * sc2 + sh2, 0.f);
    ov.w = fmaxf((acc[n][3] + bias.w) * sc3 + sh3, 0.f);
    *(float4*)&h[(size_t)(node0 + g * 4 + n) * 128 + o] = ov;
  }
}

// ---------------- layer2 dense: t = h@W2l.T ; r2 = h@W2r.T + b2l ----------------
__global__ __launch_bounds__(256) void k_gemm2(const float* __restrict__ h,
                                               const float* __restrict__ wt2l,
                                               const float* __restrict__ wt2r,
                                               const float* __restrict__ b2l,
                                               float* __restrict__ t,
                                               float* __restrict__ r2) {
  __shared__ float wl[128 * 64];  // [k][o]
  __shared__ float wr[128 * 64];
  const int tid = threadIdx.x;
  const int node0 = blockIdx.x * 32;
  for (int i = tid * 4; i < 8192; i += 1024) {
    *(float4*)&wl[i] = *(const float4*)&wt2l[i];
    *(float4*)&wr[i] = *(const float4*)&wt2r[i];
  }
  __syncthreads();
  const int c = tid & 31;        // c<16 -> t cols, c>=16 -> r2 cols
  const int g = tid >> 5;        // nodes g*4..g*4+3
  const bool isR = (c >= 16);
  const int c4 = c & 15;
  const float4* w4 = (const float4*)(isR ? wr : wl);  // [k][16]
  float acc[4][4];
#pragma unroll
  for (int n = 0; n < 4; ++n)
#pragma unroll
    for (int q = 0; q < 4; ++q) acc[n][q] = 0.f;
#pragma unroll 4
  for (int k4 = 0; k4 < 32; ++k4) {
    float4 av[4];
#pragma unroll
    for (int n = 0; n < 4; ++n)
      av[n] = *(const float4*)(h + (size_t)(node0 + g * 4 + n) * 128 + k4 * 4);
#pragma unroll
    for (int jj = 0; jj < 4; ++jj) {
      float4 wv = w4[(k4 * 4 + jj) * 16 + c4];
#pragma unroll
      for (int n = 0; n < 4; ++n) {
        float a = ((const float*)&av[n])[jj];
        acc[n][0] += a * wv.x;
        acc[n][1] += a * wv.y;
        acc[n][2] += a * wv.z;
        acc[n][3] += a * wv.w;
      }
    }
  }
  const int o = c4 * 4;
  if (!isR) {
#pragma unroll
    for (int n = 0; n < 4; ++n) {
      float4 ov;
      ov.x = acc[n][0]; ov.y = acc[n][1]; ov.z = acc[n][2]; ov.w = acc[n][3];
      *(float4*)&t[(size_t)(node0 + g * 4 + n) * 64 + o] = ov;
    }
  } else {
    float4 bias = *(const float4*)&b2l[o];
#pragma unroll
    for (int n = 0; n < 4; ++n) {
      float4 ov;
      ov.x = acc[n][0] + bias.x; ov.y = acc[n][1] + bias.y;
      ov.z = acc[n][2] + bias.z; ov.w = acc[n][3] + bias.w;
      *(float4*)&r2[(size_t)(node0 + g * 4 + n) * 64 + o] = ov;
    }
  }
}

// ---------------- layer2 aggregate + BN2 finish ----------------
__global__ __launch_bounds__(256) void k_agg2fin(const float* __restrict__ t,
                                                 const int* __restrict__ deg,
                                                 const int* __restrict__ offset,
                                                 const int* __restrict__ csr,
                                                 const float* __restrict__ r2,
                                                 const float* __restrict__ g2,
                                                 const float* __restrict__ be2,
                                                 const float* __restrict__ m2,
                                                 const float* __restrict__ v2,
                                                 float* __restrict__ outp) {
  int tid = threadIdx.x;
  int node = blockIdx.x * 16 + (tid >> 4);
  int j = tid & 15;
  int cnt = deg[node];
  const int* arow = csr + offset[node];
  float ax = 0.f, ay = 0.f, az = 0.f, aw = 0.f;
  int k = 0;
  for (; k + 4 <= cnt; k += 4) {
    int s0 = arow[k], s1 = arow[k + 1], s2 = arow[k + 2], s3 = arow[k + 3];
    float4 v0 = *(const float4*)(t + (size_t)s0 * 64 + j * 4);
    float4 v1 = *(const float4*)(t + (size_t)s1 * 64 + j * 4);
    float4 v2 = *(const float4*)(t + (size_t)s2 * 64 + j * 4);
    float4 v3 = *(const float4*)(t + (size_t)s3 * 64 + j * 4);
    ax += v0.x + v1.x + v2.x + v3.x;
    ay += v0.y + v1.y + v2.y + v3.y;
    az += v0.z + v1.z + v2.z + v3.z;
    aw += v0.w + v1.w + v2.w + v3.w;
  }
  for (; k < cnt; ++k) {
    int s = arow[k];
    float4 v = *(const float4*)(t + (size_t)s * 64 + j * 4);
    ax += v.x; ay += v.y; az += v.z; aw += v.w;
  }
  float inv = 1.0f / fmaxf((float)cnt, 1.0f);
  float4 r = *(const float4*)(r2 + (size_t)node * 64 + j * 4);
  float vx = ax * inv + r.x;
  float vy = ay * inv + r.y;
  float vz = az * inv + r.z;
  float vw = aw * inv + r.w;
  int o = j * 4;
  float4 gm = *(const float4*)&g2[o];
  float4 bt = *(const float4*)&be2[o];
  float4 mu = *(const float4*)&m2[o];
  float4 va = *(const float4*)&v2[o];
  float4 ov;
  ov.x = (vx - mu.x) * (gm.x * rsqrtf(va.x + EPSV)) + bt.x;
  ov.y = (vy - mu.y) * (gm.y * rsqrtf(va.y + EPSV)) + bt.y;
  ov.z = (vz - mu.z) * (gm.z * rsqrtf(va.z + EPSV)) + bt.z;
  ov.w = (vw - mu.w) * (gm.w * rsqrtf(va.w + EPSV)) + bt.w;
  *(float4*)(outp + (size_t)node * 64 + o) = ov;
}

extern "C" void kernel_launch(void* const* d_in, const int* in_sizes, int n_in,
                              void* d_out, int out_size, void* d_ws, size_t ws_size,
                              hipStream_t stream) {
  const float* x   = (const float*)d_in[0];
  const int*   ei  = (const int*)d_in[1];
  const float* w1l = (const float*)d_in[2];
  const float* b1l = (const float*)d_in[3];
  const float* w1r = (const float*)d_in[4];
  const float* g1  = (const float*)d_in[5];
  const float* be1 = (const float*)d_in[6];
  const float* m1  = (const float*)d_in[7];
  const float* v1  = (const float*)d_in[8];
  const float* w2l = (const float*)d_in[9];
  const float* b2l = (const float*)d_in[10];
  const float* w2r = (const float*)d_in[11];
  const float* g2  = (const float*)d_in[12];
  const float* be2 = (const float*)d_in[13];
  const float* m2  = (const float*)d_in[14];
  const float* v2  = (const float*)d_in[15];
  float* outp = (float*)d_out;

  char* ws = (char*)d_ws;
  // layout (bytes), 16B-aligned:
  //           0 : gcur       (1,024)   196 bucket cursors (padded)
  //       1,024 : bucketBase (1,024)
  //       2,048 : deg        (400,000)
  //     402,048 : offset     (400,000)
  //     802,048 : pairs      (7,225,344 = 196*9216*4)
  //   8,027,392 : csr        (6,400,000)
  //  14,427,392 : wt         (131,072)
  //  14,558,464 : agg1/r2    (25,600,000)
  //  40,158,464 : h          (51,200,000)
  //  91,358,464 : t          (25,600,000)   -> total ~117 MB
  int*      gcur       = (int*)ws;
  int*      bucketBase = (int*)(ws + 1024);
  int*      deg        = (int*)(ws + 2048);
  int*      offset     = (int*)(ws + 402048);
  unsigned* pairs      = (unsigned*)(ws + 802048);
  int*      csr        = (int*)(ws + 8027392);
  float*    wt         = (float*)(ws + 14427392);
  float*    agg1       = (float*)(ws + 14558464);
  float*    r2         = agg1;  // agg1 dead after k_gemm1; reuse for r2
  float*    h          = (float*)(ws + 40158464);
  float*    t          = (float*)(ws + 91358464);

  const int* srcp = ei;
  const int* dstp = ei + NE;

  hipMemsetAsync(gcur, 0, NBUK * sizeof(int), stream);
  hipLaunchKernelGGL(k_bin, dim3(NTIL), dim3(256), 0, stream,
                     srcp, dstp, gcur, pairs);
  hipLaunchKernelGGL(k_bscan, dim3(1), dim3(256), 0, stream, gcur, bucketBase);
  hipLaunchKernelGGL(k_build, dim3(NBUK), dim3(256), 0, stream,
                     pairs, gcur, bucketBase, deg, offset, csr);
  hipLaunchKernelGGL(k_transpose, dim3(32), dim3(256), 0, stream,
                     w1l, w1r, w2l, w2r, wt);
  hipLaunchKernelGGL(k_aggregate, dim3(NN / 16), dim3(256), 0, stream,
                     x, deg, offset, csr, agg1);
  hipLaunchKernelGGL(k_gemm1, dim3(NN / 32), dim3(256), 0, stream,
                     agg1, x, wt, wt + 8192, b1l, g1, be1, m1, v1, h);
  hipLaunchKernelGGL(k_gemm2, dim3(NN / 32), dim3(256), 0, stream,
                     h, wt + 16384, wt + 24576, b2l, t, r2);
  hipLaunchKernelGGL(k_agg2fin, dim3(NN / 16), dim3(256), 0, stream,
                     t, deg, offset, csr, r2, g2, be2, m2, v2, outp);
}

// Round 5
// 332.197 us; speedup vs baseline: 1.6327x; 1.0085x over previous
//
#include <hip/hip_runtime.h>

#define NN 100000
#define NE 1600000
#define EPSV 1e-5f

#define NBUK 196       // buckets of 512 nodes: bucket = dst >> 9
#define TILE 8192      // edges per k_bin workgroup
#define NTIL 196       // ceil(NE / TILE)
#define CAP  9216      // per-bucket capacity (mean 8163, std ~90 -> +11 sigma)

// ---------------- phase 1: LDS-binned edge partition ----------------
__global__ __launch_bounds__(256) void k_bin(const int* __restrict__ src,
                                             const int* __restrict__ dst,
                                             int* __restrict__ gcur,
                                             unsigned* __restrict__ pairs) {
  __shared__ int cnt[NBUK];
  __shared__ int lo[NBUK];
  __shared__ int gbase[NBUK];
  __shared__ int ts[256];
  __shared__ unsigned stage[TILE];
  const int tid = threadIdx.x;
  const int e0 = blockIdx.x * TILE;
  const int m = min(TILE, NE - e0);

  for (int i = tid; i < NBUK; i += 256) cnt[i] = 0;
  __syncthreads();
  for (int i = tid; i < m; i += 256) {
    int d = dst[e0 + i];
    atomicAdd(&cnt[d >> 9], 1);
  }
  __syncthreads();
  int c = (tid < NBUK) ? cnt[tid] : 0;
  ts[tid] = c;
  __syncthreads();
  for (int d = 1; d < 256; d <<= 1) {
    int v = (tid >= d) ? ts[tid - d] : 0;
    __syncthreads();
    ts[tid] += v;
    __syncthreads();
  }
  if (tid < NBUK) {
    int ex = ts[tid] - c;
    lo[tid] = ex;
    gbase[tid] = atomicAdd(&gcur[tid], c);
    cnt[tid] = ex;
  }
  __syncthreads();
  for (int i = tid; i < m; i += 256) {
    int d = dst[e0 + i];
    int s = src[e0 + i];
    int b = d >> 9;
    int pos = atomicAdd(&cnt[b], 1);
    stage[pos] = ((unsigned)(d & 511) << 17) | (unsigned)s;
  }
  __syncthreads();
  for (int i = tid; i < m; i += 256) {
    int a = 0, z = NBUK - 1;
    while (a < z) {
      int mid = (a + z + 1) >> 1;
      if (lo[mid] <= i) a = mid; else z = mid - 1;
    }
    int rel = gbase[a] + (i - lo[a]);
    if (rel < CAP) pairs[(size_t)a * CAP + rel] = stage[i];
  }
}

// ---------------- phase 1.5: scan bucket counts ----------------
__global__ __launch_bounds__(256) void k_bscan(const int* __restrict__ gcur,
                                               int* __restrict__ bucketBase) {
  __shared__ int ts[256];
  const int tid = threadIdx.x;
  int c = (tid < NBUK) ? min(gcur[tid], CAP) : 0;
  ts[tid] = c;
  __syncthreads();
  for (int d = 1; d < 256; d <<= 1) {
    int v = (tid >= d) ? ts[tid - d] : 0;
    __syncthreads();
    ts[tid] += v;
    __syncthreads();
  }
  if (tid < NBUK) bucketBase[tid] = ts[tid] - c;
}

// ---------------- phase 2: per-bucket CSR build ----------------
__global__ __launch_bounds__(256) void k_build(const unsigned* __restrict__ pairs,
                                               const int* __restrict__ gcur,
                                               const int* __restrict__ bucketBase,
                                               int* __restrict__ deg,
                                               int* __restrict__ offset,
                                               int* __restrict__ csr) {
  __shared__ int hist[512];
  __shared__ int lofs[512];
  __shared__ int ts[256];
  __shared__ unsigned stage[CAP];
  const int tid = threadIdx.x;
  const int b = blockIdx.x;
  const int count = min(gcur[b], CAP);
  const int nbase = b * 512;
  const int nloc = min(512, NN - nbase);
  const unsigned* pb = pairs + (size_t)b * CAP;
  const int obase = bucketBase[b];

  hist[tid] = 0; hist[tid + 256] = 0;
  __syncthreads();
  for (int i = tid; i < count; i += 256) {
    atomicAdd(&hist[pb[i] >> 17], 1);
  }
  __syncthreads();
  int v0 = hist[2 * tid], v1 = hist[2 * tid + 1];
  int s = v0 + v1;
  ts[tid] = s;
  __syncthreads();
  for (int d = 1; d < 256; d <<= 1) {
    int v = (tid >= d) ? ts[tid - d] : 0;
    __syncthreads();
    ts[tid] += v;
    __syncthreads();
  }
  int ex = ts[tid] - s;
  lofs[2 * tid] = ex;
  lofs[2 * tid + 1] = ex + v0;
  __syncthreads();
  for (int n = tid; n < nloc; n += 256) {
    deg[nbase + n] = hist[n];
    offset[nbase + n] = obase + lofs[n];
  }
  __syncthreads();
  hist[2 * tid] = lofs[2 * tid];
  hist[2 * tid + 1] = lofs[2 * tid + 1];
  __syncthreads();
  for (int i = tid; i < count; i += 256) {
    unsigned e = pb[i];
    int pos = atomicAdd(&hist[e >> 17], 1);
    stage[pos] = e & 0x1FFFFu;
  }
  __syncthreads();
  for (int i = tid; i < count; i += 256) csr[obase + i] = (int)stage[i];
}

// ---------------- transpose weights to [k][o] ----------------
__global__ __launch_bounds__(256) void k_transpose(const float* __restrict__ w1l,
                                                   const float* __restrict__ w1r,
                                                   const float* __restrict__ w2l,
                                                   const float* __restrict__ w2r,
                                                   float* __restrict__ wt) {
  int idx = blockIdx.x * 256 + threadIdx.x;  // 0..8191
  int o1 = idx >> 6, k1 = idx & 63;          // w1: [128][64] -> [64][128]
  wt[k1 * 128 + o1] = w1l[idx];
  wt[8192 + k1 * 128 + o1] = w1r[idx];
  int o2 = idx >> 7, k2 = idx & 127;         // w2: [64][128] -> [128][64]
  wt[16384 + k2 * 64 + o2] = w2l[idx];
  wt[24576 + k2 * 64 + o2] = w2r[idx];
}

// ---------------- mean-aggregate 64-dim rows over CSR ----------------
__global__ __launch_bounds__(256) void k_aggregate(const float* __restrict__ feat,
                                                   const int* __restrict__ deg,
                                                   const int* __restrict__ offset,
                                                   const int* __restrict__ csr,
                                                   float* __restrict__ outb) {
  int tid = threadIdx.x;
  int node = blockIdx.x * 16 + (tid >> 4);
  int j = tid & 15;
  int cnt = deg[node];
  const int* arow = csr + offset[node];
  float ax = 0.f, ay = 0.f, az = 0.f, aw = 0.f;
  int k = 0;
  for (; k + 4 <= cnt; k += 4) {
    int s0 = arow[k], s1 = arow[k + 1], s2 = arow[k + 2], s3 = arow[k + 3];
    float4 v0 = *(const float4*)(feat + (size_t)s0 * 64 + j * 4);
    float4 v1 = *(const float4*)(feat + (size_t)s1 * 64 + j * 4);
    float4 v2 = *(const float4*)(feat + (size_t)s2 * 64 + j * 4);
    float4 v3 = *(const float4*)(feat + (size_t)s3 * 64 + j * 4);
    ax += v0.x + v1.x + v2.x + v3.x;
    ay += v0.y + v1.y + v2.y + v3.y;
    az += v0.z + v1.z + v2.z + v3.z;
    aw += v0.w + v1.w + v2.w + v3.w;
  }
  for (; k < cnt; ++k) {
    int s = arow[k];
    float4 v = *(const float4*)(feat + (size_t)s * 64 + j * 4);
    ax += v.x; ay += v.y; az += v.z; aw += v.w;
  }
  float inv = 1.0f / fmaxf((float)cnt, 1.0f);
  float4 r;
  r.x = ax * inv; r.y = ay * inv; r.z = az * inv; r.w = aw * inv;
  *(float4*)(outb + (size_t)node * 64 + j * 4) = r;
}

// ---------------- layer1 dense: h = relu(bn1(agg1@W1l.T + x@W1r.T + b1l)) ----------------
// grid (ceil(NN/64), 2): blockIdx.y = output-column half. 32KB LDS -> 5 blocks/CU.
__global__ __launch_bounds__(256) void k_gemm1(const float* __restrict__ agg1,
                                               const float* __restrict__ x,
                                               const float* __restrict__ wt1l,
                                               const float* __restrict__ wt1r,
                                               const float* __restrict__ b1l,
                                               const float* __restrict__ g1,
                                               const float* __restrict__ be1,
                                               const float* __restrict__ m1,
                                               const float* __restrict__ v1,
                                               float* __restrict__ h) {
  __shared__ float wl[64 * 64];  // [k][o-half]
  __shared__ float wr[64 * 64];
  const int tid = threadIdx.x;
  const int node0 = blockIdx.x * 64;
  const int cbase = blockIdx.y * 64;
  for (int i = tid * 4; i < 4096; i += 1024) {
    int row = i >> 6, col = i & 63;
    *(float4*)&wl[i] = *(const float4*)&wt1l[row * 128 + cbase + col];
    *(float4*)&wr[i] = *(const float4*)&wt1r[row * 128 + cbase + col];
  }
  __syncthreads();
  const int c = tid & 15;   // float4 col within half (64 outs)
  const int g = tid >> 4;   // 16 groups x 4 nodes
  const float4* wl4 = (const float4*)wl;  // [k][16]
  const float4* wr4 = (const float4*)wr;
  int nd[4];
#pragma unroll
  for (int n = 0; n < 4; ++n) nd[n] = min(node0 + g * 4 + n, NN - 1);
  float acc[4][4];
#pragma unroll
  for (int n = 0; n < 4; ++n)
#pragma unroll
    for (int q = 0; q < 4; ++q) acc[n][q] = 0.f;
#pragma unroll 4
  for (int k4 = 0; k4 < 16; ++k4) {
    float4 av[4], xv[4];
#pragma unroll
    for (int n = 0; n < 4; ++n) {
      av[n] = *(const float4*)(agg1 + (size_t)nd[n] * 64 + k4 * 4);
      xv[n] = *(const float4*)(x + (size_t)nd[n] * 64 + k4 * 4);
    }
#pragma unroll
    for (int jj = 0; jj < 4; ++jj) {
      float4 wlv = wl4[(k4 * 4 + jj) * 16 + c];
      float4 wrv = wr4[(k4 * 4 + jj) * 16 + c];
#pragma unroll
      for (int n = 0; n < 4; ++n) {
        float a = ((const float*)&av[n])[jj];
        float xx = ((const float*)&xv[n])[jj];
        acc[n][0] += a * wlv.x + xx * wrv.x;
        acc[n][1] += a * wlv.y + xx * wrv.y;
        acc[n][2] += a * wlv.z + xx * wrv.z;
        acc[n][3] += a * wlv.w + xx * wrv.w;
      }
    }
  }
  const int o = cbase + c * 4;
  float4 bias = *(const float4*)&b1l[o];
  float4 gm = *(const float4*)&g1[o];
  float4 bt = *(const float4*)&be1[o];
  float4 mu = *(const float4*)&m1[o];
  float4 va = *(const float4*)&v1[o];
  float sc0 = gm.x * rsqrtf(va.x + EPSV), sh0 = bt.x - mu.x * sc0;
  float sc1 = gm.y * rsqrtf(va.y + EPSV), sh1 = bt.y - mu.y * sc1;
  float sc2 = gm.z * rsqrtf(va.z + EPSV), sh2 = bt.z - mu.z * sc2;
  float sc3 = gm.w * rsqrtf(va.w + EPSV), sh3 = bt.w - mu.w * sc3;
#pragma unroll
  for (int n = 0; n < 4; ++n) {
    int node = node0 + g * 4 + n;
    if (node < NN) {
      float4 ov;
      ov.x = fmaxf((acc[n][0] + bias.x) * sc0 + sh0, 0.f);
      ov.y = fmaxf((acc[n][1] + bias.y) * sc1 + sh1, 0.f);
      ov.z = fmaxf((acc[n][2] + bias.z) * sc2 + sh2, 0.f);
      ov.w = fmaxf((acc[n][3] + bias.w) * sc3 + sh3, 0.f);
      *(float4*)&h[(size_t)node * 128 + o] = ov;
    }
  }
}

// ---------------- layer2 dense: y=0: t = h@W2l.T ; y=1: r2 = h@W2r.T + b2l ----------------
// grid (ceil(NN/64), 2): blockIdx.y = which matrix. 32KB LDS -> 5 blocks/CU.
__global__ __launch_bounds__(256) void k_gemm2(const float* __restrict__ h,
                                               const float* __restrict__ wt2l,
                                               const float* __restrict__ wt2r,
                                               const float* __restrict__ b2l,
                                               float* __restrict__ t,
                                               float* __restrict__ r2) {
  __shared__ float wsm[128 * 64];  // [k][o]
  const int tid = threadIdx.x;
  const int node0 = blockIdx.x * 64;
  const int isR = blockIdx.y;
  const float* wsrc = isR ? wt2r : wt2l;
  for (int i = tid * 4; i < 8192; i += 1024)
    *(float4*)&wsm[i] = *(const float4*)&wsrc[i];
  __syncthreads();
  const int c = tid & 15;  // float4 col (64 outs)
  const int g = tid >> 4;  // 16 groups x 4 nodes
  const float4* w4 = (const float4*)wsm;  // [k][16]
  int nd[4];
#pragma unroll
  for (int n = 0; n < 4; ++n) nd[n] = min(node0 + g * 4 + n, NN - 1);
  float acc[4][4];
#pragma unroll
  for (int n = 0; n < 4; ++n)
#pragma unroll
    for (int q = 0; q < 4; ++q) acc[n][q] = 0.f;
#pragma unroll 4
  for (int k4 = 0; k4 < 32; ++k4) {
    float4 av[4];
#pragma unroll
    for (int n = 0; n < 4; ++n)
      av[n] = *(const float4*)(h + (size_t)nd[n] * 128 + k4 * 4);
#pragma unroll
    for (int jj = 0; jj < 4; ++jj) {
      float4 wv = w4[(k4 * 4 + jj) * 16 + c];
#pragma unroll
      for (int n = 0; n < 4; ++n) {
        float a = ((const float*)&av[n])[jj];
        acc[n][0] += a * wv.x;
        acc[n][1] += a * wv.y;
        acc[n][2] += a * wv.z;
        acc[n][3] += a * wv.w;
      }
    }
  }
  const int o = c * 4;
  if (!isR) {
#pragma unroll
    for (int n = 0; n < 4; ++n) {
      int node = node0 + g * 4 + n;
      if (node < NN) {
        float4 ov;
        ov.x = acc[n][0]; ov.y = acc[n][1]; ov.z = acc[n][2]; ov.w = acc[n][3];
        *(float4*)&t[(size_t)node * 64 + o] = ov;
      }
    }
  } else {
    float4 bias = *(const float4*)&b2l[o];
#pragma unroll
    for (int n = 0; n < 4; ++n) {
      int node = node0 + g * 4 + n;
      if (node < NN) {
        float4 ov;
        ov.x = acc[n][0] + bias.x; ov.y = acc[n][1] + bias.y;
        ov.z = acc[n][2] + bias.z; ov.w = acc[n][3] + bias.w;
        *(float4*)&r2[(size_t)node * 64 + o] = ov;
      }
    }
  }
}

// ---------------- layer2 aggregate + BN2 finish ----------------
__global__ __launch_bounds__(256) void k_agg2fin(const float* __restrict__ t,
                                                 const int* __restrict__ deg,
                                                 const int* __restrict__ offset,
                                                 const int* __restrict__ csr,
                                                 const float* __restrict__ r2,
                                                 const float* __restrict__ g2,
                                                 const float* __restrict__ be2,
                                                 const float* __restrict__ m2,
                                                 const float* __restrict__ v2,
                                                 float* __restrict__ outp) {
  int tid = threadIdx.x;
  int node = blockIdx.x * 16 + (tid >> 4);
  int j = tid & 15;
  int cnt = deg[node];
  const int* arow = csr + offset[node];
  float ax = 0.f, ay = 0.f, az = 0.f, aw = 0.f;
  int k = 0;
  for (; k + 4 <= cnt; k += 4) {
    int s0 = arow[k], s1 = arow[k + 1], s2 = arow[k + 2], s3 = arow[k + 3];
    float4 v0 = *(const float4*)(t + (size_t)s0 * 64 + j * 4);
    float4 v1 = *(const float4*)(t + (size_t)s1 * 64 + j * 4);
    float4 v2 = *(const float4*)(t + (size_t)s2 * 64 + j * 4);
    float4 v3 = *(const float4*)(t + (size_t)s3 * 64 + j * 4);
    ax += v0.x + v1.x + v2.x + v3.x;
    ay += v0.y + v1.y + v2.y + v3.y;
    az += v0.z + v1.z + v2.z + v3.z;
    aw += v0.w + v1.w + v2.w + v3.w;
  }
  for (; k < cnt; ++k) {
    int s = arow[k];
    float4 v = *(const float4*)(t + (size_t)s * 64 + j * 4);
    ax += v.x; ay += v.y; az += v.z; aw += v.w;
  }
  float inv = 1.0f / fmaxf((float)cnt, 1.0f);
  float4 r = *(const float4*)(r2 + (size_t)node * 64 + j * 4);
  float vx = ax * inv + r.x;
  float vy = ay * inv + r.y;
  float vz = az * inv + r.z;
  float vw = aw * inv + r.w;
  int o = j * 4;
  float4 gm = *(const float4*)&g2[o];
  float4 bt = *(const float4*)&be2[o];
  float4 mu = *(const float4*)&m2[o];
  float4 va = *(const float4*)&v2[o];
  float4 ov;
  ov.x = (vx - mu.x) * (gm.x * rsqrtf(va.x + EPSV)) + bt.x;
  ov.y = (vy - mu.y) * (gm.y * rsqrtf(va.y + EPSV)) + bt.y;
  ov.z = (vz - mu.z) * (gm.z * rsqrtf(va.z + EPSV)) + bt.z;
  ov.w = (vw - mu.w) * (gm.w * rsqrtf(va.w + EPSV)) + bt.w;
  *(float4*)(outp + (size_t)node * 64 + o) = ov;
}

extern "C" void kernel_launch(void* const* d_in, const int* in_sizes, int n_in,
                              void* d_out, int out_size, void* d_ws, size_t ws_size,
                              hipStream_t stream) {
  const float* x   = (const float*)d_in[0];
  const int*   ei  = (const int*)d_in[1];
  const float* w1l = (const float*)d_in[2];
  const float* b1l = (const float*)d_in[3];
  const float* w1r = (const float*)d_in[4];
  const float* g1  = (const float*)d_in[5];
  const float* be1 = (const float*)d_in[6];
  const float* m1  = (const float*)d_in[7];
  const float* v1  = (const float*)d_in[8];
  const float* w2l = (const float*)d_in[9];
  const float* b2l = (const float*)d_in[10];
  const float* w2r = (const float*)d_in[11];
  const float* g2  = (const float*)d_in[12];
  const float* be2 = (const float*)d_in[13];
  const float* m2  = (const float*)d_in[14];
  const float* v2  = (const float*)d_in[15];
  float* outp = (float*)d_out;

  char* ws = (char*)d_ws;
  // layout (bytes), 16B-aligned:
  //           0 : gcur       (1,024)
  //       1,024 : bucketBase (1,024)
  //       2,048 : deg        (400,000)
  //     402,048 : offset     (400,000)
  //     802,048 : pairs      (7,225,344 = 196*9216*4)
  //   8,027,392 : csr        (6,400,000)
  //  14,427,392 : wt         (131,072)
  //  14,558,464 : agg1/r2    (25,600,000)
  //  40,158,464 : h          (51,200,000)
  //  91,358,464 : t          (25,600,000)   -> total ~117 MB
  int*      gcur       = (int*)ws;
  int*      bucketBase = (int*)(ws + 1024);
  int*      deg        = (int*)(ws + 2048);
  int*      offset     = (int*)(ws + 402048);
  unsigned* pairs      = (unsigned*)(ws + 802048);
  int*      csr        = (int*)(ws + 8027392);
  float*    wt         = (float*)(ws + 14427392);
  float*    agg1       = (float*)(ws + 14558464);
  float*    r2         = agg1;  // agg1 dead after k_gemm1; reuse for r2
  float*    h          = (float*)(ws + 40158464);
  float*    t          = (float*)(ws + 91358464);

  const int* srcp = ei;
  const int* dstp = ei + NE;

  hipMemsetAsync(gcur, 0, NBUK * sizeof(int), stream);
  hipLaunchKernelGGL(k_bin, dim3(NTIL), dim3(256), 0, stream,
                     srcp, dstp, gcur, pairs);
  hipLaunchKernelGGL(k_bscan, dim3(1), dim3(256), 0, stream, gcur, bucketBase);
  hipLaunchKernelGGL(k_build, dim3(NBUK), dim3(256), 0, stream,
                     pairs, gcur, bucketBase, deg, offset, csr);
  hipLaunchKernelGGL(k_transpose, dim3(32), dim3(256), 0, stream,
                     w1l, w1r, w2l, w2r, wt);
  hipLaunchKernelGGL(k_aggregate, dim3(NN / 16), dim3(256), 0, stream,
                     x, deg, offset, csr, agg1);
  hipLaunchKernelGGL(k_gemm1, dim3((NN + 63) / 64, 2), dim3(256), 0, stream,
                     agg1, x, wt, wt + 8192, b1l, g1, be1, m1, v1, h);
  hipLaunchKernelGGL(k_gemm2, dim3((NN + 63) / 64, 2), dim3(256), 0, stream,
                     h, wt + 16384, wt + 24576, b2l, t, r2);
  hipLaunchKernelGGL(k_agg2fin, dim3(NN / 16), dim3(256), 0, stream,
                     t, deg, offset, csr, r2, g2, be2, m2, v2, outp);
}

// Round 6
// 227.793 us; speedup vs baseline: 2.3811x; 1.4583x over previous
//
#include <hip/hip_runtime.h>

#define NN 100000
#define NE 1600000
#define EPSV 1e-5f

#define NBUK 196       // buckets of 512 nodes: bucket = dst >> 9
#define TILE 8192      // edges per k_bin workgroup
#define NTIL 196       // ceil(NE / TILE)
#define CAP  9216      // per-bucket capacity (mean 8163, std ~90 -> +11 sigma)

typedef __attribute__((ext_vector_type(8))) short bf16x8;
typedef __attribute__((ext_vector_type(4))) float f32x4;

__device__ inline unsigned short f2bf(float f) {
  unsigned u = __builtin_bit_cast(unsigned, f);
  unsigned r = u + 0x7FFFu + ((u >> 16) & 1u);
  return (unsigned short)(r >> 16);
}
__device__ inline float bf2f(unsigned short s) {
  unsigned u = ((unsigned)s) << 16;
  return __builtin_bit_cast(float, u);
}

// ---------------- phase 1: LDS-binned edge partition ----------------
__global__ __launch_bounds__(256) void k_bin(const int* __restrict__ src,
                                             const int* __restrict__ dst,
                                             int* __restrict__ gcur,
                                             unsigned* __restrict__ pairs) {
  __shared__ int cnt[NBUK];
  __shared__ int lo[NBUK];
  __shared__ int gbase[NBUK];
  __shared__ int ts[256];
  __shared__ unsigned stage[TILE];
  const int tid = threadIdx.x;
  const int e0 = blockIdx.x * TILE;
  const int m = min(TILE, NE - e0);

  for (int i = tid; i < NBUK; i += 256) cnt[i] = 0;
  __syncthreads();
  for (int i = tid; i < m; i += 256) {
    int d = dst[e0 + i];
    atomicAdd(&cnt[d >> 9], 1);
  }
  __syncthreads();
  int c = (tid < NBUK) ? cnt[tid] : 0;
  ts[tid] = c;
  __syncthreads();
  for (int d = 1; d < 256; d <<= 1) {
    int v = (tid >= d) ? ts[tid - d] : 0;
    __syncthreads();
    ts[tid] += v;
    __syncthreads();
  }
  if (tid < NBUK) {
    int ex = ts[tid] - c;
    lo[tid] = ex;
    gbase[tid] = atomicAdd(&gcur[tid], c);
    cnt[tid] = ex;
  }
  __syncthreads();
  for (int i = tid; i < m; i += 256) {
    int d = dst[e0 + i];
    int s = src[e0 + i];
    int b = d >> 9;
    int pos = atomicAdd(&cnt[b], 1);
    stage[pos] = ((unsigned)(d & 511) << 17) | (unsigned)s;
  }
  __syncthreads();
  for (int i = tid; i < m; i += 256) {
    int a = 0, z = NBUK - 1;
    while (a < z) {
      int mid = (a + z + 1) >> 1;
      if (lo[mid] <= i) a = mid; else z = mid - 1;
    }
    int rel = gbase[a] + (i - lo[a]);
    if (rel < CAP) pairs[(size_t)a * CAP + rel] = stage[i];
  }
}

// ---------------- phase 1.5: scan bucket counts ----------------
__global__ __launch_bounds__(256) void k_bscan(const int* __restrict__ gcur,
                                               int* __restrict__ bucketBase) {
  __shared__ int ts[256];
  const int tid = threadIdx.x;
  int c = (tid < NBUK) ? min(gcur[tid], CAP) : 0;
  ts[tid] = c;
  __syncthreads();
  for (int d = 1; d < 256; d <<= 1) {
    int v = (tid >= d) ? ts[tid - d] : 0;
    __syncthreads();
    ts[tid] += v;
    __syncthreads();
  }
  if (tid < NBUK) bucketBase[tid] = ts[tid] - c;
}

// ---------------- phase 2: per-bucket CSR build ----------------
__global__ __launch_bounds__(256) void k_build(const unsigned* __restrict__ pairs,
                                               const int* __restrict__ gcur,
                                               const int* __restrict__ bucketBase,
                                               int* __restrict__ deg,
                                               int* __restrict__ offset,
                                               int* __restrict__ csr) {
  __shared__ int hist[512];
  __shared__ int lofs[512];
  __shared__ int ts[256];
  __shared__ unsigned stage[CAP];
  const int tid = threadIdx.x;
  const int b = blockIdx.x;
  const int count = min(gcur[b], CAP);
  const int nbase = b * 512;
  const int nloc = min(512, NN - nbase);
  const unsigned* pb = pairs + (size_t)b * CAP;
  const int obase = bucketBase[b];

  hist[tid] = 0; hist[tid + 256] = 0;
  __syncthreads();
  for (int i = tid; i < count; i += 256) {
    atomicAdd(&hist[pb[i] >> 17], 1);
  }
  __syncthreads();
  int v0 = hist[2 * tid], v1 = hist[2 * tid + 1];
  int s = v0 + v1;
  ts[tid] = s;
  __syncthreads();
  for (int d = 1; d < 256; d <<= 1) {
    int v = (tid >= d) ? ts[tid - d] : 0;
    __syncthreads();
    ts[tid] += v;
    __syncthreads();
  }
  int ex = ts[tid] - s;
  lofs[2 * tid] = ex;
  lofs[2 * tid + 1] = ex + v0;
  __syncthreads();
  for (int n = tid; n < nloc; n += 256) {
    deg[nbase + n] = hist[n];
    offset[nbase + n] = obase + lofs[n];
  }
  __syncthreads();
  hist[2 * tid] = lofs[2 * tid];
  hist[2 * tid + 1] = lofs[2 * tid + 1];
  __syncthreads();
  for (int i = tid; i < count; i += 256) {
    unsigned e = pb[i];
    int pos = atomicAdd(&hist[e >> 17], 1);
    stage[pos] = e & 0x1FFFFu;
  }
  __syncthreads();
  for (int i = tid; i < count; i += 256) csr[obase + i] = (int)stage[i];
}

// ---------------- weight prep: bf16 combined [o=128][k=128] row-major ----------------
// W1c[o][k] = k<64 ? w1l[o][k] : w1r[o][k-64]      (gemm1: k 0-63 agg, 64-127 x)
// W2c[o][k] = o<64 ? w2l[o][k] : w2r[o-64][k]      (gemm2: o 0-63 -> t, 64-127 -> r2)
__global__ __launch_bounds__(256) void k_wprep(const float* __restrict__ w1l,
                                               const float* __restrict__ w1r,
                                               const float* __restrict__ w2l,
                                               const float* __restrict__ w2r,
                                               unsigned short* __restrict__ w1c,
                                               unsigned short* __restrict__ w2c) {
  int i = blockIdx.x * 256 + threadIdx.x;  // 0..16383
  int o = i >> 7, k = i & 127;
  float v1 = (k < 64) ? w1l[o * 64 + k] : w1r[o * 64 + (k - 64)];
  w1c[i] = f2bf(v1);
  float v2 = (o < 64) ? w2l[o * 128 + k] : w2r[(o - 64) * 128 + k];
  w2c[i] = f2bf(v2);
}

// ---------------- convert x -> bf16 ----------------
__global__ __launch_bounds__(256) void k_cvtx(const float* __restrict__ x,
                                              unsigned short* __restrict__ xb) {
  int i = blockIdx.x * 256 + threadIdx.x;  // 1.6M threads, 4 elems each
  float4 v = *(const float4*)(x + (size_t)i * 4);
  ushort4 o;
  o.x = f2bf(v.x); o.y = f2bf(v.y); o.z = f2bf(v.z); o.w = f2bf(v.w);
  *(ushort4*)(xb + (size_t)i * 4) = o;
}

// ---------------- mean-aggregate bf16 rows over CSR -> bf16 out ----------------
// 16 lanes/node, 4 bf16 (8B) per lane
__global__ __launch_bounds__(256) void k_aggregate(const unsigned short* __restrict__ xb,
                                                   const int* __restrict__ deg,
                                                   const int* __restrict__ offset,
                                                   const int* __restrict__ csr,
                                                   unsigned short* __restrict__ aggB) {
  int tid = threadIdx.x;
  int node = blockIdx.x * 16 + (tid >> 4);
  int j = tid & 15;
  int cnt = deg[node];
  const int* arow = csr + offset[node];
  float a0 = 0.f, a1 = 0.f, a2 = 0.f, a3 = 0.f;
  int k = 0;
  for (; k + 4 <= cnt; k += 4) {
    int s0 = arow[k], s1 = arow[k + 1], s2 = arow[k + 2], s3 = arow[k + 3];
    uint2 v0 = *(const uint2*)(xb + (size_t)s0 * 64 + j * 4);
    uint2 v1 = *(const uint2*)(xb + (size_t)s1 * 64 + j * 4);
    uint2 v2 = *(const uint2*)(xb + (size_t)s2 * 64 + j * 4);
    uint2 v3 = *(const uint2*)(xb + (size_t)s3 * 64 + j * 4);
    a0 += bf2f(v0.x & 0xffff) + bf2f(v1.x & 0xffff) + bf2f(v2.x & 0xffff) + bf2f(v3.x & 0xffff);
    a1 += bf2f(v0.x >> 16)    + bf2f(v1.x >> 16)    + bf2f(v2.x >> 16)    + bf2f(v3.x >> 16);
    a2 += bf2f(v0.y & 0xffff) + bf2f(v1.y & 0xffff) + bf2f(v2.y & 0xffff) + bf2f(v3.y & 0xffff);
    a3 += bf2f(v0.y >> 16)    + bf2f(v1.y >> 16)    + bf2f(v2.y >> 16)    + bf2f(v3.y >> 16);
  }
  for (; k < cnt; ++k) {
    int s = arow[k];
    uint2 v = *(const uint2*)(xb + (size_t)s * 64 + j * 4);
    a0 += bf2f(v.x & 0xffff); a1 += bf2f(v.x >> 16);
    a2 += bf2f(v.y & 0xffff); a3 += bf2f(v.y >> 16);
  }
  float inv = 1.0f / fmaxf((float)cnt, 1.0f);
  ushort4 r;
  r.x = f2bf(a0 * inv); r.y = f2bf(a1 * inv);
  r.z = f2bf(a2 * inv); r.w = f2bf(a3 * inv);
  *(ushort4*)(aggB + (size_t)node * 64 + j * 4) = r;
}

// ---------------- layer1 MFMA: h = relu(bn1([aggB|xb] @ W1c.T + b1l)) ----------------
// 4 waves/block, each wave: 16 nodes x 128 outs. A-op = weights, B-op = acts -> D = C^T.
__global__ __launch_bounds__(256) void k_gemm1(const unsigned short* __restrict__ aggB,
                                               const unsigned short* __restrict__ xb,
                                               const unsigned short* __restrict__ w1c,
                                               const float* __restrict__ b1l,
                                               const float* __restrict__ g1,
                                               const float* __restrict__ be1,
                                               const float* __restrict__ m1,
                                               const float* __restrict__ v1,
                                               unsigned short* __restrict__ h) {
  const int tid = threadIdx.x;
  const int lane = tid & 63;
  const int n0 = (blockIdx.x * 4 + (tid >> 6)) * 16;
  if (n0 >= NN) return;
  const int lr = lane & 15;
  const int q = lane >> 4;
  const int node = n0 + lr;
  bf16x8 bfr[4];
  const unsigned short* ar = aggB + (size_t)node * 64 + q * 8;
  const unsigned short* xr = xb + (size_t)node * 64 + q * 8;
  bfr[0] = *(const bf16x8*)(ar);
  bfr[1] = *(const bf16x8*)(ar + 32);
  bfr[2] = *(const bf16x8*)(xr);
  bfr[3] = *(const bf16x8*)(xr + 32);
#pragma unroll
  for (int ot = 0; ot < 8; ++ot) {
    const unsigned short* wr = w1c + (size_t)(ot * 16 + lr) * 128 + q * 8;
    f32x4 acc = {0.f, 0.f, 0.f, 0.f};
    acc = __builtin_amdgcn_mfma_f32_16x16x32_bf16(*(const bf16x8*)(wr), bfr[0], acc, 0, 0, 0);
    acc = __builtin_amdgcn_mfma_f32_16x16x32_bf16(*(const bf16x8*)(wr + 32), bfr[1], acc, 0, 0, 0);
    acc = __builtin_amdgcn_mfma_f32_16x16x32_bf16(*(const bf16x8*)(wr + 64), bfr[2], acc, 0, 0, 0);
    acc = __builtin_amdgcn_mfma_f32_16x16x32_bf16(*(const bf16x8*)(wr + 96), bfr[3], acc, 0, 0, 0);
    const int o = ot * 16 + q * 4;
    float4 bias = *(const float4*)(b1l + o);
    float4 gm = *(const float4*)(g1 + o);
    float4 bt = *(const float4*)(be1 + o);
    float4 mu = *(const float4*)(m1 + o);
    float4 va = *(const float4*)(v1 + o);
    float sc0 = gm.x * rsqrtf(va.x + EPSV), sh0 = bt.x - mu.x * sc0;
    float sc1 = gm.y * rsqrtf(va.y + EPSV), sh1 = bt.y - mu.y * sc1;
    float sc2 = gm.z * rsqrtf(va.z + EPSV), sh2 = bt.z - mu.z * sc2;
    float sc3 = gm.w * rsqrtf(va.w + EPSV), sh3 = bt.w - mu.w * sc3;
    ushort4 hv;
    hv.x = f2bf(fmaxf((acc[0] + bias.x) * sc0 + sh0, 0.f));
    hv.y = f2bf(fmaxf((acc[1] + bias.y) * sc1 + sh1, 0.f));
    hv.z = f2bf(fmaxf((acc[2] + bias.z) * sc2 + sh2, 0.f));
    hv.w = f2bf(fmaxf((acc[3] + bias.w) * sc3 + sh3, 0.f));
    *(ushort4*)(h + (size_t)node * 128 + o) = hv;
  }
}

// ---------------- layer2 MFMA: t = h@W2l.T (bf16) ; r2 = h@W2r.T + b2l (fp32) ----------------
__global__ __launch_bounds__(256) void k_gemm2(const unsigned short* __restrict__ h,
                                               const unsigned short* __restrict__ w2c,
                                               const float* __restrict__ b2l,
                                               unsigned short* __restrict__ t,
                                               float* __restrict__ r2) {
  const int tid = threadIdx.x;
  const int lane = tid & 63;
  const int n0 = (blockIdx.x * 4 + (tid >> 6)) * 16;
  if (n0 >= NN) return;
  const int lr = lane & 15;
  const int q = lane >> 4;
  const int node = n0 + lr;
  const unsigned short* hr = h + (size_t)node * 128 + q * 8;
  bf16x8 bfr[4];
  bfr[0] = *(const bf16x8*)(hr);
  bfr[1] = *(const bf16x8*)(hr + 32);
  bfr[2] = *(const bf16x8*)(hr + 64);
  bfr[3] = *(const bf16x8*)(hr + 96);
#pragma unroll
  for (int ot = 0; ot < 8; ++ot) {
    const unsigned short* wr = w2c + (size_t)(ot * 16 + lr) * 128 + q * 8;
    f32x4 acc = {0.f, 0.f, 0.f, 0.f};
    acc = __builtin_amdgcn_mfma_f32_16x16x32_bf16(*(const bf16x8*)(wr), bfr[0], acc, 0, 0, 0);
    acc = __builtin_amdgcn_mfma_f32_16x16x32_bf16(*(const bf16x8*)(wr + 32), bfr[1], acc, 0, 0, 0);
    acc = __builtin_amdgcn_mfma_f32_16x16x32_bf16(*(const bf16x8*)(wr + 64), bfr[2], acc, 0, 0, 0);
    acc = __builtin_amdgcn_mfma_f32_16x16x32_bf16(*(const bf16x8*)(wr + 96), bfr[3], acc, 0, 0, 0);
    if (ot < 4) {
      const int o = ot * 16 + q * 4;
      ushort4 tv;
      tv.x = f2bf(acc[0]); tv.y = f2bf(acc[1]);
      tv.z = f2bf(acc[2]); tv.w = f2bf(acc[3]);
      *(ushort4*)(t + (size_t)node * 64 + o) = tv;
    } else {
      const int o = (ot - 4) * 16 + q * 4;
      float4 bias = *(const float4*)(b2l + o);
      float4 rv;
      rv.x = acc[0] + bias.x; rv.y = acc[1] + bias.y;
      rv.z = acc[2] + bias.z; rv.w = acc[3] + bias.w;
      *(float4*)(r2 + (size_t)node * 64 + o) = rv;
    }
  }
}

// ---------------- layer2 aggregate (bf16 t) + BN2 finish ----------------
__global__ __launch_bounds__(256) void k_agg2fin(const unsigned short* __restrict__ t,
                                                 const int* __restrict__ deg,
                                                 const int* __restrict__ offset,
                                                 const int* __restrict__ csr,
                                                 const float* __restrict__ r2,
                                                 const float* __restrict__ g2,
                                                 const float* __restrict__ be2,
                                                 const float* __restrict__ m2,
                                                 const float* __restrict__ v2,
                                                 float* __restrict__ outp) {
  int tid = threadIdx.x;
  int node = blockIdx.x * 16 + (tid >> 4);
  int j = tid & 15;
  int cnt = deg[node];
  const int* arow = csr + offset[node];
  float a0 = 0.f, a1 = 0.f, a2 = 0.f, a3 = 0.f;
  int k = 0;
  for (; k + 4 <= cnt; k += 4) {
    int s0 = arow[k], s1 = arow[k + 1], s2 = arow[k + 2], s3 = arow[k + 3];
    uint2 v0 = *(const uint2*)(t + (size_t)s0 * 64 + j * 4);
    uint2 v1 = *(const uint2*)(t + (size_t)s1 * 64 + j * 4);
    uint2 v2 = *(const uint2*)(t + (size_t)s2 * 64 + j * 4);
    uint2 v3 = *(const uint2*)(t + (size_t)s3 * 64 + j * 4);
    a0 += bf2f(v0.x & 0xffff) + bf2f(v1.x & 0xffff) + bf2f(v2.x & 0xffff) + bf2f(v3.x & 0xffff);
    a1 += bf2f(v0.x >> 16)    + bf2f(v1.x >> 16)    + bf2f(v2.x >> 16)    + bf2f(v3.x >> 16);
    a2 += bf2f(v0.y & 0xffff) + bf2f(v1.y & 0xffff) + bf2f(v2.y & 0xffff) + bf2f(v3.y & 0xffff);
    a3 += bf2f(v0.y >> 16)    + bf2f(v1.y >> 16)    + bf2f(v2.y >> 16)    + bf2f(v3.y >> 16);
  }
  for (; k < cnt; ++k) {
    int s = arow[k];
    uint2 v = *(const uint2*)(t + (size_t)s * 64 + j * 4);
    a0 += bf2f(v.x & 0xffff); a1 += bf2f(v.x >> 16);
    a2 += bf2f(v.y & 0xffff); a3 += bf2f(v.y >> 16);
  }
  float inv = 1.0f / fmaxf((float)cnt, 1.0f);
  int o = j * 4;
  float4 r = *(const float4*)(r2 + (size_t)node * 64 + o);
  float vx = a0 * inv + r.x;
  float vy = a1 * inv + r.y;
  float vz = a2 * inv + r.z;
  float vw = a3 * inv + r.w;
  float4 gm = *(const float4*)(g2 + o);
  float4 bt = *(const float4*)(be2 + o);
  float4 mu = *(const float4*)(m2 + o);
  float4 va = *(const float4*)(v2 + o);
  float4 ov;
  ov.x = (vx - mu.x) * (gm.x * rsqrtf(va.x + EPSV)) + bt.x;
  ov.y = (vy - mu.y) * (gm.y * rsqrtf(va.y + EPSV)) + bt.y;
  ov.z = (vz - mu.z) * (gm.z * rsqrtf(va.z + EPSV)) + bt.z;
  ov.w = (vw - mu.w) * (gm.w * rsqrtf(va.w + EPSV)) + bt.w;
  *(float4*)(outp + (size_t)node * 64 + o) = ov;
}

extern "C" void kernel_launch(void* const* d_in, const int* in_sizes, int n_in,
                              void* d_out, int out_size, void* d_ws, size_t ws_size,
                              hipStream_t stream) {
  const float* x   = (const float*)d_in[0];
  const int*   ei  = (const int*)d_in[1];
  const float* w1l = (const float*)d_in[2];
  const float* b1l = (const float*)d_in[3];
  const float* w1r = (const float*)d_in[4];
  const float* g1  = (const float*)d_in[5];
  const float* be1 = (const float*)d_in[6];
  const float* m1  = (const float*)d_in[7];
  const float* v1  = (const float*)d_in[8];
  const float* w2l = (const float*)d_in[9];
  const float* b2l = (const float*)d_in[10];
  const float* w2r = (const float*)d_in[11];
  const float* g2  = (const float*)d_in[12];
  const float* be2 = (const float*)d_in[13];
  const float* m2  = (const float*)d_in[14];
  const float* v2  = (const float*)d_in[15];
  float* outp = (float*)d_out;

  char* ws = (char*)d_ws;
  // layout (bytes), 16B-aligned:
  //           0 : gcur       (1,024)
  //       1,024 : bucketBase (1,024)
  //       2,048 : deg        (400,000)
  //     402,048 : offset     (400,000)
  //     802,048 : pairs      (7,225,344)      -> 8,027,392
  //   8,027,392 : csr        (6,400,000)      -> 14,427,392
  //  14,427,392 : w1c bf16   (32,768)         -> 14,460,160
  //  14,460,160 : w2c bf16   (32,768)         -> 14,492,928
  //  14,492,928 : xb  bf16   (12,800,000)     -> 27,292,928
  //  27,292,928 : aggB bf16  (12,800,000)     -> 40,092,928
  //  40,092,928 : h   bf16   (25,600,000)     -> 65,692,928
  //  65,692,928 : t   bf16   (12,800,000)     -> 78,492,928
  //  78,492,928 : r2  fp32   (25,600,000)     -> 104,092,928  (~104 MB)
  int*            gcur       = (int*)ws;
  int*            bucketBase = (int*)(ws + 1024);
  int*            deg        = (int*)(ws + 2048);
  int*            offset     = (int*)(ws + 402048);
  unsigned*       pairs      = (unsigned*)(ws + 802048);
  int*            csr        = (int*)(ws + 8027392);
  unsigned short* w1c        = (unsigned short*)(ws + 14427392);
  unsigned short* w2c        = (unsigned short*)(ws + 14460160);
  unsigned short* xb         = (unsigned short*)(ws + 14492928);
  unsigned short* aggB       = (unsigned short*)(ws + 27292928);
  unsigned short* h          = (unsigned short*)(ws + 40092928);
  unsigned short* t          = (unsigned short*)(ws + 65692928);
  float*          r2         = (float*)(ws + 78492928);

  const int* srcp = ei;
  const int* dstp = ei + NE;

  hipMemsetAsync(gcur, 0, NBUK * sizeof(int), stream);
  hipLaunchKernelGGL(k_bin, dim3(NTIL), dim3(256), 0, stream,
                     srcp, dstp, gcur, pairs);
  hipLaunchKernelGGL(k_bscan, dim3(1), dim3(256), 0, stream, gcur, bucketBase);
  hipLaunchKernelGGL(k_build, dim3(NBUK), dim3(256), 0, stream,
                     pairs, gcur, bucketBase, deg, offset, csr);
  hipLaunchKernelGGL(k_wprep, dim3(64), dim3(256), 0, stream,
                     w1l, w1r, w2l, w2r, w1c, w2c);
  hipLaunchKernelGGL(k_cvtx, dim3(NN * 64 / 1024), dim3(256), 0, stream, x, xb);
  hipLaunchKernelGGL(k_aggregate, dim3(NN / 16), dim3(256), 0, stream,
                     xb, deg, offset, csr, aggB);
  hipLaunchKernelGGL(k_gemm1, dim3((NN / 16 + 3) / 4), dim3(256), 0, stream,
                     aggB, xb, w1c, b1l, g1, be1, m1, v1, h);
  hipLaunchKernelGGL(k_gemm2, dim3((NN / 16 + 3) / 4), dim3(256), 0, stream,
                     h, w2c, b2l, t, r2);
  hipLaunchKernelGGL(k_agg2fin, dim3(NN / 16), dim3(256), 0, stream,
                     t, deg, offset, csr, r2, g2, be2, m2, v2, outp);
}

// Round 7
// 207.410 us; speedup vs baseline: 2.6151x; 1.0983x over previous
//
#include <hip/hip_runtime.h>

#define NN 100000
#define NE 1600000
#define EPSV 1e-5f

#define NBUK 196       // buckets of 512 nodes: bucket = dst >> 9
#define TILE 2048      // edges per k_bin workgroup (small -> high grid parallelism)
#define NTIL 782       // ceil(NE / TILE)
#define CAP  9216      // per-bucket capacity (mean 8163, std ~90 -> +11 sigma)

typedef __attribute__((ext_vector_type(8))) short bf16x8;
typedef __attribute__((ext_vector_type(4))) float f32x4;

__device__ inline unsigned short f2bf(float f) {
  unsigned u = __builtin_bit_cast(unsigned, f);
  unsigned r = u + 0x7FFFu + ((u >> 16) & 1u);
  return (unsigned short)(r >> 16);
}
__device__ inline float bf2f(unsigned short s) {
  unsigned u = ((unsigned)s) << 16;
  return __builtin_bit_cast(float, u);
}

// ---------------- phase 1: LDS-binned edge partition ----------------
__global__ __launch_bounds__(256) void k_bin(const int* __restrict__ src,
                                             const int* __restrict__ dst,
                                             int* __restrict__ gcur,
                                             unsigned* __restrict__ pairs) {
  __shared__ int cnt[NBUK];
  __shared__ int lo[NBUK];
  __shared__ int gbase[NBUK];
  __shared__ int ts[256];
  __shared__ unsigned stage[TILE];
  const int tid = threadIdx.x;
  const int e0 = blockIdx.x * TILE;
  const int m = min(TILE, NE - e0);

  for (int i = tid; i < NBUK; i += 256) cnt[i] = 0;
  __syncthreads();
  for (int i = tid; i < m; i += 256) {
    int d = dst[e0 + i];
    atomicAdd(&cnt[d >> 9], 1);
  }
  __syncthreads();
  int c = (tid < NBUK) ? cnt[tid] : 0;
  ts[tid] = c;
  __syncthreads();
  for (int d = 1; d < 256; d <<= 1) {
    int v = (tid >= d) ? ts[tid - d] : 0;
    __syncthreads();
    ts[tid] += v;
    __syncthreads();
  }
  if (tid < NBUK) {
    int ex = ts[tid] - c;
    lo[tid] = ex;
    gbase[tid] = atomicAdd(&gcur[tid], c);
    cnt[tid] = ex;
  }
  __syncthreads();
  for (int i = tid; i < m; i += 256) {
    int d = dst[e0 + i];
    int s = src[e0 + i];
    int b = d >> 9;
    int pos = atomicAdd(&cnt[b], 1);
    stage[pos] = ((unsigned)(d & 511) << 17) | (unsigned)s;
  }
  __syncthreads();
  for (int i = tid; i < m; i += 256) {
    int a = 0, z = NBUK - 1;
    while (a < z) {
      int mid = (a + z + 1) >> 1;
      if (lo[mid] <= i) a = mid; else z = mid - 1;
    }
    int rel = gbase[a] + (i - lo[a]);
    if (rel < CAP) pairs[(size_t)a * CAP + rel] = stage[i];
  }
}

// ---------------- phase 1.5: scan bucket counts ----------------
__global__ __launch_bounds__(256) void k_bscan(const int* __restrict__ gcur,
                                               int* __restrict__ bucketBase) {
  __shared__ int ts[256];
  const int tid = threadIdx.x;
  int c = (tid < NBUK) ? min(gcur[tid], CAP) : 0;
  ts[tid] = c;
  __syncthreads();
  for (int d = 1; d < 256; d <<= 1) {
    int v = (tid >= d) ? ts[tid - d] : 0;
    __syncthreads();
    ts[tid] += v;
    __syncthreads();
  }
  if (tid < NBUK) bucketBase[tid] = ts[tid] - c;
}

// ---------------- phase 2: per-bucket CSR build (512 threads) ----------------
__global__ __launch_bounds__(512) void k_build(const unsigned* __restrict__ pairs,
                                               const int* __restrict__ gcur,
                                               const int* __restrict__ bucketBase,
                                               int* __restrict__ deg,
                                               int* __restrict__ offset,
                                               int* __restrict__ csr) {
  __shared__ int hist[512];   // counts -> cursor
  __shared__ int ts[512];
  __shared__ unsigned stage[CAP];
  const int tid = threadIdx.x;
  const int b = blockIdx.x;
  const int count = min(gcur[b], CAP);
  const int nbase = b * 512;
  const int nloc = min(512, NN - nbase);
  const unsigned* pb = pairs + (size_t)b * CAP;
  const int obase = bucketBase[b];

  hist[tid] = 0;
  __syncthreads();
  for (int i = tid; i < count; i += 512) {
    atomicAdd(&hist[pb[i] >> 17], 1);
  }
  __syncthreads();
  int s = hist[tid];
  ts[tid] = s;
  __syncthreads();
  for (int d = 1; d < 512; d <<= 1) {
    int v = (tid >= d) ? ts[tid - d] : 0;
    __syncthreads();
    ts[tid] += v;
    __syncthreads();
  }
  int ex = ts[tid] - s;   // exclusive prefix for node tid
  if (tid < nloc) {
    deg[nbase + tid] = s;
    offset[nbase + tid] = obase + ex;
  }
  __syncthreads();
  hist[tid] = ex;  // cursor
  __syncthreads();
  for (int i = tid; i < count; i += 512) {
    unsigned e = pb[i];
    int pos = atomicAdd(&hist[e >> 17], 1);
    stage[pos] = e & 0x1FFFFu;
  }
  __syncthreads();
  for (int i = tid; i < count; i += 512) csr[obase + i] = (int)stage[i];
}

// ---------------- weight prep: bf16 combined [o=128][k=128] row-major ----------------
// W1c[o][k] = k<64 ? w1l[o][k] : w1r[o][k-64]      (gemm1: k 0-63 agg, 64-127 x)
// W2c[o][k] = o<64 ? w2l[o][k] : w2r[o-64][k]      (gemm2: o 0-63 -> t, 64-127 -> r2)
__global__ __launch_bounds__(256) void k_wprep(const float* __restrict__ w1l,
                                               const float* __restrict__ w1r,
                                               const float* __restrict__ w2l,
                                               const float* __restrict__ w2r,
                                               unsigned short* __restrict__ w1c,
                                               unsigned short* __restrict__ w2c) {
  int i = blockIdx.x * 256 + threadIdx.x;  // 0..16383
  int o = i >> 7, k = i & 127;
  float v1 = (k < 64) ? w1l[o * 64 + k] : w1r[o * 64 + (k - 64)];
  w1c[i] = f2bf(v1);
  float v2 = (o < 64) ? w2l[o * 128 + k] : w2r[(o - 64) * 128 + k];
  w2c[i] = f2bf(v2);
}

// ---------------- convert x -> bf16 ----------------
__global__ __launch_bounds__(256) void k_cvtx(const float* __restrict__ x,
                                              unsigned short* __restrict__ xb) {
  int i = blockIdx.x * 256 + threadIdx.x;
  float4 v = *(const float4*)(x + (size_t)i * 4);
  ushort4 o;
  o.x = f2bf(v.x); o.y = f2bf(v.y); o.z = f2bf(v.z); o.w = f2bf(v.w);
  *(ushort4*)(xb + (size_t)i * 4) = o;
}

// ---------------- mean-aggregate bf16 rows over CSR -> bf16 out ----------------
__global__ __launch_bounds__(256) void k_aggregate(const unsigned short* __restrict__ xb,
                                                   const int* __restrict__ deg,
                                                   const int* __restrict__ offset,
                                                   const int* __restrict__ csr,
                                                   unsigned short* __restrict__ aggB) {
  int tid = threadIdx.x;
  int node = blockIdx.x * 16 + (tid >> 4);
  int j = tid & 15;
  int cnt = deg[node];
  const int* arow = csr + offset[node];
  float a0 = 0.f, a1 = 0.f, a2 = 0.f, a3 = 0.f;
  int k = 0;
  for (; k + 4 <= cnt; k += 4) {
    int s0 = arow[k], s1 = arow[k + 1], s2 = arow[k + 2], s3 = arow[k + 3];
    uint2 v0 = *(const uint2*)(xb + (size_t)s0 * 64 + j * 4);
    uint2 v1 = *(const uint2*)(xb + (size_t)s1 * 64 + j * 4);
    uint2 v2 = *(const uint2*)(xb + (size_t)s2 * 64 + j * 4);
    uint2 v3 = *(const uint2*)(xb + (size_t)s3 * 64 + j * 4);
    a0 += bf2f(v0.x & 0xffff) + bf2f(v1.x & 0xffff) + bf2f(v2.x & 0xffff) + bf2f(v3.x & 0xffff);
    a1 += bf2f(v0.x >> 16)    + bf2f(v1.x >> 16)    + bf2f(v2.x >> 16)    + bf2f(v3.x >> 16);
    a2 += bf2f(v0.y & 0xffff) + bf2f(v1.y & 0xffff) + bf2f(v2.y & 0xffff) + bf2f(v3.y & 0xffff);
    a3 += bf2f(v0.y >> 16)    + bf2f(v1.y >> 16)    + bf2f(v2.y >> 16)    + bf2f(v3.y >> 16);
  }
  for (; k < cnt; ++k) {
    int s = arow[k];
    uint2 v = *(const uint2*)(xb + (size_t)s * 64 + j * 4);
    a0 += bf2f(v.x & 0xffff); a1 += bf2f(v.x >> 16);
    a2 += bf2f(v.y & 0xffff); a3 += bf2f(v.y >> 16);
  }
  float inv = 1.0f / fmaxf((float)cnt, 1.0f);
  ushort4 r;
  r.x = f2bf(a0 * inv); r.y = f2bf(a1 * inv);
  r.z = f2bf(a2 * inv); r.w = f2bf(a3 * inv);
  *(ushort4*)(aggB + (size_t)node * 64 + j * 4) = r;
}

// ---------------- layer1 MFMA: h = relu(bn1([aggB|xb] @ W1c.T + b1l)) ----------------
__global__ __launch_bounds__(256) void k_gemm1(const unsigned short* __restrict__ aggB,
                                               const unsigned short* __restrict__ xb,
                                               const unsigned short* __restrict__ w1c,
                                               const float* __restrict__ b1l,
                                               const float* __restrict__ g1,
                                               const float* __restrict__ be1,
                                               const float* __restrict__ m1,
                                               const float* __restrict__ v1,
                                               unsigned short* __restrict__ h) {
  const int tid = threadIdx.x;
  const int lane = tid & 63;
  const int n0 = (blockIdx.x * 4 + (tid >> 6)) * 16;
  if (n0 >= NN) return;
  const int lr = lane & 15;
  const int q = lane >> 4;
  const int node = n0 + lr;
  bf16x8 bfr[4];
  const unsigned short* ar = aggB + (size_t)node * 64 + q * 8;
  const unsigned short* xr = xb + (size_t)node * 64 + q * 8;
  bfr[0] = *(const bf16x8*)(ar);
  bfr[1] = *(const bf16x8*)(ar + 32);
  bfr[2] = *(const bf16x8*)(xr);
  bfr[3] = *(const bf16x8*)(xr + 32);
#pragma unroll
  for (int ot = 0; ot < 8; ++ot) {
    const unsigned short* wr = w1c + (size_t)(ot * 16 + lr) * 128 + q * 8;
    f32x4 acc = {0.f, 0.f, 0.f, 0.f};
    acc = __builtin_amdgcn_mfma_f32_16x16x32_bf16(*(const bf16x8*)(wr), bfr[0], acc, 0, 0, 0);
    acc = __builtin_amdgcn_mfma_f32_16x16x32_bf16(*(const bf16x8*)(wr + 32), bfr[1], acc, 0, 0, 0);
    acc = __builtin_amdgcn_mfma_f32_16x16x32_bf16(*(const bf16x8*)(wr + 64), bfr[2], acc, 0, 0, 0);
    acc = __builtin_amdgcn_mfma_f32_16x16x32_bf16(*(const bf16x8*)(wr + 96), bfr[3], acc, 0, 0, 0);
    const int o = ot * 16 + q * 4;
    float4 bias = *(const float4*)(b1l + o);
    float4 gm = *(const float4*)(g1 + o);
    float4 bt = *(const float4*)(be1 + o);
    float4 mu = *(const float4*)(m1 + o);
    float4 va = *(const float4*)(v1 + o);
    float sc0 = gm.x * rsqrtf(va.x + EPSV), sh0 = bt.x - mu.x * sc0;
    float sc1 = gm.y * rsqrtf(va.y + EPSV), sh1 = bt.y - mu.y * sc1;
    float sc2 = gm.z * rsqrtf(va.z + EPSV), sh2 = bt.z - mu.z * sc2;
    float sc3 = gm.w * rsqrtf(va.w + EPSV), sh3 = bt.w - mu.w * sc3;
    ushort4 hv;
    hv.x = f2bf(fmaxf((acc[0] + bias.x) * sc0 + sh0, 0.f));
    hv.y = f2bf(fmaxf((acc[1] + bias.y) * sc1 + sh1, 0.f));
    hv.z = f2bf(fmaxf((acc[2] + bias.z) * sc2 + sh2, 0.f));
    hv.w = f2bf(fmaxf((acc[3] + bias.w) * sc3 + sh3, 0.f));
    *(ushort4*)(h + (size_t)node * 128 + o) = hv;
  }
}

// ---------------- layer2 MFMA: t = h@W2l.T (bf16) ; r2 = h@W2r.T + b2l (fp32) ----------------
__global__ __launch_bounds__(256) void k_gemm2(const unsigned short* __restrict__ h,
                                               const unsigned short* __restrict__ w2c,
                                               const float* __restrict__ b2l,
                                               unsigned short* __restrict__ t,
                                               float* __restrict__ r2) {
  const int tid = threadIdx.x;
  const int lane = tid & 63;
  const int n0 = (blockIdx.x * 4 + (tid >> 6)) * 16;
  if (n0 >= NN) return;
  const int lr = lane & 15;
  const int q = lane >> 4;
  const int node = n0 + lr;
  const unsigned short* hr = h + (size_t)node * 128 + q * 8;
  bf16x8 bfr[4];
  bfr[0] = *(const bf16x8*)(hr);
  bfr[1] = *(const bf16x8*)(hr + 32);
  bfr[2] = *(const bf16x8*)(hr + 64);
  bfr[3] = *(const bf16x8*)(hr + 96);
#pragma unroll
  for (int ot = 0; ot < 8; ++ot) {
    const unsigned short* wr = w2c + (size_t)(ot * 16 + lr) * 128 + q * 8;
    f32x4 acc = {0.f, 0.f, 0.f, 0.f};
    acc = __builtin_amdgcn_mfma_f32_16x16x32_bf16(*(const bf16x8*)(wr), bfr[0], acc, 0, 0, 0);
    acc = __builtin_amdgcn_mfma_f32_16x16x32_bf16(*(const bf16x8*)(wr + 32), bfr[1], acc, 0, 0, 0);
    acc = __builtin_amdgcn_mfma_f32_16x16x32_bf16(*(const bf16x8*)(wr + 64), bfr[2], acc, 0, 0, 0);
    acc = __builtin_amdgcn_mfma_f32_16x16x32_bf16(*(const bf16x8*)(wr + 96), bfr[3], acc, 0, 0, 0);
    if (ot < 4) {
      const int o = ot * 16 + q * 4;
      ushort4 tv;
      tv.x = f2bf(acc[0]); tv.y = f2bf(acc[1]);
      tv.z = f2bf(acc[2]); tv.w = f2bf(acc[3]);
      *(ushort4*)(t + (size_t)node * 64 + o) = tv;
    } else {
      const int o = (ot - 4) * 16 + q * 4;
      float4 bias = *(const float4*)(b2l + o);
      float4 rv;
      rv.x = acc[0] + bias.x; rv.y = acc[1] + bias.y;
      rv.z = acc[2] + bias.z; rv.w = acc[3] + bias.w;
      *(float4*)(r2 + (size_t)node * 64 + o) = rv;
    }
  }
}

// ---------------- layer2 aggregate (bf16 t) + BN2 finish ----------------
__global__ __launch_bounds__(256) void k_agg2fin(const unsigned short* __restrict__ t,
                                                 const int* __restrict__ deg,
                                                 const int* __restrict__ offset,
                                                 const int* __restrict__ csr,
                                                 const float* __restrict__ r2,
                                                 const float* __restrict__ g2,
                                                 const float* __restrict__ be2,
                                                 const float* __restrict__ m2,
                                                 const float* __restrict__ v2,
                                                 float* __restrict__ outp) {
  int tid = threadIdx.x;
  int node = blockIdx.x * 16 + (tid >> 4);
  int j = tid & 15;
  int cnt = deg[node];
  const int* arow = csr + offset[node];
  float a0 = 0.f, a1 = 0.f, a2 = 0.f, a3 = 0.f;
  int k = 0;
  for (; k + 4 <= cnt; k += 4) {
    int s0 = arow[k], s1 = arow[k + 1], s2 = arow[k + 2], s3 = arow[k + 3];
    uint2 v0 = *(const uint2*)(t + (size_t)s0 * 64 + j * 4);
    uint2 v1 = *(const uint2*)(t + (size_t)s1 * 64 + j * 4);
    uint2 v2 = *(const uint2*)(t + (size_t)s2 * 64 + j * 4);
    uint2 v3 = *(const uint2*)(t + (size_t)s3 * 64 + j * 4);
    a0 += bf2f(v0.x & 0xffff) + bf2f(v1.x & 0xffff) + bf2f(v2.x & 0xffff) + bf2f(v3.x & 0xffff);
    a1 += bf2f(v0.x >> 16)    + bf2f(v1.x >> 16)    + bf2f(v2.x >> 16)    + bf2f(v3.x >> 16);
    a2 += bf2f(v0.y & 0xffff) + bf2f(v1.y & 0xffff) + bf2f(v2.y & 0xffff) + bf2f(v3.y & 0xffff);
    a3 += bf2f(v0.y >> 16)    + bf2f(v1.y >> 16)    + bf2f(v2.y >> 16)    + bf2f(v3.y >> 16);
  }
  for (; k < cnt; ++k) {
    int s = arow[k];
    uint2 v = *(const uint2*)(t + (size_t)s * 64 + j * 4);
    a0 += bf2f(v.x & 0xffff); a1 += bf2f(v.x >> 16);
    a2 += bf2f(v.y & 0xffff); a3 += bf2f(v.y >> 16);
  }
  float inv = 1.0f / fmaxf((float)cnt, 1.0f);
  int o = j * 4;
  float4 r = *(const float4*)(r2 + (size_t)node * 64 + o);
  float vx = a0 * inv + r.x;
  float vy = a1 * inv + r.y;
  float vz = a2 * inv + r.z;
  float vw = a3 * inv + r.w;
  float4 gm = *(const float4*)(g2 + o);
  float4 bt = *(const float4*)(be2 + o);
  float4 mu = *(const float4*)(m2 + o);
  float4 va = *(const float4*)(v2 + o);
  float4 ov;
  ov.x = (vx - mu.x) * (gm.x * rsqrtf(va.x + EPSV)) + bt.x;
  ov.y = (vy - mu.y) * (gm.y * rsqrtf(va.y + EPSV)) + bt.y;
  ov.z = (vz - mu.z) * (gm.z * rsqrtf(va.z + EPSV)) + bt.z;
  ov.w = (vw - mu.w) * (gm.w * rsqrtf(va.w + EPSV)) + bt.w;
  *(float4*)(outp + (size_t)node * 64 + o) = ov;
}

extern "C" void kernel_launch(void* const* d_in, const int* in_sizes, int n_in,
                              void* d_out, int out_size, void* d_ws, size_t ws_size,
                              hipStream_t stream) {
  const float* x   = (const float*)d_in[0];
  const int*   ei  = (const int*)d_in[1];
  const float* w1l = (const float*)d_in[2];
  const float* b1l = (const float*)d_in[3];
  const float* w1r = (const float*)d_in[4];
  const float* g1  = (const float*)d_in[5];
  const float* be1 = (const float*)d_in[6];
  const float* m1  = (const float*)d_in[7];
  const float* v1  = (const float*)d_in[8];
  const float* w2l = (const float*)d_in[9];
  const float* b2l = (const float*)d_in[10];
  const float* w2r = (const float*)d_in[11];
  const float* g2  = (const float*)d_in[12];
  const float* be2 = (const float*)d_in[13];
  const float* m2  = (const float*)d_in[14];
  const float* v2  = (const float*)d_in[15];
  float* outp = (float*)d_out;

  char* ws = (char*)d_ws;
  // layout (bytes), 16B-aligned:
  //           0 : gcur       (1,024)
  //       1,024 : bucketBase (1,024)
  //       2,048 : deg        (400,000)
  //     402,048 : offset     (400,000)
  //     802,048 : pairs      (7,225,344)      -> 8,027,392
  //   8,027,392 : csr        (6,400,000)      -> 14,427,392
  //  14,427,392 : w1c bf16   (32,768)         -> 14,460,160
  //  14,460,160 : w2c bf16   (32,768)         -> 14,492,928
  //  14,492,928 : xb  bf16   (12,800,000)     -> 27,292,928
  //  27,292,928 : aggB bf16  (12,800,000)     -> 40,092,928
  //  40,092,928 : h   bf16   (25,600,000)     -> 65,692,928
  //  65,692,928 : t   bf16   (12,800,000)     -> 78,492,928
  //  78,492,928 : r2  fp32   (25,600,000)     -> 104,092,928  (~104 MB)
  int*            gcur       = (int*)ws;
  int*            bucketBase = (int*)(ws + 1024);
  int*            deg        = (int*)(ws + 2048);
  int*            offset     = (int*)(ws + 402048);
  unsigned*       pairs      = (unsigned*)(ws + 802048);
  int*            csr        = (int*)(ws + 8027392);
  unsigned short* w1c        = (unsigned short*)(ws + 14427392);
  unsigned short* w2c        = (unsigned short*)(ws + 14460160);
  unsigned short* xb         = (unsigned short*)(ws + 14492928);
  unsigned short* aggB       = (unsigned short*)(ws + 27292928);
  unsigned short* h          = (unsigned short*)(ws + 40092928);
  unsigned short* t          = (unsigned short*)(ws + 65692928);
  float*          r2         = (float*)(ws + 78492928);

  const int* srcp = ei;
  const int* dstp = ei + NE;

  hipMemsetAsync(gcur, 0, NBUK * sizeof(int), stream);
  hipLaunchKernelGGL(k_bin, dim3(NTIL), dim3(256), 0, stream,
                     srcp, dstp, gcur, pairs);
  hipLaunchKernelGGL(k_bscan, dim3(1), dim3(256), 0, stream, gcur, bucketBase);
  hipLaunchKernelGGL(k_build, dim3(NBUK), dim3(512), 0, stream,
                     pairs, gcur, bucketBase, deg, offset, csr);
  hipLaunchKernelGGL(k_wprep, dim3(64), dim3(256), 0, stream,
                     w1l, w1r, w2l, w2r, w1c, w2c);
  hipLaunchKernelGGL(k_cvtx, dim3(NN * 64 / 1024), dim3(256), 0, stream, x, xb);
  hipLaunchKernelGGL(k_aggregate, dim3(NN / 16), dim3(256), 0, stream,
                     xb, deg, offset, csr, aggB);
  hipLaunchKernelGGL(k_gemm1, dim3((NN / 16 + 3) / 4), dim3(256), 0, stream,
                     aggB, xb, w1c, b1l, g1, be1, m1, v1, h);
  hipLaunchKernelGGL(k_gemm2, dim3((NN / 16 + 3) / 4), dim3(256), 0, stream,
                     h, w2c, b2l, t, r2);
  hipLaunchKernelGGL(k_agg2fin, dim3(NN / 16), dim3(256), 0, stream,
                     t, deg, offset, csr, r2, g2, be2, m2, v2, outp);
}

// Round 8
// 165.463 us; speedup vs baseline: 3.2780x; 1.2535x over previous
//
#include <hip/hip_runtime.h>

#define NN 100000
#define NE 1600000
#define EPSV 1e-5f

#define NBUK 196       // buckets of 512 nodes: bucket = dst >> 9
#define TILE 2048      // edges per k_bin workgroup
#define NTIL 782       // ceil(NE / TILE)
#define CAP  9216      // per-bucket capacity

typedef __attribute__((ext_vector_type(8))) short bf16x8;
typedef __attribute__((ext_vector_type(4))) float f32x4;

__device__ inline unsigned short f2bf(float f) {
  unsigned u = __builtin_bit_cast(unsigned, f);
  unsigned r = u + 0x7FFFu + ((u >> 16) & 1u);
  return (unsigned short)(r >> 16);
}
__device__ inline float bf2f(unsigned short s) {
  unsigned u = ((unsigned)s) << 16;
  return __builtin_bit_cast(float, u);
}

// ---------------- phase 1: LDS-binned edge partition ----------------
__global__ __launch_bounds__(256) void k_bin(const int* __restrict__ src,
                                             const int* __restrict__ dst,
                                             int* __restrict__ gcur,
                                             unsigned* __restrict__ pairs) {
  __shared__ int cnt[NBUK];
  __shared__ int lo[NBUK];
  __shared__ int gbase[NBUK];
  __shared__ int ts[256];
  __shared__ unsigned stage[TILE];
  const int tid = threadIdx.x;
  const int e0 = blockIdx.x * TILE;
  const int m = min(TILE, NE - e0);

  for (int i = tid; i < NBUK; i += 256) cnt[i] = 0;
  __syncthreads();
  for (int i = tid; i < m; i += 256) {
    int d = dst[e0 + i];
    atomicAdd(&cnt[d >> 9], 1);
  }
  __syncthreads();
  int c = (tid < NBUK) ? cnt[tid] : 0;
  ts[tid] = c;
  __syncthreads();
  for (int d = 1; d < 256; d <<= 1) {
    int v = (tid >= d) ? ts[tid - d] : 0;
    __syncthreads();
    ts[tid] += v;
    __syncthreads();
  }
  if (tid < NBUK) {
    int ex = ts[tid] - c;
    lo[tid] = ex;
    gbase[tid] = atomicAdd(&gcur[tid], c);
    cnt[tid] = ex;
  }
  __syncthreads();
  for (int i = tid; i < m; i += 256) {
    int d = dst[e0 + i];
    int s = src[e0 + i];
    int b = d >> 9;
    int pos = atomicAdd(&cnt[b], 1);
    stage[pos] = ((unsigned)(d & 511) << 17) | (unsigned)s;
  }
  __syncthreads();
  for (int i = tid; i < m; i += 256) {
    int a = 0, z = NBUK - 1;
    while (a < z) {
      int mid = (a + z + 1) >> 1;
      if (lo[mid] <= i) a = mid; else z = mid - 1;
    }
    int rel = gbase[a] + (i - lo[a]);
    if (rel < CAP) pairs[(size_t)a * CAP + rel] = stage[i];
  }
}

// ---------------- phase 1.5: scan bucket counts ----------------
__global__ __launch_bounds__(256) void k_bscan(const int* __restrict__ gcur,
                                               int* __restrict__ bucketBase) {
  __shared__ int ts[256];
  const int tid = threadIdx.x;
  int c = (tid < NBUK) ? min(gcur[tid], CAP) : 0;
  ts[tid] = c;
  __syncthreads();
  for (int d = 1; d < 256; d <<= 1) {
    int v = (tid >= d) ? ts[tid - d] : 0;
    __syncthreads();
    ts[tid] += v;
    __syncthreads();
  }
  if (tid < NBUK) bucketBase[tid] = ts[tid] - c;
}

// ---------------- phase 2: per-bucket CSR build (512 threads) ----------------
__global__ __launch_bounds__(512) void k_build(const unsigned* __restrict__ pairs,
                                               const int* __restrict__ gcur,
                                               const int* __restrict__ bucketBase,
                                               int* __restrict__ deg,
                                               int* __restrict__ offset,
                                               int* __restrict__ csr) {
  __shared__ int hist[512];
  __shared__ int ts[512];
  __shared__ unsigned stage[CAP];
  const int tid = threadIdx.x;
  const int b = blockIdx.x;
  const int count = min(gcur[b], CAP);
  const int nbase = b * 512;
  const int nloc = min(512, NN - nbase);
  const unsigned* pb = pairs + (size_t)b * CAP;
  const int obase = bucketBase[b];

  hist[tid] = 0;
  __syncthreads();
  for (int i = tid; i < count; i += 512) {
    atomicAdd(&hist[pb[i] >> 17], 1);
  }
  __syncthreads();
  int s = hist[tid];
  ts[tid] = s;
  __syncthreads();
  for (int d = 1; d < 512; d <<= 1) {
    int v = (tid >= d) ? ts[tid - d] : 0;
    __syncthreads();
    ts[tid] += v;
    __syncthreads();
  }
  int ex = ts[tid] - s;
  if (tid < nloc) {
    deg[nbase + tid] = s;
    offset[nbase + tid] = obase + ex;
  }
  __syncthreads();
  hist[tid] = ex;
  __syncthreads();
  for (int i = tid; i < count; i += 512) {
    unsigned e = pb[i];
    int pos = atomicAdd(&hist[e >> 17], 1);
    stage[pos] = e & 0x1FFFFu;
  }
  __syncthreads();
  for (int i = tid; i < count; i += 512) csr[obase + i] = (int)stage[i];
}

// ---------------- weight + BN-param prep ----------------
// w1c[o][k]: k<64 w1l, k>=64 w1r. w2c[o][k]: o<64 w2l -> t, o>=64 w2r -> r2.
// bn[0..127]=SC1, [128..255]=SH1 (bias folded), [256..319]=SC2, [320..383]=SH2.
__global__ __launch_bounds__(256) void k_wprep(const float* __restrict__ w1l,
                                               const float* __restrict__ w1r,
                                               const float* __restrict__ w2l,
                                               const float* __restrict__ w2r,
                                               const float* __restrict__ b1l,
                                               const float* __restrict__ g1,
                                               const float* __restrict__ be1,
                                               const float* __restrict__ m1,
                                               const float* __restrict__ v1,
                                               const float* __restrict__ g2,
                                               const float* __restrict__ be2,
                                               const float* __restrict__ m2,
                                               const float* __restrict__ v2,
                                               unsigned short* __restrict__ w1c,
                                               unsigned short* __restrict__ w2c,
                                               float* __restrict__ bn) {
  int i = blockIdx.x * 256 + threadIdx.x;  // 0..16383
  int o = i >> 7, k = i & 127;
  float vv1 = (k < 64) ? w1l[o * 64 + k] : w1r[o * 64 + (k - 64)];
  w1c[i] = f2bf(vv1);
  float vv2 = (o < 64) ? w2l[o * 128 + k] : w2r[(o - 64) * 128 + k];
  w2c[i] = f2bf(vv2);
  if (i < 128) {
    float sc = g1[i] * rsqrtf(v1[i] + EPSV);
    bn[i] = sc;
    bn[128 + i] = (b1l[i] - m1[i]) * sc + be1[i];
  }
  if (i < 64) {
    float sc = g2[i] * rsqrtf(v2[i] + EPSV);
    bn[256 + i] = sc;
    bn[320 + i] = be2[i] - m2[i] * sc;
  }
}

// ---------------- convert x -> bf16 ----------------
__global__ __launch_bounds__(256) void k_cvtx(const float* __restrict__ x,
                                              unsigned short* __restrict__ xb) {
  int i = blockIdx.x * 256 + threadIdx.x;
  float4 v = *(const float4*)(x + (size_t)i * 4);
  ushort4 o;
  o.x = f2bf(v.x); o.y = f2bf(v.y); o.z = f2bf(v.z); o.w = f2bf(v.w);
  *(ushort4*)(xb + (size_t)i * 4) = o;
}

// ---------------- mean-aggregate: 8 lanes/node, 16B per lane ----------------
__global__ __launch_bounds__(256) void k_aggregate(const unsigned short* __restrict__ xb,
                                                   const int* __restrict__ deg,
                                                   const int* __restrict__ offset,
                                                   const int* __restrict__ csr,
                                                   unsigned short* __restrict__ aggB) {
  int tid = threadIdx.x;
  int node = blockIdx.x * 32 + (tid >> 3);   // NN%32==0
  int j = tid & 7;
  int cnt = deg[node];
  const int* arow = csr + offset[node];
  float a0=0.f,a1=0.f,a2=0.f,a3=0.f,a4=0.f,a5=0.f,a6=0.f,a7=0.f;
  int k = 0;
  for (; k + 4 <= cnt; k += 4) {
    int s0 = arow[k], s1 = arow[k+1], s2 = arow[k+2], s3 = arow[k+3];
    uint4 v0 = *(const uint4*)(xb + (size_t)s0 * 64 + j * 8);
    uint4 v1 = *(const uint4*)(xb + (size_t)s1 * 64 + j * 8);
    uint4 v2 = *(const uint4*)(xb + (size_t)s2 * 64 + j * 8);
    uint4 v3 = *(const uint4*)(xb + (size_t)s3 * 64 + j * 8);
    a0 += bf2f(v0.x & 0xffff) + bf2f(v1.x & 0xffff) + bf2f(v2.x & 0xffff) + bf2f(v3.x & 0xffff);
    a1 += bf2f(v0.x >> 16)    + bf2f(v1.x >> 16)    + bf2f(v2.x >> 16)    + bf2f(v3.x >> 16);
    a2 += bf2f(v0.y & 0xffff) + bf2f(v1.y & 0xffff) + bf2f(v2.y & 0xffff) + bf2f(v3.y & 0xffff);
    a3 += bf2f(v0.y >> 16)    + bf2f(v1.y >> 16)    + bf2f(v2.y >> 16)    + bf2f(v3.y >> 16);
    a4 += bf2f(v0.z & 0xffff) + bf2f(v1.z & 0xffff) + bf2f(v2.z & 0xffff) + bf2f(v3.z & 0xffff);
    a5 += bf2f(v0.z >> 16)    + bf2f(v1.z >> 16)    + bf2f(v2.z >> 16)    + bf2f(v3.z >> 16);
    a6 += bf2f(v0.w & 0xffff) + bf2f(v1.w & 0xffff) + bf2f(v2.w & 0xffff) + bf2f(v3.w & 0xffff);
    a7 += bf2f(v0.w >> 16)    + bf2f(v1.w >> 16)    + bf2f(v2.w >> 16)    + bf2f(v3.w >> 16);
  }
  for (; k < cnt; ++k) {
    int s = arow[k];
    uint4 v = *(const uint4*)(xb + (size_t)s * 64 + j * 8);
    a0 += bf2f(v.x & 0xffff); a1 += bf2f(v.x >> 16);
    a2 += bf2f(v.y & 0xffff); a3 += bf2f(v.y >> 16);
    a4 += bf2f(v.z & 0xffff); a5 += bf2f(v.z >> 16);
    a6 += bf2f(v.w & 0xffff); a7 += bf2f(v.w >> 16);
  }
  float inv = 1.0f / fmaxf((float)cnt, 1.0f);
  ushort4 r0, r1;
  r0.x = f2bf(a0 * inv); r0.y = f2bf(a1 * inv); r0.z = f2bf(a2 * inv); r0.w = f2bf(a3 * inv);
  r1.x = f2bf(a4 * inv); r1.y = f2bf(a5 * inv); r1.z = f2bf(a6 * inv); r1.w = f2bf(a7 * inv);
  *(ushort4*)(aggB + (size_t)node * 64 + j * 8) = r0;
  *(ushort4*)(aggB + (size_t)node * 64 + j * 8 + 4) = r1;
}

// ---------------- fused MFMA: layer1 (h in LDS) + layer2 ----------------
// 4 waves/block, 32 nodes/wave (2 groups of 16). 128 nodes/block.
__global__ __launch_bounds__(256) void k_gemm12(const unsigned short* __restrict__ aggB,
                                                const unsigned short* __restrict__ xb,
                                                const unsigned short* __restrict__ w1c,
                                                const unsigned short* __restrict__ w2c,
                                                const float* __restrict__ bn,
                                                const float* __restrict__ b2l,
                                                unsigned short* __restrict__ t,
                                                float* __restrict__ r2) {
  __shared__ unsigned short hlds[4][2][16 * 128];  // 32KB
  const int tid = threadIdx.x;
  const int w = tid >> 6;
  const int lane = tid & 63;
  const int lr = lane & 15;
  const int q = lane >> 4;
  const int base = blockIdx.x * 128 + w * 32;
  const int nA = base + lr, nB = base + 16 + lr;
  const int cA = min(nA, NN - 1), cB = min(nB, NN - 1);
  const int swz = (lr & 7) << 4;

  bf16x8 fA[4], fB[4];
  {
    const unsigned short* a = aggB + (size_t)cA * 64 + q * 8;
    const unsigned short* xx = xb + (size_t)cA * 64 + q * 8;
    fA[0] = *(const bf16x8*)a;        fA[1] = *(const bf16x8*)(a + 32);
    fA[2] = *(const bf16x8*)xx;       fA[3] = *(const bf16x8*)(xx + 32);
  }
  {
    const unsigned short* a = aggB + (size_t)cB * 64 + q * 8;
    const unsigned short* xx = xb + (size_t)cB * 64 + q * 8;
    fB[0] = *(const bf16x8*)a;        fB[1] = *(const bf16x8*)(a + 32);
    fB[2] = *(const bf16x8*)xx;       fB[3] = *(const bf16x8*)(xx + 32);
  }
  char* ldsA = (char*)&hlds[w][0][0];
  char* ldsB = (char*)&hlds[w][1][0];

  // ---- layer 1: h = relu(acc*SC1 + SH1), written to swizzled LDS ----
#pragma unroll
  for (int ot = 0; ot < 8; ++ot) {
    const unsigned short* wr = w1c + (size_t)(ot * 16 + lr) * 128 + q * 8;
    bf16x8 w0 = *(const bf16x8*)(wr);
    bf16x8 w1 = *(const bf16x8*)(wr + 32);
    bf16x8 w2 = *(const bf16x8*)(wr + 64);
    bf16x8 w3 = *(const bf16x8*)(wr + 96);
    f32x4 aA = {0.f, 0.f, 0.f, 0.f}, aB = {0.f, 0.f, 0.f, 0.f};
    aA = __builtin_amdgcn_mfma_f32_16x16x32_bf16(w0, fA[0], aA, 0, 0, 0);
    aA = __builtin_amdgcn_mfma_f32_16x16x32_bf16(w1, fA[1], aA, 0, 0, 0);
    aA = __builtin_amdgcn_mfma_f32_16x16x32_bf16(w2, fA[2], aA, 0, 0, 0);
    aA = __builtin_amdgcn_mfma_f32_16x16x32_bf16(w3, fA[3], aA, 0, 0, 0);
    aB = __builtin_amdgcn_mfma_f32_16x16x32_bf16(w0, fB[0], aB, 0, 0, 0);
    aB = __builtin_amdgcn_mfma_f32_16x16x32_bf16(w1, fB[1], aB, 0, 0, 0);
    aB = __builtin_amdgcn_mfma_f32_16x16x32_bf16(w2, fB[2], aB, 0, 0, 0);
    aB = __builtin_amdgcn_mfma_f32_16x16x32_bf16(w3, fB[3], aB, 0, 0, 0);
    const int o = ot * 16 + q * 4;
    float4 sc = *(const float4*)(bn + o);
    float4 sh = *(const float4*)(bn + 128 + o);
    ushort4 hA, hB;
    hA.x = f2bf(fmaxf(aA[0] * sc.x + sh.x, 0.f));
    hA.y = f2bf(fmaxf(aA[1] * sc.y + sh.y, 0.f));
    hA.z = f2bf(fmaxf(aA[2] * sc.z + sh.z, 0.f));
    hA.w = f2bf(fmaxf(aA[3] * sc.w + sh.w, 0.f));
    hB.x = f2bf(fmaxf(aB[0] * sc.x + sh.x, 0.f));
    hB.y = f2bf(fmaxf(aB[1] * sc.y + sh.y, 0.f));
    hB.z = f2bf(fmaxf(aB[2] * sc.z + sh.z, 0.f));
    hB.w = f2bf(fmaxf(aB[3] * sc.w + sh.w, 0.f));
    const int wb = lr * 256 + ot * 32 + q * 8;
    *(ushort4*)(ldsA + (wb ^ swz)) = hA;
    *(ushort4*)(ldsB + (wb ^ swz)) = hB;
  }

  // ---- redistribute: read B-fragments of h from LDS (same wave; no barrier) ----
  bf16x8 hA[4], hB[4];
#pragma unroll
  for (int jj = 0; jj < 4; ++jj) {
    const int rb = lr * 256 + jj * 64 + q * 16;
    hA[jj] = *(const bf16x8*)(ldsA + (rb ^ swz));
    hB[jj] = *(const bf16x8*)(ldsB + (rb ^ swz));
  }

  // ---- layer 2: ot<4 -> t (bf16), ot>=4 -> r2 (fp32, +b2l) ----
#pragma unroll
  for (int ot = 0; ot < 8; ++ot) {
    const unsigned short* wr = w2c + (size_t)(ot * 16 + lr) * 128 + q * 8;
    bf16x8 w0 = *(const bf16x8*)(wr);
    bf16x8 w1 = *(const bf16x8*)(wr + 32);
    bf16x8 w2 = *(const bf16x8*)(wr + 64);
    bf16x8 w3 = *(const bf16x8*)(wr + 96);
    f32x4 aA = {0.f, 0.f, 0.f, 0.f}, aB = {0.f, 0.f, 0.f, 0.f};
    aA = __builtin_amdgcn_mfma_f32_16x16x32_bf16(w0, hA[0], aA, 0, 0, 0);
    aA = __builtin_amdgcn_mfma_f32_16x16x32_bf16(w1, hA[1], aA, 0, 0, 0);
    aA = __builtin_amdgcn_mfma_f32_16x16x32_bf16(w2, hA[2], aA, 0, 0, 0);
    aA = __builtin_amdgcn_mfma_f32_16x16x32_bf16(w3, hA[3], aA, 0, 0, 0);
    aB = __builtin_amdgcn_mfma_f32_16x16x32_bf16(w0, hB[0], aB, 0, 0, 0);
    aB = __builtin_amdgcn_mfma_f32_16x16x32_bf16(w1, hB[1], aB, 0, 0, 0);
    aB = __builtin_amdgcn_mfma_f32_16x16x32_bf16(w2, hB[2], aB, 0, 0, 0);
    aB = __builtin_amdgcn_mfma_f32_16x16x32_bf16(w3, hB[3], aB, 0, 0, 0);
    if (ot < 4) {
      const int o = ot * 16 + q * 4;
      ushort4 tv;
      tv.x = f2bf(aA[0]); tv.y = f2bf(aA[1]); tv.z = f2bf(aA[2]); tv.w = f2bf(aA[3]);
      if (nA < NN) *(ushort4*)(t + (size_t)nA * 64 + o) = tv;
      tv.x = f2bf(aB[0]); tv.y = f2bf(aB[1]); tv.z = f2bf(aB[2]); tv.w = f2bf(aB[3]);
      if (nB < NN) *(ushort4*)(t + (size_t)nB * 64 + o) = tv;
    } else {
      const int o = (ot - 4) * 16 + q * 4;
      float4 bias = *(const float4*)(b2l + o);
      float4 rv;
      rv.x = aA[0] + bias.x; rv.y = aA[1] + bias.y;
      rv.z = aA[2] + bias.z; rv.w = aA[3] + bias.w;
      if (nA < NN) *(float4*)(r2 + (size_t)nA * 64 + o) = rv;
      rv.x = aB[0] + bias.x; rv.y = aB[1] + bias.y;
      rv.z = aB[2] + bias.z; rv.w = aB[3] + bias.w;
      if (nB < NN) *(float4*)(r2 + (size_t)nB * 64 + o) = rv;
    }
  }
}

// ---------------- layer2 aggregate (bf16 t) + BN2: 8 lanes/node ----------------
__global__ __launch_bounds__(256) void k_agg2fin(const unsigned short* __restrict__ t,
                                                 const int* __restrict__ deg,
                                                 const int* __restrict__ offset,
                                                 const int* __restrict__ csr,
                                                 const float* __restrict__ r2,
                                                 const float* __restrict__ bn,
                                                 float* __restrict__ outp) {
  int tid = threadIdx.x;
  int node = blockIdx.x * 32 + (tid >> 3);
  int j = tid & 7;
  int cnt = deg[node];
  const int* arow = csr + offset[node];
  float a0=0.f,a1=0.f,a2=0.f,a3=0.f,a4=0.f,a5=0.f,a6=0.f,a7=0.f;
  int k = 0;
  for (; k + 4 <= cnt; k += 4) {
    int s0 = arow[k], s1 = arow[k+1], s2 = arow[k+2], s3 = arow[k+3];
    uint4 v0 = *(const uint4*)(t + (size_t)s0 * 64 + j * 8);
    uint4 v1 = *(const uint4*)(t + (size_t)s1 * 64 + j * 8);
    uint4 v2 = *(const uint4*)(t + (size_t)s2 * 64 + j * 8);
    uint4 v3 = *(const uint4*)(t + (size_t)s3 * 64 + j * 8);
    a0 += bf2f(v0.x & 0xffff) + bf2f(v1.x & 0xffff) + bf2f(v2.x & 0xffff) + bf2f(v3.x & 0xffff);
    a1 += bf2f(v0.x >> 16)    + bf2f(v1.x >> 16)    + bf2f(v2.x >> 16)    + bf2f(v3.x >> 16);
    a2 += bf2f(v0.y & 0xffff) + bf2f(v1.y & 0xffff) + bf2f(v2.y & 0xffff) + bf2f(v3.y & 0xffff);
    a3 += bf2f(v0.y >> 16)    + bf2f(v1.y >> 16)    + bf2f(v2.y >> 16)    + bf2f(v3.y >> 16);
    a4 += bf2f(v0.z & 0xffff) + bf2f(v1.z & 0xffff) + bf2f(v2.z & 0xffff) + bf2f(v3.z & 0xffff);
    a5 += bf2f(v0.z >> 16)    + bf2f(v1.z >> 16)    + bf2f(v2.z >> 16)    + bf2f(v3.z >> 16);
    a6 += bf2f(v0.w & 0xffff) + bf2f(v1.w & 0xffff) + bf2f(v2.w & 0xffff) + bf2f(v3.w & 0xffff);
    a7 += bf2f(v0.w >> 16)    + bf2f(v1.w >> 16)    + bf2f(v2.w >> 16)    + bf2f(v3.w >> 16);
  }
  for (; k < cnt; ++k) {
    int s = arow[k];
    uint4 v = *(const uint4*)(t + (size_t)s * 64 + j * 8);
    a0 += bf2f(v.x & 0xffff); a1 += bf2f(v.x >> 16);
    a2 += bf2f(v.y & 0xffff); a3 += bf2f(v.y >> 16);
    a4 += bf2f(v.z & 0xffff); a5 += bf2f(v.z >> 16);
    a6 += bf2f(v.w & 0xffff); a7 += bf2f(v.w >> 16);
  }
  float inv = 1.0f / fmaxf((float)cnt, 1.0f);
  int o = j * 8;
  float4 ra = *(const float4*)(r2 + (size_t)node * 64 + o);
  float4 rb = *(const float4*)(r2 + (size_t)node * 64 + o + 4);
  float4 sca = *(const float4*)(bn + 256 + o);
  float4 scb = *(const float4*)(bn + 256 + o + 4);
  float4 sha = *(const float4*)(bn + 320 + o);
  float4 shb = *(const float4*)(bn + 320 + o + 4);
  float4 o0, o1;
  o0.x = (a0 * inv + ra.x) * sca.x + sha.x;
  o0.y = (a1 * inv + ra.y) * sca.y + sha.y;
  o0.z = (a2 * inv + ra.z) * sca.z + sha.z;
  o0.w = (a3 * inv + ra.w) * sca.w + sha.w;
  o1.x = (a4 * inv + rb.x) * scb.x + shb.x;
  o1.y = (a5 * inv + rb.y) * scb.y + shb.y;
  o1.z = (a6 * inv + rb.z) * scb.z + shb.z;
  o1.w = (a7 * inv + rb.w) * scb.w + shb.w;
  *(float4*)(outp + (size_t)node * 64 + o) = o0;
  *(float4*)(outp + (size_t)node * 64 + o + 4) = o1;
}

extern "C" void kernel_launch(void* const* d_in, const int* in_sizes, int n_in,
                              void* d_out, int out_size, void* d_ws, size_t ws_size,
                              hipStream_t stream) {
  const float* x   = (const float*)d_in[0];
  const int*   ei  = (const int*)d_in[1];
  const float* w1l = (const float*)d_in[2];
  const float* b1l = (const float*)d_in[3];
  const float* w1r = (const float*)d_in[4];
  const float* g1  = (const float*)d_in[5];
  const float* be1 = (const float*)d_in[6];
  const float* m1  = (const float*)d_in[7];
  const float* v1  = (const float*)d_in[8];
  const float* w2l = (const float*)d_in[9];
  const float* b2l = (const float*)d_in[10];
  const float* w2r = (const float*)d_in[11];
  const float* g2  = (const float*)d_in[12];
  const float* be2 = (const float*)d_in[13];
  const float* m2  = (const float*)d_in[14];
  const float* v2  = (const float*)d_in[15];
  float* outp = (float*)d_out;

  char* ws = (char*)d_ws;
  // layout (bytes), 16B-aligned:
  //           0 : gcur       (1,024)
  //       1,024 : bucketBase (1,024)
  //       2,048 : deg        (400,000)
  //     402,048 : offset     (400,000)
  //     802,048 : pairs      (7,225,344)   -> 8,027,392
  //   8,027,392 : csr        (6,400,000)   -> 14,427,392
  //  14,427,392 : w1c bf16   (32,768)      -> 14,460,160
  //  14,460,160 : w2c bf16   (32,768)      -> 14,492,928
  //  14,492,928 : bn  fp32   (2,048)       -> 14,494,976
  //  14,494,976 : xb  bf16   (12,800,000)  -> 27,294,976
  //  27,294,976 : aggB bf16  (12,800,000)  -> 40,094,976
  //  40,094,976 : t   bf16   (12,800,000)  -> 52,894,976
  //  52,894,976 : r2  fp32   (25,600,000)  -> 78,494,976  (~78.5 MB)
  int*            gcur       = (int*)ws;
  int*            bucketBase = (int*)(ws + 1024);
  int*            deg        = (int*)(ws + 2048);
  int*            offset     = (int*)(ws + 402048);
  unsigned*       pairs      = (unsigned*)(ws + 802048);
  int*            csr        = (int*)(ws + 8027392);
  unsigned short* w1c        = (unsigned short*)(ws + 14427392);
  unsigned short* w2c        = (unsigned short*)(ws + 14460160);
  float*          bn         = (float*)(ws + 14492928);
  unsigned short* xb         = (unsigned short*)(ws + 14494976);
  unsigned short* aggB       = (unsigned short*)(ws + 27294976);
  unsigned short* t          = (unsigned short*)(ws + 40094976);
  float*          r2         = (float*)(ws + 52894976);

  const int* srcp = ei;
  const int* dstp = ei + NE;

  hipMemsetAsync(gcur, 0, NBUK * sizeof(int), stream);
  hipLaunchKernelGGL(k_bin, dim3(NTIL), dim3(256), 0, stream,
                     srcp, dstp, gcur, pairs);
  hipLaunchKernelGGL(k_bscan, dim3(1), dim3(256), 0, stream, gcur, bucketBase);
  hipLaunchKernelGGL(k_build, dim3(NBUK), dim3(512), 0, stream,
                     pairs, gcur, bucketBase, deg, offset, csr);
  hipLaunchKernelGGL(k_wprep, dim3(64), dim3(256), 0, stream,
                     w1l, w1r, w2l, w2r, b1l, g1, be1, m1, v1,
                     g2, be2, m2, v2, w1c, w2c, bn);
  hipLaunchKernelGGL(k_cvtx, dim3(NN * 64 / 1024), dim3(256), 0, stream, x, xb);
  hipLaunchKernelGGL(k_aggregate, dim3(NN / 32), dim3(256), 0, stream,
                     xb, deg, offset, csr, aggB);
  hipLaunchKernelGGL(k_gemm12, dim3((NN + 127) / 128), dim3(256), 0, stream,
                     aggB, xb, w1c, w2c, bn, b2l, t, r2);
  hipLaunchKernelGGL(k_agg2fin, dim3(NN / 32), dim3(256), 0, stream,
                     t, deg, offset, csr, r2, bn, outp);
}

// Round 9
// 157.906 us; speedup vs baseline: 3.4349x; 1.0479x over previous
//
#include <hip/hip_runtime.h>

#define NN 100000
#define NE 1600000
#define EPSV 1e-5f

#define NBUK 196       // buckets of 512 nodes: bucket = dst >> 9
#define TILE 2048      // edges per k_bin workgroup
#define NTIL 782       // ceil(NE / TILE)
#define CAP  9216      // per-bucket capacity
#define GW   6         // waves per k_gemm12 block

typedef __attribute__((ext_vector_type(8))) short bf16x8;
typedef __attribute__((ext_vector_type(4))) float f32x4;

__device__ inline unsigned short f2bf(float f) {
  unsigned u = __builtin_bit_cast(unsigned, f);
  unsigned r = u + 0x7FFFu + ((u >> 16) & 1u);
  return (unsigned short)(r >> 16);
}
__device__ inline float bf2f(unsigned short s) {
  unsigned u = ((unsigned)s) << 16;
  return __builtin_bit_cast(float, u);
}

// ---------------- phase 1: LDS-binned edge partition ----------------
__global__ __launch_bounds__(256) void k_bin(const int* __restrict__ src,
                                             const int* __restrict__ dst,
                                             int* __restrict__ gcur,
                                             unsigned* __restrict__ pairs) {
  __shared__ int cnt[NBUK];
  __shared__ int lo[NBUK];
  __shared__ int gbase[NBUK];
  __shared__ int ts[256];
  __shared__ unsigned stage[TILE];
  const int tid = threadIdx.x;
  const int e0 = blockIdx.x * TILE;
  const int m = min(TILE, NE - e0);

  for (int i = tid; i < NBUK; i += 256) cnt[i] = 0;
  __syncthreads();
  for (int i = tid; i < m; i += 256) {
    int d = dst[e0 + i];
    atomicAdd(&cnt[d >> 9], 1);
  }
  __syncthreads();
  int c = (tid < NBUK) ? cnt[tid] : 0;
  ts[tid] = c;
  __syncthreads();
  for (int d = 1; d < 256; d <<= 1) {
    int v = (tid >= d) ? ts[tid - d] : 0;
    __syncthreads();
    ts[tid] += v;
    __syncthreads();
  }
  if (tid < NBUK) {
    int ex = ts[tid] - c;
    lo[tid] = ex;
    gbase[tid] = atomicAdd(&gcur[tid], c);
    cnt[tid] = ex;
  }
  __syncthreads();
  for (int i = tid; i < m; i += 256) {
    int d = dst[e0 + i];
    int s = src[e0 + i];
    int b = d >> 9;
    int pos = atomicAdd(&cnt[b], 1);
    stage[pos] = ((unsigned)(d & 511) << 17) | (unsigned)s;
  }
  __syncthreads();
  for (int i = tid; i < m; i += 256) {
    int a = 0, z = NBUK - 1;
    while (a < z) {
      int mid = (a + z + 1) >> 1;
      if (lo[mid] <= i) a = mid; else z = mid - 1;
    }
    int rel = gbase[a] + (i - lo[a]);
    if (rel < CAP) pairs[(size_t)a * CAP + rel] = stage[i];
  }
}

// ---------------- phase 1.5: scan bucket counts ----------------
__global__ __launch_bounds__(256) void k_bscan(const int* __restrict__ gcur,
                                               int* __restrict__ bucketBase) {
  __shared__ int ts[256];
  const int tid = threadIdx.x;
  int c = (tid < NBUK) ? min(gcur[tid], CAP) : 0;
  ts[tid] = c;
  __syncthreads();
  for (int d = 1; d < 256; d <<= 1) {
    int v = (tid >= d) ? ts[tid - d] : 0;
    __syncthreads();
    ts[tid] += v;
    __syncthreads();
  }
  if (tid < NBUK) bucketBase[tid] = ts[tid] - c;
}

// ---------------- phase 2: per-bucket CSR build (512 threads) ----------------
__global__ __launch_bounds__(512) void k_build(const unsigned* __restrict__ pairs,
                                               const int* __restrict__ gcur,
                                               const int* __restrict__ bucketBase,
                                               int* __restrict__ deg,
                                               int* __restrict__ offset,
                                               int* __restrict__ csr) {
  __shared__ int hist[512];
  __shared__ int ts[512];
  __shared__ unsigned stage[CAP];
  const int tid = threadIdx.x;
  const int b = blockIdx.x;
  const int count = min(gcur[b], CAP);
  const int nbase = b * 512;
  const int nloc = min(512, NN - nbase);
  const unsigned* pb = pairs + (size_t)b * CAP;
  const int obase = bucketBase[b];

  hist[tid] = 0;
  __syncthreads();
  for (int i = tid; i < count; i += 512) {
    atomicAdd(&hist[pb[i] >> 17], 1);
  }
  __syncthreads();
  int s = hist[tid];
  ts[tid] = s;
  __syncthreads();
  for (int d = 1; d < 512; d <<= 1) {
    int v = (tid >= d) ? ts[tid - d] : 0;
    __syncthreads();
    ts[tid] += v;
    __syncthreads();
  }
  int ex = ts[tid] - s;
  if (tid < nloc) {
    deg[nbase + tid] = s;
    offset[nbase + tid] = obase + ex;
  }
  __syncthreads();
  hist[tid] = ex;
  __syncthreads();
  for (int i = tid; i < count; i += 512) {
    unsigned e = pb[i];
    int pos = atomicAdd(&hist[e >> 17], 1);
    stage[pos] = e & 0x1FFFFu;
  }
  __syncthreads();
  for (int i = tid; i < count; i += 512) csr[obase + i] = (int)stage[i];
}

// ---------------- weight + BN-param prep ----------------
// w1c[o][k]: k<64 w1l, k>=64 w1r. w2c[o][k]: o<64 w2l -> t, o>=64 w2r -> r2.
// bn[0..127]=SC1, [128..255]=SH1 (b1l folded), [256..319]=SC2, [320..383]=SH2 (b2l folded).
__global__ __launch_bounds__(256) void k_wprep(const float* __restrict__ w1l,
                                               const float* __restrict__ w1r,
                                               const float* __restrict__ w2l,
                                               const float* __restrict__ w2r,
                                               const float* __restrict__ b1l,
                                               const float* __restrict__ g1,
                                               const float* __restrict__ be1,
                                               const float* __restrict__ m1,
                                               const float* __restrict__ v1,
                                               const float* __restrict__ b2l,
                                               const float* __restrict__ g2,
                                               const float* __restrict__ be2,
                                               const float* __restrict__ m2,
                                               const float* __restrict__ v2,
                                               unsigned short* __restrict__ w1c,
                                               unsigned short* __restrict__ w2c,
                                               float* __restrict__ bn) {
  int i = blockIdx.x * 256 + threadIdx.x;  // 0..16383
  int o = i >> 7, k = i & 127;
  float vv1 = (k < 64) ? w1l[o * 64 + k] : w1r[o * 64 + (k - 64)];
  w1c[i] = f2bf(vv1);
  float vv2 = (o < 64) ? w2l[o * 128 + k] : w2r[(o - 64) * 128 + k];
  w2c[i] = f2bf(vv2);
  if (i < 128) {
    float sc = g1[i] * rsqrtf(v1[i] + EPSV);
    bn[i] = sc;
    bn[128 + i] = (b1l[i] - m1[i]) * sc + be1[i];
  }
  if (i < 64) {
    float sc = g2[i] * rsqrtf(v2[i] + EPSV);
    bn[256 + i] = sc;
    bn[320 + i] = (b2l[i] - m2[i]) * sc + be2[i];
  }
}

// ---------------- convert x -> bf16 ----------------
__global__ __launch_bounds__(256) void k_cvtx(const float* __restrict__ x,
                                              unsigned short* __restrict__ xb) {
  int i = blockIdx.x * 256 + threadIdx.x;
  float4 v = *(const float4*)(x + (size_t)i * 4);
  ushort4 o;
  o.x = f2bf(v.x); o.y = f2bf(v.y); o.z = f2bf(v.z); o.w = f2bf(v.w);
  *(ushort4*)(xb + (size_t)i * 4) = o;
}

// ---------------- mean-aggregate: 8 lanes/node, 16B per lane ----------------
__global__ __launch_bounds__(256) void k_aggregate(const unsigned short* __restrict__ xb,
                                                   const int* __restrict__ deg,
                                                   const int* __restrict__ offset,
                                                   const int* __restrict__ csr,
                                                   unsigned short* __restrict__ aggB) {
  int tid = threadIdx.x;
  int node = blockIdx.x * 32 + (tid >> 3);
  int j = tid & 7;
  int cnt = deg[node];
  const int* arow = csr + offset[node];
  float a0=0.f,a1=0.f,a2=0.f,a3=0.f,a4=0.f,a5=0.f,a6=0.f,a7=0.f;
  int k = 0;
  for (; k + 4 <= cnt; k += 4) {
    int s0 = arow[k], s1 = arow[k+1], s2 = arow[k+2], s3 = arow[k+3];
    uint4 v0 = *(const uint4*)(xb + (size_t)s0 * 64 + j * 8);
    uint4 v1 = *(const uint4*)(xb + (size_t)s1 * 64 + j * 8);
    uint4 v2 = *(const uint4*)(xb + (size_t)s2 * 64 + j * 8);
    uint4 v3 = *(const uint4*)(xb + (size_t)s3 * 64 + j * 8);
    a0 += bf2f(v0.x & 0xffff) + bf2f(v1.x & 0xffff) + bf2f(v2.x & 0xffff) + bf2f(v3.x & 0xffff);
    a1 += bf2f(v0.x >> 16)    + bf2f(v1.x >> 16)    + bf2f(v2.x >> 16)    + bf2f(v3.x >> 16);
    a2 += bf2f(v0.y & 0xffff) + bf2f(v1.y & 0xffff) + bf2f(v2.y & 0xffff) + bf2f(v3.y & 0xffff);
    a3 += bf2f(v0.y >> 16)    + bf2f(v1.y >> 16)    + bf2f(v2.y >> 16)    + bf2f(v3.y >> 16);
    a4 += bf2f(v0.z & 0xffff) + bf2f(v1.z & 0xffff) + bf2f(v2.z & 0xffff) + bf2f(v3.z & 0xffff);
    a5 += bf2f(v0.z >> 16)    + bf2f(v1.z >> 16)    + bf2f(v2.z >> 16)    + bf2f(v3.z >> 16);
    a6 += bf2f(v0.w & 0xffff) + bf2f(v1.w & 0xffff) + bf2f(v2.w & 0xffff) + bf2f(v3.w & 0xffff);
    a7 += bf2f(v0.w >> 16)    + bf2f(v1.w >> 16)    + bf2f(v2.w >> 16)    + bf2f(v3.w >> 16);
  }
  for (; k < cnt; ++k) {
    int s = arow[k];
    uint4 v = *(const uint4*)(xb + (size_t)s * 64 + j * 8);
    a0 += bf2f(v.x & 0xffff); a1 += bf2f(v.x >> 16);
    a2 += bf2f(v.y & 0xffff); a3 += bf2f(v.y >> 16);
    a4 += bf2f(v.z & 0xffff); a5 += bf2f(v.z >> 16);
    a6 += bf2f(v.w & 0xffff); a7 += bf2f(v.w >> 16);
  }
  float inv = 1.0f / fmaxf((float)cnt, 1.0f);
  ushort4 r0, r1;
  r0.x = f2bf(a0 * inv); r0.y = f2bf(a1 * inv); r0.z = f2bf(a2 * inv); r0.w = f2bf(a3 * inv);
  r1.x = f2bf(a4 * inv); r1.y = f2bf(a5 * inv); r1.z = f2bf(a6 * inv); r1.w = f2bf(a7 * inv);
  *(ushort4*)(aggB + (size_t)node * 64 + j * 8) = r0;
  *(ushort4*)(aggB + (size_t)node * 64 + j * 8 + 4) = r1;
}

// ---------------- fused MFMA: weights staged in LDS (fragment-major, time-muxed) ----------------
// 6 waves/block, 32 nodes/wave. LDS: 32KB weights + 48KB h = 80KB -> 2 blocks/CU.
__global__ __launch_bounds__(384) void k_gemm12(const unsigned short* __restrict__ aggB,
                                                const unsigned short* __restrict__ xb,
                                                const unsigned short* __restrict__ w1c,
                                                const unsigned short* __restrict__ w2c,
                                                const float* __restrict__ bn,
                                                unsigned short* __restrict__ t,
                                                float* __restrict__ r2) {
  __shared__ unsigned short wlds[32 * 512];        // 32KB: frag f (0..31) at f*512, lane*8
  __shared__ unsigned short hlds[GW][2][16 * 128]; // 48KB
  const int tid = threadIdx.x;
  const int w = tid / 64;
  const int lane = tid & 63;
  const int lr = lane & 15;
  const int q = lane >> 4;
  const int base = blockIdx.x * (GW * 32) + w * 32;
  const int nA = base + lr, nB = base + 16 + lr;
  const int cA = min(nA, NN - 1), cB = min(nB, NN - 1);
  const int swz = (lr & 7) << 4;

  // issue activation loads first (latency hides under weight staging + barrier)
  bf16x8 fA[4], fB[4];
  {
    const unsigned short* a = aggB + (size_t)cA * 64 + q * 8;
    const unsigned short* xx = xb + (size_t)cA * 64 + q * 8;
    fA[0] = *(const bf16x8*)a;        fA[1] = *(const bf16x8*)(a + 32);
    fA[2] = *(const bf16x8*)xx;       fA[3] = *(const bf16x8*)(xx + 32);
  }
  {
    const unsigned short* a = aggB + (size_t)cB * 64 + q * 8;
    const unsigned short* xx = xb + (size_t)cB * 64 + q * 8;
    fB[0] = *(const bf16x8*)a;        fB[1] = *(const bf16x8*)(a + 32);
    fB[2] = *(const bf16x8*)xx;       fB[3] = *(const bf16x8*)(xx + 32);
  }

  // stage w1c fragment-major: frag f=(ot*4+chunk), lane l -> w1c[(ot*16+l&15)*128 + chunk*32 + (l>>4)*8]
  for (int idx = tid; idx < 2048; idx += 384) {
    int f = idx >> 6, l = idx & 63;
    int gofs = ((f >> 2) * 16 + (l & 15)) * 128 + (f & 3) * 32 + (l >> 4) * 8;
    *(uint4*)&wlds[idx * 8] = *(const uint4*)&w1c[gofs];
  }
  __syncthreads();

  char* ldsA = (char*)&hlds[w][0][0];
  char* ldsB = (char*)&hlds[w][1][0];

  // ---- layer 1: h = relu(acc*SC1 + SH1) -> swizzled h-LDS ----
#pragma unroll
  for (int ot = 0; ot < 8; ++ot) {
    const unsigned short* wp = &wlds[(ot * 4) * 512 + lane * 8];
    bf16x8 w0 = *(const bf16x8*)(wp);
    bf16x8 w1 = *(const bf16x8*)(wp + 512);
    bf16x8 w2 = *(const bf16x8*)(wp + 1024);
    bf16x8 w3 = *(const bf16x8*)(wp + 1536);
    f32x4 aA = {0.f, 0.f, 0.f, 0.f}, aB = {0.f, 0.f, 0.f, 0.f};
    aA = __builtin_amdgcn_mfma_f32_16x16x32_bf16(w0, fA[0], aA, 0, 0, 0);
    aA = __builtin_amdgcn_mfma_f32_16x16x32_bf16(w1, fA[1], aA, 0, 0, 0);
    aA = __builtin_amdgcn_mfma_f32_16x16x32_bf16(w2, fA[2], aA, 0, 0, 0);
    aA = __builtin_amdgcn_mfma_f32_16x16x32_bf16(w3, fA[3], aA, 0, 0, 0);
    aB = __builtin_amdgcn_mfma_f32_16x16x32_bf16(w0, fB[0], aB, 0, 0, 0);
    aB = __builtin_amdgcn_mfma_f32_16x16x32_bf16(w1, fB[1], aB, 0, 0, 0);
    aB = __builtin_amdgcn_mfma_f32_16x16x32_bf16(w2, fB[2], aB, 0, 0, 0);
    aB = __builtin_amdgcn_mfma_f32_16x16x32_bf16(w3, fB[3], aB, 0, 0, 0);
    const int o = ot * 16 + q * 4;
    float4 sc = *(const float4*)(bn + o);
    float4 sh = *(const float4*)(bn + 128 + o);
    ushort4 hA, hB;
    hA.x = f2bf(fmaxf(aA[0] * sc.x + sh.x, 0.f));
    hA.y = f2bf(fmaxf(aA[1] * sc.y + sh.y, 0.f));
    hA.z = f2bf(fmaxf(aA[2] * sc.z + sh.z, 0.f));
    hA.w = f2bf(fmaxf(aA[3] * sc.w + sh.w, 0.f));
    hB.x = f2bf(fmaxf(aB[0] * sc.x + sh.x, 0.f));
    hB.y = f2bf(fmaxf(aB[1] * sc.y + sh.y, 0.f));
    hB.z = f2bf(fmaxf(aB[2] * sc.z + sh.z, 0.f));
    hB.w = f2bf(fmaxf(aB[3] * sc.w + sh.w, 0.f));
    const int wb = lr * 256 + ot * 32 + q * 8;
    *(ushort4*)(ldsA + (wb ^ swz)) = hA;
    *(ushort4*)(ldsB + (wb ^ swz)) = hB;
  }
  __syncthreads();

  // stage w2c into the same LDS
  for (int idx = tid; idx < 2048; idx += 384) {
    int f = idx >> 6, l = idx & 63;
    int gofs = ((f >> 2) * 16 + (l & 15)) * 128 + (f & 3) * 32 + (l >> 4) * 8;
    *(uint4*)&wlds[idx * 8] = *(const uint4*)&w2c[gofs];
  }
  __syncthreads();

  // read back h as B-fragments
  bf16x8 hA[4], hB[4];
#pragma unroll
  for (int jj = 0; jj < 4; ++jj) {
    const int rb = lr * 256 + jj * 64 + q * 16;
    hA[jj] = *(const bf16x8*)(ldsA + (rb ^ swz));
    hB[jj] = *(const bf16x8*)(ldsB + (rb ^ swz));
  }

  // ---- layer 2: ot<4 -> t (bf16), ot>=4 -> r2 (fp32, bias folded into BN2) ----
#pragma unroll
  for (int ot = 0; ot < 8; ++ot) {
    const unsigned short* wp = &wlds[(ot * 4) * 512 + lane * 8];
    bf16x8 w0 = *(const bf16x8*)(wp);
    bf16x8 w1 = *(const bf16x8*)(wp + 512);
    bf16x8 w2 = *(const bf16x8*)(wp + 1024);
    bf16x8 w3 = *(const bf16x8*)(wp + 1536);
    f32x4 aA = {0.f, 0.f, 0.f, 0.f}, aB = {0.f, 0.f, 0.f, 0.f};
    aA = __builtin_amdgcn_mfma_f32_16x16x32_bf16(w0, hA[0], aA, 0, 0, 0);
    aA = __builtin_amdgcn_mfma_f32_16x16x32_bf16(w1, hA[1], aA, 0, 0, 0);
    aA = __builtin_amdgcn_mfma_f32_16x16x32_bf16(w2, hA[2], aA, 0, 0, 0);
    aA = __builtin_amdgcn_mfma_f32_16x16x32_bf16(w3, hA[3], aA, 0, 0, 0);
    aB = __builtin_amdgcn_mfma_f32_16x16x32_bf16(w0, hB[0], aB, 0, 0, 0);
    aB = __builtin_amdgcn_mfma_f32_16x16x32_bf16(w1, hB[1], aB, 0, 0, 0);
    aB = __builtin_amdgcn_mfma_f32_16x16x32_bf16(w2, hB[2], aB, 0, 0, 0);
    aB = __builtin_amdgcn_mfma_f32_16x16x32_bf16(w3, hB[3], aB, 0, 0, 0);
    if (ot < 4) {
      const int o = ot * 16 + q * 4;
      ushort4 tv;
      tv.x = f2bf(aA[0]); tv.y = f2bf(aA[1]); tv.z = f2bf(aA[2]); tv.w = f2bf(aA[3]);
      if (nA < NN) *(ushort4*)(t + (size_t)nA * 64 + o) = tv;
      tv.x = f2bf(aB[0]); tv.y = f2bf(aB[1]); tv.z = f2bf(aB[2]); tv.w = f2bf(aB[3]);
      if (nB < NN) *(ushort4*)(t + (size_t)nB * 64 + o) = tv;
    } else {
      const int o = (ot - 4) * 16 + q * 4;
      float4 rv;
      rv.x = aA[0]; rv.y = aA[1]; rv.z = aA[2]; rv.w = aA[3];
      if (nA < NN) *(float4*)(r2 + (size_t)nA * 64 + o) = rv;
      rv.x = aB[0]; rv.y = aB[1]; rv.z = aB[2]; rv.w = aB[3];
      if (nB < NN) *(float4*)(r2 + (size_t)nB * 64 + o) = rv;
    }
  }
}

// ---------------- layer2 aggregate (bf16 t) + BN2: 8 lanes/node ----------------
__global__ __launch_bounds__(256) void k_agg2fin(const unsigned short* __restrict__ t,
                                                 const int* __restrict__ deg,
                                                 const int* __restrict__ offset,
                                                 const int* __restrict__ csr,
                                                 const float* __restrict__ r2,
                                                 const float* __restrict__ bn,
                                                 float* __restrict__ outp) {
  int tid = threadIdx.x;
  int node = blockIdx.x * 32 + (tid >> 3);
  int j = tid & 7;
  int cnt = deg[node];
  const int* arow = csr + offset[node];
  float a0=0.f,a1=0.f,a2=0.f,a3=0.f,a4=0.f,a5=0.f,a6=0.f,a7=0.f;
  int k = 0;
  for (; k + 4 <= cnt; k += 4) {
    int s0 = arow[k], s1 = arow[k+1], s2 = arow[k+2], s3 = arow[k+3];
    uint4 v0 = *(const uint4*)(t + (size_t)s0 * 64 + j * 8);
    uint4 v1 = *(const uint4*)(t + (size_t)s1 * 64 + j * 8);
    uint4 v2 = *(const uint4*)(t + (size_t)s2 * 64 + j * 8);
    uint4 v3 = *(const uint4*)(t + (size_t)s3 * 64 + j * 8);
    a0 += bf2f(v0.x & 0xffff) + bf2f(v1.x & 0xffff) + bf2f(v2.x & 0xffff) + bf2f(v3.x & 0xffff);
    a1 += bf2f(v0.x >> 16)    + bf2f(v1.x >> 16)    + bf2f(v2.x >> 16)    + bf2f(v3.x >> 16);
    a2 += bf2f(v0.y & 0xffff) + bf2f(v1.y & 0xffff) + bf2f(v2.y & 0xffff) + bf2f(v3.y & 0xffff);
    a3 += bf2f(v0.y >> 16)    + bf2f(v1.y >> 16)    + bf2f(v2.y >> 16)    + bf2f(v3.y >> 16);
    a4 += bf2f(v0.z & 0xffff) + bf2f(v1.z & 0xffff) + bf2f(v2.z & 0xffff) + bf2f(v3.z & 0xffff);
    a5 += bf2f(v0.z >> 16)    + bf2f(v1.z >> 16)    + bf2f(v2.z >> 16)    + bf2f(v3.z >> 16);
    a6 += bf2f(v0.w & 0xffff) + bf2f(v1.w & 0xffff) + bf2f(v2.w & 0xffff) + bf2f(v3.w & 0xffff);
    a7 += bf2f(v0.w >> 16)    + bf2f(v1.w >> 16)    + bf2f(v2.w >> 16)    + bf2f(v3.w >> 16);
  }
  for (; k < cnt; ++k) {
    int s = arow[k];
    uint4 v = *(const uint4*)(t + (size_t)s * 64 + j * 8);
    a0 += bf2f(v.x & 0xffff); a1 += bf2f(v.x >> 16);
    a2 += bf2f(v.y & 0xffff); a3 += bf2f(v.y >> 16);
    a4 += bf2f(v.z & 0xffff); a5 += bf2f(v.z >> 16);
    a6 += bf2f(v.w & 0xffff); a7 += bf2f(v.w >> 16);
  }
  float inv = 1.0f / fmaxf((float)cnt, 1.0f);
  int o = j * 8;
  float4 ra = *(const float4*)(r2 + (size_t)node * 64 + o);
  float4 rb = *(const float4*)(r2 + (size_t)node * 64 + o + 4);
  float4 sca = *(const float4*)(bn + 256 + o);
  float4 scb = *(const float4*)(bn + 256 + o + 4);
  float4 sha = *(const float4*)(bn + 320 + o);
  float4 shb = *(const float4*)(bn + 320 + o + 4);
  float4 o0, o1;
  o0.x = (a0 * inv + ra.x) * sca.x + sha.x;
  o0.y = (a1 * inv + ra.y) * sca.y + sha.y;
  o0.z = (a2 * inv + ra.z) * sca.z + sha.z;
  o0.w = (a3 * inv + ra.w) * sca.w + sha.w;
  o1.x = (a4 * inv + rb.x) * scb.x + shb.x;
  o1.y = (a5 * inv + rb.y) * scb.y + shb.y;
  o1.z = (a6 * inv + rb.z) * scb.z + shb.z;
  o1.w = (a7 * inv + rb.w) * scb.w + shb.w;
  *(float4*)(outp + (size_t)node * 64 + o) = o0;
  *(float4*)(outp + (size_t)node * 64 + o + 4) = o1;
}

extern "C" void kernel_launch(void* const* d_in, const int* in_sizes, int n_in,
                              void* d_out, int out_size, void* d_ws, size_t ws_size,
                              hipStream_t stream) {
  const float* x   = (const float*)d_in[0];
  const int*   ei  = (const int*)d_in[1];
  const float* w1l = (const float*)d_in[2];
  const float* b1l = (const float*)d_in[3];
  const float* w1r = (const float*)d_in[4];
  const float* g1  = (const float*)d_in[5];
  const float* be1 = (const float*)d_in[6];
  const float* m1  = (const float*)d_in[7];
  const float* v1  = (const float*)d_in[8];
  const float* w2l = (const float*)d_in[9];
  const float* b2l = (const float*)d_in[10];
  const float* w2r = (const float*)d_in[11];
  const float* g2  = (const float*)d_in[12];
  const float* be2 = (const float*)d_in[13];
  const float* m2  = (const float*)d_in[14];
  const float* v2  = (const float*)d_in[15];
  float* outp = (float*)d_out;

  char* ws = (char*)d_ws;
  // layout (bytes), 16B-aligned:
  //           0 : gcur       (1,024)
  //       1,024 : bucketBase (1,024)
  //       2,048 : deg        (400,000)
  //     402,048 : offset     (400,000)
  //     802,048 : pairs      (7,225,344)   -> 8,027,392
  //   8,027,392 : csr        (6,400,000)   -> 14,427,392
  //  14,427,392 : w1c bf16   (32,768)      -> 14,460,160
  //  14,460,160 : w2c bf16   (32,768)      -> 14,492,928
  //  14,492,928 : bn  fp32   (2,048)       -> 14,494,976
  //  14,494,976 : xb  bf16   (12,800,000)  -> 27,294,976
  //  27,294,976 : aggB bf16  (12,800,000)  -> 40,094,976
  //  40,094,976 : t   bf16   (12,800,000)  -> 52,894,976
  //  52,894,976 : r2  fp32   (25,600,000)  -> 78,494,976  (~78.5 MB)
  int*            gcur       = (int*)ws;
  int*            bucketBase = (int*)(ws + 1024);
  int*            deg        = (int*)(ws + 2048);
  int*            offset     = (int*)(ws + 402048);
  unsigned*       pairs      = (unsigned*)(ws + 802048);
  int*            csr        = (int*)(ws + 8027392);
  unsigned short* w1c        = (unsigned short*)(ws + 14427392);
  unsigned short* w2c        = (unsigned short*)(ws + 14460160);
  float*          bn         = (float*)(ws + 14492928);
  unsigned short* xb         = (unsigned short*)(ws + 14494976);
  unsigned short* aggB       = (unsigned short*)(ws + 27294976);
  unsigned short* t          = (unsigned short*)(ws + 40094976);
  float*          r2         = (float*)(ws + 52894976);

  const int* srcp = ei;
  const int* dstp = ei + NE;

  hipMemsetAsync(gcur, 0, NBUK * sizeof(int), stream);
  hipLaunchKernelGGL(k_bin, dim3(NTIL), dim3(256), 0, stream,
                     srcp, dstp, gcur, pairs);
  hipLaunchKernelGGL(k_bscan, dim3(1), dim3(256), 0, stream, gcur, bucketBase);
  hipLaunchKernelGGL(k_build, dim3(NBUK), dim3(512), 0, stream,
                     pairs, gcur, bucketBase, deg, offset, csr);
  hipLaunchKernelGGL(k_wprep, dim3(64), dim3(256), 0, stream,
                     w1l, w1r, w2l, w2r, b1l, g1, be1, m1, v1,
                     b2l, g2, be2, m2, v2, w1c, w2c, bn);
  hipLaunchKernelGGL(k_cvtx, dim3(NN * 64 / 1024), dim3(256), 0, stream, x, xb);
  hipLaunchKernelGGL(k_aggregate, dim3(NN / 32), dim3(256), 0, stream,
                     xb, deg, offset, csr, aggB);
  hipLaunchKernelGGL(k_gemm12, dim3((NN + GW * 32 - 1) / (GW * 32)), dim3(384), 0, stream,
                     aggB, xb, w1c, w2c, bn, t, r2);
  hipLaunchKernelGGL(k_agg2fin, dim3(NN / 32), dim3(256), 0, stream,
                     t, deg, offset, csr, r2, bn, outp);
}

// Round 10
// 150.062 us; speedup vs baseline: 3.6144x; 1.0523x over previous
//
#include <hip/hip_runtime.h>

#define NN 100000
#define NE 1600000
#define EPSV 1e-5f

#define NBUK 196       // buckets of 512 nodes: bucket = dst >> 9
#define TILE 2048      // edges per k_bin workgroup
#define NTIL 782       // ceil(NE / TILE)
#define CAP  9216      // per-bucket capacity

typedef __attribute__((ext_vector_type(8))) short bf16x8;
typedef __attribute__((ext_vector_type(4))) float f32x4;

__device__ inline unsigned short f2bf(float f) {
  unsigned u = __builtin_bit_cast(unsigned, f);
  unsigned r = u + 0x7FFFu + ((u >> 16) & 1u);
  return (unsigned short)(r >> 16);
}
__device__ inline float bf2f(unsigned short s) {
  unsigned u = ((unsigned)s) << 16;
  return __builtin_bit_cast(float, u);
}

// ---------------- phase 1: LDS-binned edge partition ----------------
__global__ __launch_bounds__(256) void k_bin(const int* __restrict__ src,
                                             const int* __restrict__ dst,
                                             int* __restrict__ gcur,
                                             unsigned* __restrict__ pairs) {
  __shared__ int cnt[NBUK];
  __shared__ int lo[NBUK];
  __shared__ int gbase[NBUK];
  __shared__ int ts[256];
  __shared__ unsigned stage[TILE];
  const int tid = threadIdx.x;
  const int e0 = blockIdx.x * TILE;
  const int m = min(TILE, NE - e0);

  for (int i = tid; i < NBUK; i += 256) cnt[i] = 0;
  __syncthreads();
  for (int i = tid; i < m; i += 256) {
    int d = dst[e0 + i];
    atomicAdd(&cnt[d >> 9], 1);
  }
  __syncthreads();
  int c = (tid < NBUK) ? cnt[tid] : 0;
  ts[tid] = c;
  __syncthreads();
  for (int d = 1; d < 256; d <<= 1) {
    int v = (tid >= d) ? ts[tid - d] : 0;
    __syncthreads();
    ts[tid] += v;
    __syncthreads();
  }
  if (tid < NBUK) {
    int ex = ts[tid] - c;
    lo[tid] = ex;
    gbase[tid] = atomicAdd(&gcur[tid], c);
    cnt[tid] = ex;
  }
  __syncthreads();
  for (int i = tid; i < m; i += 256) {
    int d = dst[e0 + i];
    int s = src[e0 + i];
    int b = d >> 9;
    int pos = atomicAdd(&cnt[b], 1);
    stage[pos] = ((unsigned)(d & 511) << 17) | (unsigned)s;
  }
  __syncthreads();
  for (int i = tid; i < m; i += 256) {
    int a = 0, z = NBUK - 1;
    while (a < z) {
      int mid = (a + z + 1) >> 1;
      if (lo[mid] <= i) a = mid; else z = mid - 1;
    }
    int rel = gbase[a] + (i - lo[a]);
    if (rel < CAP) pairs[(size_t)a * CAP + rel] = stage[i];
  }
}

// ---------------- phase 1.5: scan bucket counts ----------------
__global__ __launch_bounds__(256) void k_bscan(const int* __restrict__ gcur,
                                               int* __restrict__ bucketBase) {
  __shared__ int ts[256];
  const int tid = threadIdx.x;
  int c = (tid < NBUK) ? min(gcur[tid], CAP) : 0;
  ts[tid] = c;
  __syncthreads();
  for (int d = 1; d < 256; d <<= 1) {
    int v = (tid >= d) ? ts[tid - d] : 0;
    __syncthreads();
    ts[tid] += v;
    __syncthreads();
  }
  if (tid < NBUK) bucketBase[tid] = ts[tid] - c;
}

// ---------------- phase 2: per-bucket CSR build (512 threads) ----------------
__global__ __launch_bounds__(512) void k_build(const unsigned* __restrict__ pairs,
                                               const int* __restrict__ gcur,
                                               const int* __restrict__ bucketBase,
                                               int* __restrict__ deg,
                                               int* __restrict__ offset,
                                               int* __restrict__ csr) {
  __shared__ int hist[512];
  __shared__ int ts[512];
  __shared__ unsigned stage[CAP];
  const int tid = threadIdx.x;
  const int b = blockIdx.x;
  const int count = min(gcur[b], CAP);
  const int nbase = b * 512;
  const int nloc = min(512, NN - nbase);
  const unsigned* pb = pairs + (size_t)b * CAP;
  const int obase = bucketBase[b];

  hist[tid] = 0;
  __syncthreads();
  for (int i = tid; i < count; i += 512) {
    atomicAdd(&hist[pb[i] >> 17], 1);
  }
  __syncthreads();
  int s = hist[tid];
  ts[tid] = s;
  __syncthreads();
  for (int d = 1; d < 512; d <<= 1) {
    int v = (tid >= d) ? ts[tid - d] : 0;
    __syncthreads();
    ts[tid] += v;
    __syncthreads();
  }
  int ex = ts[tid] - s;
  if (tid < nloc) {
    deg[nbase + tid] = s;
    offset[nbase + tid] = obase + ex;
  }
  __syncthreads();
  hist[tid] = ex;
  __syncthreads();
  for (int i = tid; i < count; i += 512) {
    unsigned e = pb[i];
    int pos = atomicAdd(&hist[e >> 17], 1);
    stage[pos] = e & 0x1FFFFu;
  }
  __syncthreads();
  for (int i = tid; i < count; i += 512) csr[obase + i] = (int)stage[i];
}

// ---------------- weight + BN-param prep ----------------
// w1c[o][k]: k<64 w1l, k>=64 w1r. w2c[o][k]: o<64 w2l -> t, o>=64 w2r -> r2.
// bn[0..127]=SC1, [128..255]=SH1 (b1l folded), [256..319]=SC2, [320..383]=SH2 (b2l folded).
__global__ __launch_bounds__(256) void k_wprep(const float* __restrict__ w1l,
                                               const float* __restrict__ w1r,
                                               const float* __restrict__ w2l,
                                               const float* __restrict__ w2r,
                                               const float* __restrict__ b1l,
                                               const float* __restrict__ g1,
                                               const float* __restrict__ be1,
                                               const float* __restrict__ m1,
                                               const float* __restrict__ v1,
                                               const float* __restrict__ b2l,
                                               const float* __restrict__ g2,
                                               const float* __restrict__ be2,
                                               const float* __restrict__ m2,
                                               const float* __restrict__ v2,
                                               unsigned short* __restrict__ w1c,
                                               unsigned short* __restrict__ w2c,
                                               float* __restrict__ bn) {
  int i = blockIdx.x * 256 + threadIdx.x;  // 0..16383
  int o = i >> 7, k = i & 127;
  float vv1 = (k < 64) ? w1l[o * 64 + k] : w1r[o * 64 + (k - 64)];
  w1c[i] = f2bf(vv1);
  float vv2 = (o < 64) ? w2l[o * 128 + k] : w2r[(o - 64) * 128 + k];
  w2c[i] = f2bf(vv2);
  if (i < 128) {
    float sc = g1[i] * rsqrtf(v1[i] + EPSV);
    bn[i] = sc;
    bn[128 + i] = (b1l[i] - m1[i]) * sc + be1[i];
  }
  if (i < 64) {
    float sc = g2[i] * rsqrtf(v2[i] + EPSV);
    bn[256 + i] = sc;
    bn[320 + i] = (b2l[i] - m2[i]) * sc + be2[i];
  }
}

// ---------------- convert x -> bf16 ----------------
__global__ __launch_bounds__(256) void k_cvtx(const float* __restrict__ x,
                                              unsigned short* __restrict__ xb) {
  int i = blockIdx.x * 256 + threadIdx.x;
  float4 v = *(const float4*)(x + (size_t)i * 4);
  ushort4 o;
  o.x = f2bf(v.x); o.y = f2bf(v.y); o.z = f2bf(v.z); o.w = f2bf(v.w);
  *(ushort4*)(xb + (size_t)i * 4) = o;
}

// ---------------- mean-aggregate: 8 lanes/node, 16B per lane ----------------
__global__ __launch_bounds__(256) void k_aggregate(const unsigned short* __restrict__ xb,
                                                   const int* __restrict__ deg,
                                                   const int* __restrict__ offset,
                                                   const int* __restrict__ csr,
                                                   unsigned short* __restrict__ aggB) {
  int tid = threadIdx.x;
  int node = blockIdx.x * 32 + (tid >> 3);
  int j = tid & 7;
  int cnt = deg[node];
  const int* arow = csr + offset[node];
  float a0=0.f,a1=0.f,a2=0.f,a3=0.f,a4=0.f,a5=0.f,a6=0.f,a7=0.f;
  int k = 0;
  for (; k + 4 <= cnt; k += 4) {
    int s0 = arow[k], s1 = arow[k+1], s2 = arow[k+2], s3 = arow[k+3];
    uint4 v0 = *(const uint4*)(xb + (size_t)s0 * 64 + j * 8);
    uint4 v1 = *(const uint4*)(xb + (size_t)s1 * 64 + j * 8);
    uint4 v2 = *(const uint4*)(xb + (size_t)s2 * 64 + j * 8);
    uint4 v3 = *(const uint4*)(xb + (size_t)s3 * 64 + j * 8);
    a0 += bf2f(v0.x & 0xffff) + bf2f(v1.x & 0xffff) + bf2f(v2.x & 0xffff) + bf2f(v3.x & 0xffff);
    a1 += bf2f(v0.x >> 16)    + bf2f(v1.x >> 16)    + bf2f(v2.x >> 16)    + bf2f(v3.x >> 16);
    a2 += bf2f(v0.y & 0xffff) + bf2f(v1.y & 0xffff) + bf2f(v2.y & 0xffff) + bf2f(v3.y & 0xffff);
    a3 += bf2f(v0.y >> 16)    + bf2f(v1.y >> 16)    + bf2f(v2.y >> 16)    + bf2f(v3.y >> 16);
    a4 += bf2f(v0.z & 0xffff) + bf2f(v1.z & 0xffff) + bf2f(v2.z & 0xffff) + bf2f(v3.z & 0xffff);
    a5 += bf2f(v0.z >> 16)    + bf2f(v1.z >> 16)    + bf2f(v2.z >> 16)    + bf2f(v3.z >> 16);
    a6 += bf2f(v0.w & 0xffff) + bf2f(v1.w & 0xffff) + bf2f(v2.w & 0xffff) + bf2f(v3.w & 0xffff);
    a7 += bf2f(v0.w >> 16)    + bf2f(v1.w >> 16)    + bf2f(v2.w >> 16)    + bf2f(v3.w >> 16);
  }
  for (; k < cnt; ++k) {
    int s = arow[k];
    uint4 v = *(const uint4*)(xb + (size_t)s * 64 + j * 8);
    a0 += bf2f(v.x & 0xffff); a1 += bf2f(v.x >> 16);
    a2 += bf2f(v.y & 0xffff); a3 += bf2f(v.y >> 16);
    a4 += bf2f(v.z & 0xffff); a5 += bf2f(v.z >> 16);
    a6 += bf2f(v.w & 0xffff); a7 += bf2f(v.w >> 16);
  }
  float inv = 1.0f / fmaxf((float)cnt, 1.0f);
  ushort4 r0, r1;
  r0.x = f2bf(a0 * inv); r0.y = f2bf(a1 * inv); r0.z = f2bf(a2 * inv); r0.w = f2bf(a3 * inv);
  r1.x = f2bf(a4 * inv); r1.y = f2bf(a5 * inv); r1.z = f2bf(a6 * inv); r1.w = f2bf(a7 * inv);
  *(ushort4*)(aggB + (size_t)node * 64 + j * 8) = r0;
  *(ushort4*)(aggB + (size_t)node * 64 + j * 8 + 4) = r1;
}

// ---------------- fused MFMA: all in-loop operands from LDS ----------------
// 4 waves/block, 32 nodes/wave. LDS: 32KB weights (time-muxed) + 32KB h + 1.5KB bn
// = ~66KB -> 2 blocks/CU. The ot loops contain zero global loads.
__global__ __launch_bounds__(256) void k_gemm12(const unsigned short* __restrict__ aggB,
                                                const unsigned short* __restrict__ xb,
                                                const unsigned short* __restrict__ w1c,
                                                const unsigned short* __restrict__ w2c,
                                                const float* __restrict__ bn,
                                                unsigned short* __restrict__ t,
                                                unsigned short* __restrict__ r2) {
  __shared__ unsigned short wlds[32 * 512];       // 32KB: frag f at f*512, lane*8
  __shared__ unsigned short hlds[4][2][16 * 128]; // 32KB
  __shared__ float bnlds[384];                    // 1.5KB
  const int tid = threadIdx.x;
  const int w = tid >> 6;
  const int lane = tid & 63;
  const int lr = lane & 15;
  const int q = lane >> 4;
  const int base = blockIdx.x * 128 + w * 32;
  const int nA = base + lr, nB = base + 16 + lr;
  const int cA = min(nA, NN - 1), cB = min(nB, NN - 1);
  const int swz = (lr & 7) << 4;

  // issue activation loads first (latency hides under staging + barrier)
  bf16x8 fA[4], fB[4];
  {
    const unsigned short* a = aggB + (size_t)cA * 64 + q * 8;
    const unsigned short* xx = xb + (size_t)cA * 64 + q * 8;
    fA[0] = *(const bf16x8*)a;        fA[1] = *(const bf16x8*)(a + 32);
    fA[2] = *(const bf16x8*)xx;       fA[3] = *(const bf16x8*)(xx + 32);
  }
  {
    const unsigned short* a = aggB + (size_t)cB * 64 + q * 8;
    const unsigned short* xx = xb + (size_t)cB * 64 + q * 8;
    fB[0] = *(const bf16x8*)a;        fB[1] = *(const bf16x8*)(a + 32);
    fB[2] = *(const bf16x8*)xx;       fB[3] = *(const bf16x8*)(xx + 32);
  }

  // stage bn + w1 (fragment-major)
  for (int i = tid; i < 384; i += 256) bnlds[i] = bn[i];
  for (int idx = tid; idx < 2048; idx += 256) {
    int f = idx >> 6, l = idx & 63;
    int gofs = ((f >> 2) * 16 + (l & 15)) * 128 + (f & 3) * 32 + (l >> 4) * 8;
    *(uint4*)&wlds[idx * 8] = *(const uint4*)&w1c[gofs];
  }
  __syncthreads();

  char* ldsA = (char*)&hlds[w][0][0];
  char* ldsB = (char*)&hlds[w][1][0];

  // ---- layer 1 ----
#pragma unroll
  for (int ot = 0; ot < 8; ++ot) {
    const unsigned short* wp = &wlds[(ot * 4) * 512 + lane * 8];
    bf16x8 w0 = *(const bf16x8*)(wp);
    bf16x8 w1 = *(const bf16x8*)(wp + 512);
    bf16x8 w2 = *(const bf16x8*)(wp + 1024);
    bf16x8 w3 = *(const bf16x8*)(wp + 1536);
    f32x4 aA = {0.f, 0.f, 0.f, 0.f}, aB = {0.f, 0.f, 0.f, 0.f};
    aA = __builtin_amdgcn_mfma_f32_16x16x32_bf16(w0, fA[0], aA, 0, 0, 0);
    aA = __builtin_amdgcn_mfma_f32_16x16x32_bf16(w1, fA[1], aA, 0, 0, 0);
    aA = __builtin_amdgcn_mfma_f32_16x16x32_bf16(w2, fA[2], aA, 0, 0, 0);
    aA = __builtin_amdgcn_mfma_f32_16x16x32_bf16(w3, fA[3], aA, 0, 0, 0);
    aB = __builtin_amdgcn_mfma_f32_16x16x32_bf16(w0, fB[0], aB, 0, 0, 0);
    aB = __builtin_amdgcn_mfma_f32_16x16x32_bf16(w1, fB[1], aB, 0, 0, 0);
    aB = __builtin_amdgcn_mfma_f32_16x16x32_bf16(w2, fB[2], aB, 0, 0, 0);
    aB = __builtin_amdgcn_mfma_f32_16x16x32_bf16(w3, fB[3], aB, 0, 0, 0);
    const int o = ot * 16 + q * 4;
    float4 sc = *(const float4*)&bnlds[o];
    float4 sh = *(const float4*)&bnlds[128 + o];
    ushort4 hA, hB;
    hA.x = f2bf(fmaxf(aA[0] * sc.x + sh.x, 0.f));
    hA.y = f2bf(fmaxf(aA[1] * sc.y + sh.y, 0.f));
    hA.z = f2bf(fmaxf(aA[2] * sc.z + sh.z, 0.f));
    hA.w = f2bf(fmaxf(aA[3] * sc.w + sh.w, 0.f));
    hB.x = f2bf(fmaxf(aB[0] * sc.x + sh.x, 0.f));
    hB.y = f2bf(fmaxf(aB[1] * sc.y + sh.y, 0.f));
    hB.z = f2bf(fmaxf(aB[2] * sc.z + sh.z, 0.f));
    hB.w = f2bf(fmaxf(aB[3] * sc.w + sh.w, 0.f));
    const int wb = lr * 256 + ot * 32 + q * 8;
    *(ushort4*)(ldsA + (wb ^ swz)) = hA;
    *(ushort4*)(ldsB + (wb ^ swz)) = hB;
  }
  __syncthreads();

  // stage w2 into the same LDS
  for (int idx = tid; idx < 2048; idx += 256) {
    int f = idx >> 6, l = idx & 63;
    int gofs = ((f >> 2) * 16 + (l & 15)) * 128 + (f & 3) * 32 + (l >> 4) * 8;
    *(uint4*)&wlds[idx * 8] = *(const uint4*)&w2c[gofs];
  }
  __syncthreads();

  // read back h as B-fragments
  bf16x8 hA[4], hB[4];
#pragma unroll
  for (int jj = 0; jj < 4; ++jj) {
    const int rb = lr * 256 + jj * 64 + q * 16;
    hA[jj] = *(const bf16x8*)(ldsA + (rb ^ swz));
    hB[jj] = *(const bf16x8*)(ldsB + (rb ^ swz));
  }

  // ---- layer 2: ot<4 -> t (bf16), ot>=4 -> r2 (bf16, bias folded into BN2) ----
#pragma unroll
  for (int ot = 0; ot < 8; ++ot) {
    const unsigned short* wp = &wlds[(ot * 4) * 512 + lane * 8];
    bf16x8 w0 = *(const bf16x8*)(wp);
    bf16x8 w1 = *(const bf16x8*)(wp + 512);
    bf16x8 w2 = *(const bf16x8*)(wp + 1024);
    bf16x8 w3 = *(const bf16x8*)(wp + 1536);
    f32x4 aA = {0.f, 0.f, 0.f, 0.f}, aB = {0.f, 0.f, 0.f, 0.f};
    aA = __builtin_amdgcn_mfma_f32_16x16x32_bf16(w0, hA[0], aA, 0, 0, 0);
    aA = __builtin_amdgcn_mfma_f32_16x16x32_bf16(w1, hA[1], aA, 0, 0, 0);
    aA = __builtin_amdgcn_mfma_f32_16x16x32_bf16(w2, hA[2], aA, 0, 0, 0);
    aA = __builtin_amdgcn_mfma_f32_16x16x32_bf16(w3, hA[3], aA, 0, 0, 0);
    aB = __builtin_amdgcn_mfma_f32_16x16x32_bf16(w0, hB[0], aB, 0, 0, 0);
    aB = __builtin_amdgcn_mfma_f32_16x16x32_bf16(w1, hB[1], aB, 0, 0, 0);
    aB = __builtin_amdgcn_mfma_f32_16x16x32_bf16(w2, hB[2], aB, 0, 0, 0);
    aB = __builtin_amdgcn_mfma_f32_16x16x32_bf16(w3, hB[3], aB, 0, 0, 0);
    ushort4 tv;
    if (ot < 4) {
      const int o = ot * 16 + q * 4;
      tv.x = f2bf(aA[0]); tv.y = f2bf(aA[1]); tv.z = f2bf(aA[2]); tv.w = f2bf(aA[3]);
      if (nA < NN) *(ushort4*)(t + (size_t)nA * 64 + o) = tv;
      tv.x = f2bf(aB[0]); tv.y = f2bf(aB[1]); tv.z = f2bf(aB[2]); tv.w = f2bf(aB[3]);
      if (nB < NN) *(ushort4*)(t + (size_t)nB * 64 + o) = tv;
    } else {
      const int o = (ot - 4) * 16 + q * 4;
      tv.x = f2bf(aA[0]); tv.y = f2bf(aA[1]); tv.z = f2bf(aA[2]); tv.w = f2bf(aA[3]);
      if (nA < NN) *(ushort4*)(r2 + (size_t)nA * 64 + o) = tv;
      tv.x = f2bf(aB[0]); tv.y = f2bf(aB[1]); tv.z = f2bf(aB[2]); tv.w = f2bf(aB[3]);
      if (nB < NN) *(ushort4*)(r2 + (size_t)nB * 64 + o) = tv;
    }
  }
}

// ---------------- layer2 aggregate (bf16 t) + bf16 r2 + BN2: 8 lanes/node ----------------
__global__ __launch_bounds__(256) void k_agg2fin(const unsigned short* __restrict__ t,
                                                 const int* __restrict__ deg,
                                                 const int* __restrict__ offset,
                                                 const int* __restrict__ csr,
                                                 const unsigned short* __restrict__ r2,
                                                 const float* __restrict__ bn,
                                                 float* __restrict__ outp) {
  int tid = threadIdx.x;
  int node = blockIdx.x * 32 + (tid >> 3);
  int j = tid & 7;
  int cnt = deg[node];
  const int* arow = csr + offset[node];
  float a0=0.f,a1=0.f,a2=0.f,a3=0.f,a4=0.f,a5=0.f,a6=0.f,a7=0.f;
  int k = 0;
  for (; k + 4 <= cnt; k += 4) {
    int s0 = arow[k], s1 = arow[k+1], s2 = arow[k+2], s3 = arow[k+3];
    uint4 v0 = *(const uint4*)(t + (size_t)s0 * 64 + j * 8);
    uint4 v1 = *(const uint4*)(t + (size_t)s1 * 64 + j * 8);
    uint4 v2 = *(const uint4*)(t + (size_t)s2 * 64 + j * 8);
    uint4 v3 = *(const uint4*)(t + (size_t)s3 * 64 + j * 8);
    a0 += bf2f(v0.x & 0xffff) + bf2f(v1.x & 0xffff) + bf2f(v2.x & 0xffff) + bf2f(v3.x & 0xffff);
    a1 += bf2f(v0.x >> 16)    + bf2f(v1.x >> 16)    + bf2f(v2.x >> 16)    + bf2f(v3.x >> 16);
    a2 += bf2f(v0.y & 0xffff) + bf2f(v1.y & 0xffff) + bf2f(v2.y & 0xffff) + bf2f(v3.y & 0xffff);
    a3 += bf2f(v0.y >> 16)    + bf2f(v1.y >> 16)    + bf2f(v2.y >> 16)    + bf2f(v3.y >> 16);
    a4 += bf2f(v0.z & 0xffff) + bf2f(v1.z & 0xffff) + bf2f(v2.z & 0xffff) + bf2f(v3.z & 0xffff);
    a5 += bf2f(v0.z >> 16)    + bf2f(v1.z >> 16)    + bf2f(v2.z >> 16)    + bf2f(v3.z >> 16);
    a6 += bf2f(v0.w & 0xffff) + bf2f(v1.w & 0xffff) + bf2f(v2.w & 0xffff) + bf2f(v3.w & 0xffff);
    a7 += bf2f(v0.w >> 16)    + bf2f(v1.w >> 16)    + bf2f(v2.w >> 16)    + bf2f(v3.w >> 16);
  }
  for (; k < cnt; ++k) {
    int s = arow[k];
    uint4 v = *(const uint4*)(t + (size_t)s * 64 + j * 8);
    a0 += bf2f(v.x & 0xffff); a1 += bf2f(v.x >> 16);
    a2 += bf2f(v.y & 0xffff); a3 += bf2f(v.y >> 16);
    a4 += bf2f(v.z & 0xffff); a5 += bf2f(v.z >> 16);
    a6 += bf2f(v.w & 0xffff); a7 += bf2f(v.w >> 16);
  }
  float inv = 1.0f / fmaxf((float)cnt, 1.0f);
  int o = j * 8;
  uint4 rv = *(const uint4*)(r2 + (size_t)node * 64 + o);
  float r0 = bf2f(rv.x & 0xffff), r1 = bf2f(rv.x >> 16);
  float r2a = bf2f(rv.y & 0xffff), r3 = bf2f(rv.y >> 16);
  float r4 = bf2f(rv.z & 0xffff), r5 = bf2f(rv.z >> 16);
  float r6 = bf2f(rv.w & 0xffff), r7 = bf2f(rv.w >> 16);
  float4 sca = *(const float4*)(bn + 256 + o);
  float4 scb = *(const float4*)(bn + 256 + o + 4);
  float4 sha = *(const float4*)(bn + 320 + o);
  float4 shb = *(const float4*)(bn + 320 + o + 4);
  float4 o0, o1;
  o0.x = (a0 * inv + r0) * sca.x + sha.x;
  o0.y = (a1 * inv + r1) * sca.y + sha.y;
  o0.z = (a2 * inv + r2a) * sca.z + sha.z;
  o0.w = (a3 * inv + r3) * sca.w + sha.w;
  o1.x = (a4 * inv + r4) * scb.x + shb.x;
  o1.y = (a5 * inv + r5) * scb.y + shb.y;
  o1.z = (a6 * inv + r6) * scb.z + shb.z;
  o1.w = (a7 * inv + r7) * scb.w + shb.w;
  *(float4*)(outp + (size_t)node * 64 + o) = o0;
  *(float4*)(outp + (size_t)node * 64 + o + 4) = o1;
}

extern "C" void kernel_launch(void* const* d_in, const int* in_sizes, int n_in,
                              void* d_out, int out_size, void* d_ws, size_t ws_size,
                              hipStream_t stream) {
  const float* x   = (const float*)d_in[0];
  const int*   ei  = (const int*)d_in[1];
  const float* w1l = (const float*)d_in[2];
  const float* b1l = (const float*)d_in[3];
  const float* w1r = (const float*)d_in[4];
  const float* g1  = (const float*)d_in[5];
  const float* be1 = (const float*)d_in[6];
  const float* m1  = (const float*)d_in[7];
  const float* v1  = (const float*)d_in[8];
  const float* w2l = (const float*)d_in[9];
  const float* b2l = (const float*)d_in[10];
  const float* w2r = (const float*)d_in[11];
  const float* g2  = (const float*)d_in[12];
  const float* be2 = (const float*)d_in[13];
  const float* m2  = (const float*)d_in[14];
  const float* v2  = (const float*)d_in[15];
  float* outp = (float*)d_out;

  char* ws = (char*)d_ws;
  // layout (bytes), 16B-aligned:
  //           0 : gcur       (1,024)
  //       1,024 : bucketBase (1,024)
  //       2,048 : deg        (400,000)
  //     402,048 : offset     (400,000)
  //     802,048 : pairs      (7,225,344)   -> 8,027,392
  //   8,027,392 : csr        (6,400,000)   -> 14,427,392
  //  14,427,392 : w1c bf16   (32,768)      -> 14,460,160
  //  14,460,160 : w2c bf16   (32,768)      -> 14,492,928
  //  14,492,928 : bn  fp32   (2,048)       -> 14,494,976
  //  14,494,976 : xb  bf16   (12,800,000)  -> 27,294,976
  //  27,294,976 : aggB bf16  (12,800,000)  -> 40,094,976
  //  40,094,976 : t   bf16   (12,800,000)  -> 52,894,976
  //  52,894,976 : r2  bf16   (12,800,000)  -> 65,694,976  (~65.7 MB)
  int*            gcur       = (int*)ws;
  int*            bucketBase = (int*)(ws + 1024);
  int*            deg        = (int*)(ws + 2048);
  int*            offset     = (int*)(ws + 402048);
  unsigned*       pairs      = (unsigned*)(ws + 802048);
  int*            csr        = (int*)(ws + 8027392);
  unsigned short* w1c        = (unsigned short*)(ws + 14427392);
  unsigned short* w2c        = (unsigned short*)(ws + 14460160);
  float*          bn         = (float*)(ws + 14492928);
  unsigned short* xb         = (unsigned short*)(ws + 14494976);
  unsigned short* aggB       = (unsigned short*)(ws + 27294976);
  unsigned short* t          = (unsigned short*)(ws + 40094976);
  unsigned short* r2         = (unsigned short*)(ws + 52894976);

  const int* srcp = ei;
  const int* dstp = ei + NE;

  hipMemsetAsync(gcur, 0, NBUK * sizeof(int), stream);
  hipLaunchKernelGGL(k_bin, dim3(NTIL), dim3(256), 0, stream,
                     srcp, dstp, gcur, pairs);
  hipLaunchKernelGGL(k_bscan, dim3(1), dim3(256), 0, stream, gcur, bucketBase);
  hipLaunchKernelGGL(k_build, dim3(NBUK), dim3(512), 0, stream,
                     pairs, gcur, bucketBase, deg, offset, csr);
  hipLaunchKernelGGL(k_wprep, dim3(64), dim3(256), 0, stream,
                     w1l, w1r, w2l, w2r, b1l, g1, be1, m1, v1,
                     b2l, g2, be2, m2, v2, w1c, w2c, bn);
  hipLaunchKernelGGL(k_cvtx, dim3(NN * 64 / 1024), dim3(256), 0, stream, x, xb);
  hipLaunchKernelGGL(k_aggregate, dim3(NN / 32), dim3(256), 0, stream,
                     xb, deg, offset, csr, aggB);
  hipLaunchKernelGGL(k_gemm12, dim3((NN + 127) / 128), dim3(256), 0, stream,
                     aggB, xb, w1c, w2c, bn, t, r2);
  hipLaunchKernelGGL(k_agg2fin, dim3(NN / 32), dim3(256), 0, stream,
                     t, deg, offset, csr, r2, bn, outp);
}